// Round 1
// baseline (1837.210 us; speedup 1.0000x reference)
//
#include <hip/hip_runtime.h>

static constexpr float NEG_SLOPE = 0.2f;

// Monotone float->uint encoding for atomicMax on floats.
__device__ __forceinline__ unsigned enc_f(float f) {
  unsigned u = __float_as_uint(f);
  return (u & 0x80000000u) ? ~u : (u | 0x80000000u);
}
__device__ __forceinline__ float dec_f(unsigned x) {
  return (x & 0x80000000u) ? __uint_as_float(x & 0x7FFFFFFFu) : __uint_as_float(~x);
}

// h = x @ W  (W cached in LDS), plus per-node attention logits
// als[n,h] = sum_c h[n,h,c]*a_src[h,c], ald likewise.
// blockDim.x == H*C*GROUPS; each group of H*C threads handles one row.
template <int F_IN, int H, int C, int GROUPS>
__global__ void k_gemm_attn(const float* __restrict__ x, const float* __restrict__ W,
                            const float* __restrict__ a_src, const float* __restrict__ a_dst,
                            float* __restrict__ h_out, float* __restrict__ als,
                            float* __restrict__ ald, int N) {
  constexpr int HC = H * C;
  __shared__ float Wlds[F_IN * HC];
  for (int i = threadIdx.x; i < F_IN * HC; i += HC * GROUPS) Wlds[i] = W[i];
  __syncthreads();
  const int g = threadIdx.x / HC;
  const int t = threadIdx.x % HC;
  const int hd = t / C, c = t % C;
  const float as_ = a_src[t], ad_ = a_dst[t];
  for (int row = blockIdx.x * GROUPS + g; row < N; row += gridDim.x * GROUPS) {
    const float* xr = x + (size_t)row * F_IN;
    float acc = 0.f;
#pragma unroll 8
    for (int k = 0; k < F_IN; ++k) acc = fmaf(xr[k], Wlds[k * HC + t], acc);
    h_out[(size_t)row * HC + t] = acc;
    float ps = acc * as_, pd = acc * ad_;
#pragma unroll
    for (int off = C / 2; off > 0; off >>= 1) {
      ps += __shfl_xor(ps, off, 64);
      pd += __shfl_xor(pd, off, 64);
    }
    if (c == 0) {
      als[(size_t)row * H + hd] = ps;
      ald[(size_t)row * H + hd] = pd;
    }
  }
}

// Pass 1 over edges: e = leakyrelu(als[src]+ald[dst]); segment max into m_enc[dst].
template <int H>
__global__ void k_edge_max(const int* __restrict__ esrc, const int* __restrict__ edst,
                           const float* __restrict__ als, const float* __restrict__ ald,
                           unsigned* __restrict__ m_enc, int E, int N) {
  const int total = (E + N) * H;
  for (int wi = blockIdx.x * blockDim.x + threadIdx.x; wi < total;
       wi += gridDim.x * blockDim.x) {
    const int e = wi / H, hd = wi % H;
    const int s = e < E ? esrc[e] : e - E;
    const int d = e < E ? edst[e] : e - E;
    float v = als[(size_t)s * H + hd] + ald[(size_t)d * H + hd];
    v = v >= 0.f ? v : NEG_SLOPE * v;
    atomicMax(m_enc + (size_t)d * H + hd, enc_f(v));
  }
}

// Pass 2 over edges: ex = exp(e - m[dst]); store ex; segment-sum denom.
template <int H>
__global__ void k_edge_expsum(const int* __restrict__ esrc, const int* __restrict__ edst,
                              const float* __restrict__ als, const float* __restrict__ ald,
                              const unsigned* __restrict__ m_enc, float* __restrict__ den,
                              float* __restrict__ exb, int E, int N) {
  const int total = (E + N) * H;
  for (int wi = blockIdx.x * blockDim.x + threadIdx.x; wi < total;
       wi += gridDim.x * blockDim.x) {
    const int e = wi / H, hd = wi % H;
    const int s = e < E ? esrc[e] : e - E;
    const int d = e < E ? edst[e] : e - E;
    float v = als[(size_t)s * H + hd] + ald[(size_t)d * H + hd];
    v = v >= 0.f ? v : NEG_SLOPE * v;
    const float ex = __expf(v - dec_f(m_enc[(size_t)d * H + hd]));
    exb[(size_t)e * H + hd] = ex;
    atomicAdd(den + (size_t)d * H + hd, ex);
  }
}

// Pass 3 over edges: out[dst] += h[src] * (ex / den[dst]).  One wave per edge.
template <int H, int C>
__global__ void k_edge_scatter(const int* __restrict__ esrc, const int* __restrict__ edst,
                               const float* __restrict__ exb, const float* __restrict__ den,
                               const float* __restrict__ hfeat, float* __restrict__ out,
                               int E, int N) {
  constexpr int HC = H * C;
  const int lane = threadIdx.x & 63;
  const int wave = (int)((blockIdx.x * blockDim.x + threadIdx.x) >> 6);
  const int nw = (int)((gridDim.x * blockDim.x) >> 6);
  for (int e = wave; e < E + N; e += nw) {
    const int s = e < E ? esrc[e] : e - E;
    const int d = e < E ? edst[e] : e - E;
#pragma unroll
    for (int hc = lane; hc < HC; hc += 64) {
      const int hd = hc / C;
      const float alpha = exb[(size_t)e * H + hd] / den[(size_t)d * H + hd];
      atomicAdd(out + (size_t)d * HC + hc, hfeat[(size_t)s * HC + hc] * alpha);
    }
  }
}

// Epilogue: add bias, optional ELU, in place.
template <int HC, bool ELU>
__global__ void k_bias_act(float* __restrict__ io, const float* __restrict__ b, int total) {
  for (int i = blockIdx.x * blockDim.x + threadIdx.x; i < total;
       i += gridDim.x * blockDim.x) {
    float v = io[i] + b[i & (HC - 1)];
    if (ELU) v = v > 0.f ? v : (__expf(v) - 1.f);
    io[i] = v;
  }
}

extern "C" void kernel_launch(void* const* d_in, const int* in_sizes, int n_in,
                              void* d_out, int out_size, void* d_ws, size_t ws_size,
                              hipStream_t stream) {
  const float* x   = (const float*)d_in[0];
  const int*   ei  = (const int*)d_in[1];
  const float* W1  = (const float*)d_in[2];
  const float* a1s = (const float*)d_in[3];
  const float* a1d = (const float*)d_in[4];
  const float* b1  = (const float*)d_in[5];
  const float* W2  = (const float*)d_in[6];
  const float* a2s = (const float*)d_in[7];
  const float* a2d = (const float*)d_in[8];
  const float* b2  = (const float*)d_in[9];

  const int N = in_sizes[0] / 128;  // 100000
  const int E = in_sizes[1] / 2;    // 1600000
  const int* esrc = ei;
  const int* edst = ei + E;

  // Workspace layout (floats)
  float* ws   = (float*)d_ws;
  float* h    = ws;                        // N*128 (layer1) / N*64 (layer2)
  float* out1 = h    + (size_t)N * 128;    // N*128
  float* als  = out1 + (size_t)N * 128;    // N*4 (layer1) / N (layer2)
  float* ald  = als  + (size_t)N * 4;      // N*4
  unsigned* menc = (unsigned*)(ald + (size_t)N * 4);  // N*4
  float* den  = (float*)menc + (size_t)N * 4;         // N*4
  float* exb  = den  + (size_t)N * 4;      // (E+N)*4 (layer1) / (E+N) (layer2)

  float* outF = (float*)d_out;             // N*64

  // ---------------- Layer 1: H=4, C=32, concat -> [N,128], +b1, ELU ----------------
  hipMemsetAsync(out1, 0, (size_t)N * 128 * 4, stream);
  hipMemsetAsync(menc, 0, (size_t)N * 4 * 4, stream);
  hipMemsetAsync(den,  0, (size_t)N * 4 * 4, stream);

  k_gemm_attn<128, 4, 32, 2><<<1024, 256, 0, stream>>>(x, W1, a1s, a1d, h, als, ald, N);
  k_edge_max<4><<<4096, 256, 0, stream>>>(esrc, edst, als, ald, menc, E, N);
  k_edge_expsum<4><<<4096, 256, 0, stream>>>(esrc, edst, als, ald, menc, den, exb, E, N);
  k_edge_scatter<4, 32><<<8192, 256, 0, stream>>>(esrc, edst, exb, den, h, out1, E, N);
  k_bias_act<128, true><<<4096, 256, 0, stream>>>(out1, b1, N * 128);

  // ---------------- Layer 2: H=1, C=64, mean(H=1) -> [N,64], +b2 ----------------
  hipMemsetAsync(outF, 0, (size_t)N * 64 * 4, stream);
  hipMemsetAsync(menc, 0, (size_t)N * 4, stream);
  hipMemsetAsync(den,  0, (size_t)N * 4, stream);

  k_gemm_attn<128, 1, 64, 2><<<1024, 128, 0, stream>>>(out1, W2, a2s, a2d, h, als, ald, N);
  k_edge_max<1><<<2048, 256, 0, stream>>>(esrc, edst, als, ald, menc, E, N);
  k_edge_expsum<1><<<2048, 256, 0, stream>>>(esrc, edst, als, ald, menc, den, exb, E, N);
  k_edge_scatter<1, 64><<<8192, 256, 0, stream>>>(esrc, edst, exb, den, h, outF, E, N);
  k_bias_act<64, false><<<2048, 256, 0, stream>>>(outF, b2, N * 64);
}

// Round 3
// 889.455 us; speedup vs baseline: 2.0655x; 2.0655x over previous
//
#include <hip/hip_runtime.h>
#include <math.h>

static constexpr float NEG_SLOPE = 0.2f;
static constexpr float NEG_BIG = -3.0e38f;  // finite sentinel: avoids (-inf) - (-inf) = NaN

// ---------------- GEMM + attention logits ----------------
// h = x @ W  (W cached in LDS), plus per-node logits
// als[n,h] = sum_c h[n,h,c]*a_src[h,c], ald likewise.
// blockDim.x == H*C*GROUPS; each group of H*C threads handles one row.
template <int F_IN, int H, int C, int GROUPS>
__global__ void k_gemm_attn(const float* __restrict__ x, const float* __restrict__ W,
                            const float* __restrict__ a_src, const float* __restrict__ a_dst,
                            float* __restrict__ h_out, float* __restrict__ als,
                            float* __restrict__ ald, int N) {
  constexpr int HC = H * C;
  __shared__ float Wlds[F_IN * HC];
  for (int i = threadIdx.x; i < F_IN * HC; i += HC * GROUPS) Wlds[i] = W[i];
  __syncthreads();
  const int g = threadIdx.x / HC;
  const int t = threadIdx.x % HC;
  const int hd = t / C, c = t % C;
  const float as_ = a_src[t], ad_ = a_dst[t];
  for (int row = blockIdx.x * GROUPS + g; row < N; row += gridDim.x * GROUPS) {
    const float* xr = x + (size_t)row * F_IN;
    float acc = 0.f;
#pragma unroll 8
    for (int k = 0; k < F_IN; ++k) acc = fmaf(xr[k], Wlds[k * HC + t], acc);
    h_out[(size_t)row * HC + t] = acc;
    float ps = acc * as_, pd = acc * ad_;
#pragma unroll
    for (int off = C / 2; off > 0; off >>= 1) {
      ps += __shfl_xor(ps, off, 64);
      pd += __shfl_xor(pd, off, 64);
    }
    if (c == 0) {
      als[(size_t)row * H + hd] = ps;
      ald[(size_t)row * H + hd] = pd;
    }
  }
}

// ---------------- CSR build (counting sort by dst) ----------------
__global__ void k_fill1(int* __restrict__ cnt, int N) {
  int i = blockIdx.x * blockDim.x + threadIdx.x;
  if (i < N) cnt[i] = 1;  // self-loop
}

__global__ void k_count(const int* __restrict__ edst, int* __restrict__ cnt, int E) {
  int i = blockIdx.x * blockDim.x + threadIdx.x;
  if (i < E) atomicAdd(cnt + edst[i], 1);
}

// block-local exclusive scan: 256 threads x 4 items = 1024 elements/block
__global__ void k_scan_local(const int* __restrict__ cnt, int* __restrict__ rowptr,
                             int* __restrict__ bsum, int N) {
  __shared__ int lds[256];
  const int tid = threadIdx.x;
  const int base = blockIdx.x * 1024;
  int vals[4], tsum = 0;
#pragma unroll
  for (int q = 0; q < 4; ++q) {
    int i = base + tid * 4 + q;
    vals[q] = (i < N) ? cnt[i] : 0;
    tsum += vals[q];
  }
  lds[tid] = tsum;
  __syncthreads();
  for (int off = 1; off < 256; off <<= 1) {
    int t = (tid >= off) ? lds[tid - off] : 0;
    __syncthreads();
    lds[tid] += t;
    __syncthreads();
  }
  int run = lds[tid] - tsum;  // exclusive prefix of this thread's chunk
  if (tid == 255) bsum[blockIdx.x] = lds[255];
#pragma unroll
  for (int q = 0; q < 4; ++q) {
    int i = base + tid * 4 + q;
    if (i < N) rowptr[i] = run;
    run += vals[q];
  }
}

// single-block exclusive scan of block sums (up to 1024 blocks)
__global__ void k_scan_bsum(int* __restrict__ bsum, int nb) {
  __shared__ int lds[1024];
  const int tid = threadIdx.x;
  int v = (tid < nb) ? bsum[tid] : 0;
  lds[tid] = v;
  __syncthreads();
  for (int off = 1; off < 1024; off <<= 1) {
    int t = (tid >= off) ? lds[tid - off] : 0;
    __syncthreads();
    lds[tid] += t;
    __syncthreads();
  }
  bsum[tid] = lds[tid] - v;  // exclusive
}

__global__ void k_scan_add(const int* __restrict__ bsum, int* __restrict__ rowptr,
                           int* __restrict__ cursor, int N, int total) {
  int i = blockIdx.x * blockDim.x + threadIdx.x;
  if (i < N) {
    int r = rowptr[i] + bsum[i >> 10];
    rowptr[i] = r;
    cursor[i] = r;
  } else if (i == N) {
    rowptr[N] = total;
  }
}

__global__ void k_build(const int* __restrict__ esrc, const int* __restrict__ edst,
                        int* __restrict__ cursor, int* __restrict__ nbr, int E, int N) {
  int i = blockIdx.x * blockDim.x + threadIdx.x;
  if (i >= E + N) return;
  const int s = i < E ? esrc[i] : i - E;
  const int d = i < E ? edst[i] : i - E;
  int pos = atomicAdd(cursor + d, 1);
  nbr[pos] = s;
}

// ---------------- Gather: one wave per dst node, no atomics ----------------
template <int H, int C, bool ELU>
__global__ void k_gather(const int* __restrict__ rowptr, const int* __restrict__ nbr,
                         const float* __restrict__ als, const float* __restrict__ ald,
                         const float* __restrict__ hfeat, const float* __restrict__ bias,
                         float* __restrict__ out, int N) {
  constexpr int HC = H * C;
  constexpr int NCH = HC / 64;
  const int lane = threadIdx.x & 63;
  const int node = (int)((blockIdx.x * blockDim.x + threadIdx.x) >> 6);
  if (node >= N) return;
  const int start = rowptr[node], end = rowptr[node + 1];
  const int deg = end - start;

  float aldd[H];
#pragma unroll
  for (int hh = 0; hh < H; ++hh) aldd[hh] = ald[(size_t)node * H + hh];

  // Pass A: per-lane online softmax stats over this lane's edges
  float m[H], s[H], v0[H];
  int myn = 0;
#pragma unroll
  for (int hh = 0; hh < H; ++hh) { m[hh] = NEG_BIG; s[hh] = 0.f; v0[hh] = NEG_BIG; }
  for (int base = start; base < end; base += 64) {
    const int j = base + lane;
    if (j < end) {
      const int sn = nbr[j];
      if (base == start) myn = sn;
#pragma unroll
      for (int hh = 0; hh < H; ++hh) {
        float t = als[(size_t)sn * H + hh] + aldd[hh];
        t = t >= 0.f ? t : NEG_SLOPE * t;
        if (base == start) v0[hh] = t;
        const float M = fmaxf(m[hh], t);
        s[hh] = s[hh] * __expf(m[hh] - M) + __expf(t - M);
        m[hh] = M;
      }
    }
  }
  // wave merge of (m, s) — sentinels are finite, so m-M is never NaN
#pragma unroll
  for (int off = 1; off < 64; off <<= 1) {
#pragma unroll
    for (int hh = 0; hh < H; ++hh) {
      const float m2 = __shfl_xor(m[hh], off, 64);
      const float s2 = __shfl_xor(s[hh], off, 64);
      const float M = fmaxf(m[hh], m2);
      s[hh] = s[hh] * __expf(m[hh] - M) + s2 * __expf(m2 - M);
      m[hh] = M;
    }
  }
  float rden[H], exa[H];
#pragma unroll
  for (int hh = 0; hh < H; ++hh) {
    rden[hh] = 1.f / s[hh];
    exa[hh] = __expf(v0[hh] - m[hh]) * rden[hh];  // this lane's edge alpha (0 if inactive)
  }

  // Pass C: edge-serial accumulate, alphas broadcast via shuffle
  float acc[NCH];
#pragma unroll
  for (int q = 0; q < NCH; ++q) acc[q] = 0.f;
  const int cnt_first = deg < 64 ? deg : 64;
  for (int j = 0; j < cnt_first; ++j) {
    const int sn = __shfl(myn, j, 64);
    const float* hr = hfeat + (size_t)sn * HC;
    if (H == 4) {
      const float a0 = __shfl(exa[0], j, 64);
      const float a1 = __shfl(exa[1], j, 64);
      const float a2 = __shfl(exa[2], j, 64);
      const float a3 = __shfl(exa[3], j, 64);
      const float s0 = (lane & 32) ? a1 : a0;   // q=0: head = lane/32
      const float s1 = (lane & 32) ? a3 : a2;   // q=1: head = 2 + lane/32
      acc[0] = fmaf(hr[lane], s0, acc[0]);
      if (NCH > 1) acc[NCH - 1] = fmaf(hr[lane + 64], s1, acc[NCH - 1]);
    } else {  // H == 1
      const float a0 = __shfl(exa[0], j, 64);
      acc[0] = fmaf(hr[lane], a0, acc[0]);
    }
  }
  // rare tail: deg > 64
  for (int j = start + 64; j < end; ++j) {
    const int sn = nbr[j];
    float ex[H];
#pragma unroll
    for (int hh = 0; hh < H; ++hh) {
      float t = als[(size_t)sn * H + hh] + aldd[hh];
      t = t >= 0.f ? t : NEG_SLOPE * t;
      ex[hh] = __expf(t - m[hh]) * rden[hh];
    }
    const float* hr = hfeat + (size_t)sn * HC;
    if (H == 4) {
      const float s0 = (lane & 32) ? ex[1] : ex[0];
      const float s1 = (lane & 32) ? ex[3] : ex[2];
      acc[0] = fmaf(hr[lane], s0, acc[0]);
      if (NCH > 1) acc[NCH - 1] = fmaf(hr[lane + 64], s1, acc[NCH - 1]);
    } else {
      acc[0] = fmaf(hr[lane], ex[0], acc[0]);
    }
  }

  // epilogue: bias (+ELU)
#pragma unroll
  for (int q = 0; q < NCH; ++q) {
    const int hc = lane + q * 64;
    float r = acc[q] + bias[hc];
    if (ELU) r = r > 0.f ? r : (__expf(r) - 1.f);
    out[(size_t)node * HC + hc] = r;
  }
}

extern "C" void kernel_launch(void* const* d_in, const int* in_sizes, int n_in,
                              void* d_out, int out_size, void* d_ws, size_t ws_size,
                              hipStream_t stream) {
  const float* x   = (const float*)d_in[0];
  const int*   ei  = (const int*)d_in[1];
  const float* W1  = (const float*)d_in[2];
  const float* a1s = (const float*)d_in[3];
  const float* a1d = (const float*)d_in[4];
  const float* b1  = (const float*)d_in[5];
  const float* W2  = (const float*)d_in[6];
  const float* a2s = (const float*)d_in[7];
  const float* a2d = (const float*)d_in[8];
  const float* b2  = (const float*)d_in[9];

  const int N = in_sizes[0] / 128;  // 100000
  const int E = in_sizes[1] / 2;    // 1600000
  const int* esrc = ei;
  const int* edst = ei + E;

  // Workspace layout
  float* ws   = (float*)d_ws;
  float* h    = ws;                          // N*128
  float* out1 = h    + (size_t)N * 128;      // N*128
  float* als  = out1 + (size_t)N * 128;      // N*4
  float* ald  = als  + (size_t)N * 4;        // N*4
  int* cnt    = (int*)(ald + (size_t)N * 4); // N
  int* rowptr = cnt + N;                     // N+1
  int* cursor = rowptr + N + 1;              // N
  int* bsum   = cursor + N;                  // 1024
  int* nbr    = bsum + 1024;                 // E+N

  float* outF = (float*)d_out;               // N*64

  const int total = E + N;
  const int nb = (N + 1023) / 1024;

  // ---- CSR build (shared by both layers) ----
  k_fill1<<<(N + 255) / 256, 256, 0, stream>>>(cnt, N);
  k_count<<<(E + 255) / 256, 256, 0, stream>>>(edst, cnt, E);
  k_scan_local<<<nb, 256, 0, stream>>>(cnt, rowptr, bsum, N);
  k_scan_bsum<<<1, 1024, 0, stream>>>(bsum, nb);
  k_scan_add<<<(N + 256) / 256, 256, 0, stream>>>(bsum, rowptr, cursor, N, total);
  k_build<<<(total + 255) / 256, 256, 0, stream>>>(esrc, edst, cursor, nbr, E, N);

  // ---- Layer 1: H=4, C=32, concat -> [N,128], +b1, ELU ----
  k_gemm_attn<128, 4, 32, 2><<<1024, 256, 0, stream>>>(x, W1, a1s, a1d, h, als, ald, N);
  k_gather<4, 32, true><<<(N + 3) / 4, 256, 0, stream>>>(rowptr, nbr, als, ald, h, b1, out1, N);

  // ---- Layer 2: H=1, C=64, mean(H=1) -> [N,64], +b2 ----
  k_gemm_attn<128, 1, 64, 2><<<1024, 128, 0, stream>>>(out1, W2, a2s, a2d, h, als, ald, N);
  k_gather<1, 64, false><<<(N + 3) / 4, 256, 0, stream>>>(rowptr, nbr, als, ald, h, b2, outF, N);
}

// Round 4
// 663.176 us; speedup vs baseline: 2.7703x; 1.3412x over previous
//
#include <hip/hip_runtime.h>
#include <math.h>

static constexpr float NEG_SLOPE = 0.2f;
static constexpr float NEG_BIG = -3.0e38f;  // finite sentinel: avoids (-inf) - (-inf) = NaN

// ---------------- GEMM + attention logits (v2: x-tile in LDS + R-row register blocking) ----
// h = x @ W, als[n,h] = sum_c h[n,h,c]*a_src[h,c], ald likewise.
// Block = HC*GROUPS threads; group g handles rows [base+g*R, base+g*R+R).
// W cached in LDS (1 read feeds R FMAs); x tile in LDS (same-address broadcast reads).
template <int F_IN, int H, int C, int GROUPS, int R>
__global__ void k_gemm_attn_v2(const float* __restrict__ x, const float* __restrict__ W,
                               const float* __restrict__ a_src, const float* __restrict__ a_dst,
                               float* __restrict__ h_out, float* __restrict__ als,
                               float* __restrict__ ald, int N) {
  constexpr int HC = H * C;
  constexpr int NT = HC * GROUPS;       // threads per block
  constexpr int RPI = GROUPS * R;       // rows per iteration
  __shared__ float Wlds[F_IN * HC];
  __shared__ float Xlds[RPI][F_IN];
  const int tid = threadIdx.x;
  for (int i = tid; i < F_IN * HC; i += NT) Wlds[i] = W[i];
  const int g = tid / HC;
  const int t = tid % HC;
  const int hd = t / C, c = t % C;
  const float as_ = a_src[t], ad_ = a_dst[t];

  for (int base = blockIdx.x * RPI; base < N; base += gridDim.x * RPI) {
    __syncthreads();  // prior iter done reading Xlds (also covers initial W load)
    for (int i = tid; i < RPI * F_IN; i += NT) {
      const int r = i / F_IN, k = i % F_IN;
      const int row = base + r;
      Xlds[r][k] = (row < N) ? x[(size_t)row * F_IN + k] : 0.f;
    }
    __syncthreads();

    float acc[R];
#pragma unroll
    for (int r = 0; r < R; ++r) acc[r] = 0.f;
#pragma unroll 4
    for (int k4 = 0; k4 < F_IN; k4 += 4) {
      float w[4];
#pragma unroll
      for (int q = 0; q < 4; ++q) w[q] = Wlds[(k4 + q) * HC + t];
#pragma unroll
      for (int r = 0; r < R; ++r) {
        const float4 xv = *reinterpret_cast<const float4*>(&Xlds[g * R + r][k4]);
        acc[r] = fmaf(xv.x, w[0], acc[r]);
        acc[r] = fmaf(xv.y, w[1], acc[r]);
        acc[r] = fmaf(xv.z, w[2], acc[r]);
        acc[r] = fmaf(xv.w, w[3], acc[r]);
      }
    }

#pragma unroll
    for (int r = 0; r < R; ++r) {
      const int row = base + g * R + r;
      if (row < N) {
        h_out[(size_t)row * HC + t] = acc[r];
        float ps = acc[r] * as_, pd = acc[r] * ad_;
#pragma unroll
        for (int off = C / 2; off > 0; off >>= 1) {
          ps += __shfl_xor(ps, off, 64);
          pd += __shfl_xor(pd, off, 64);
        }
        if (c == 0) {
          als[(size_t)row * H + hd] = ps;
          ald[(size_t)row * H + hd] = pd;
        }
      }
    }
  }
}

// ---------------- CSR build (counting sort by dst) ----------------
__global__ void k_fill1(int* __restrict__ cnt, int N) {
  int i = blockIdx.x * blockDim.x + threadIdx.x;
  if (i < N) cnt[i] = 1;  // self-loop
}

__global__ void k_count(const int* __restrict__ edst, int* __restrict__ cnt, int E) {
  int i = blockIdx.x * blockDim.x + threadIdx.x;
  if (i < E) atomicAdd(cnt + edst[i], 1);
}

// block-local exclusive scan: 256 threads x 4 items = 1024 elements/block
__global__ void k_scan_local(const int* __restrict__ cnt, int* __restrict__ rowptr,
                             int* __restrict__ bsum, int N) {
  __shared__ int lds[256];
  const int tid = threadIdx.x;
  const int base = blockIdx.x * 1024;
  int vals[4], tsum = 0;
#pragma unroll
  for (int q = 0; q < 4; ++q) {
    int i = base + tid * 4 + q;
    vals[q] = (i < N) ? cnt[i] : 0;
    tsum += vals[q];
  }
  lds[tid] = tsum;
  __syncthreads();
  for (int off = 1; off < 256; off <<= 1) {
    int t = (tid >= off) ? lds[tid - off] : 0;
    __syncthreads();
    lds[tid] += t;
    __syncthreads();
  }
  int run = lds[tid] - tsum;  // exclusive prefix of this thread's chunk
  if (tid == 255) bsum[blockIdx.x] = lds[255];
#pragma unroll
  for (int q = 0; q < 4; ++q) {
    int i = base + tid * 4 + q;
    if (i < N) rowptr[i] = run;
    run += vals[q];
  }
}

// single-block exclusive scan of block sums (up to 1024 blocks)
__global__ void k_scan_bsum(int* __restrict__ bsum, int nb) {
  __shared__ int lds[1024];
  const int tid = threadIdx.x;
  int v = (tid < nb) ? bsum[tid] : 0;
  lds[tid] = v;
  __syncthreads();
  for (int off = 1; off < 1024; off <<= 1) {
    int t = (tid >= off) ? lds[tid - off] : 0;
    __syncthreads();
    lds[tid] += t;
    __syncthreads();
  }
  bsum[tid] = lds[tid] - v;  // exclusive
}

__global__ void k_scan_add(const int* __restrict__ bsum, int* __restrict__ rowptr,
                           int* __restrict__ cursor, int N, int total) {
  int i = blockIdx.x * blockDim.x + threadIdx.x;
  if (i < N) {
    int r = rowptr[i] + bsum[i >> 10];
    rowptr[i] = r;
    cursor[i] = r;
  } else if (i == N) {
    rowptr[N] = total;
  }
}

__global__ void k_build(const int* __restrict__ esrc, const int* __restrict__ edst,
                        int* __restrict__ cursor, int* __restrict__ nbr, int E, int N) {
  int i = blockIdx.x * blockDim.x + threadIdx.x;
  if (i >= E + N) return;
  const int s = i < E ? esrc[i] : i - E;
  const int d = i < E ? edst[i] : i - E;
  int pos = atomicAdd(cursor + d, 1);
  nbr[pos] = s;
}

// ---------------- Gather: one wave per dst node, no atomics ----------------
template <int H, int C, bool ELU>
__global__ void k_gather(const int* __restrict__ rowptr, const int* __restrict__ nbr,
                         const float* __restrict__ als, const float* __restrict__ ald,
                         const float* __restrict__ hfeat, const float* __restrict__ bias,
                         float* __restrict__ out, int N) {
  constexpr int HC = H * C;
  constexpr int NCH = HC / 64;
  const int lane = threadIdx.x & 63;
  const int node = (int)((blockIdx.x * blockDim.x + threadIdx.x) >> 6);
  if (node >= N) return;
  const int start = rowptr[node], end = rowptr[node + 1];
  const int deg = end - start;

  float aldd[H];
#pragma unroll
  for (int hh = 0; hh < H; ++hh) aldd[hh] = ald[(size_t)node * H + hh];

  // Pass A: per-lane online softmax stats over this lane's edges
  float m[H], s[H], v0[H];
  int myn = 0;
#pragma unroll
  for (int hh = 0; hh < H; ++hh) { m[hh] = NEG_BIG; s[hh] = 0.f; v0[hh] = NEG_BIG; }
  for (int base = start; base < end; base += 64) {
    const int j = base + lane;
    if (j < end) {
      const int sn = nbr[j];
      if (base == start) myn = sn;
#pragma unroll
      for (int hh = 0; hh < H; ++hh) {
        float t = als[(size_t)sn * H + hh] + aldd[hh];
        t = t >= 0.f ? t : NEG_SLOPE * t;
        if (base == start) v0[hh] = t;
        const float M = fmaxf(m[hh], t);
        s[hh] = s[hh] * __expf(m[hh] - M) + __expf(t - M);
        m[hh] = M;
      }
    }
  }
  // wave merge of (m, s) — sentinels are finite, so m-M is never NaN
#pragma unroll
  for (int off = 1; off < 64; off <<= 1) {
#pragma unroll
    for (int hh = 0; hh < H; ++hh) {
      const float m2 = __shfl_xor(m[hh], off, 64);
      const float s2 = __shfl_xor(s[hh], off, 64);
      const float M = fmaxf(m[hh], m2);
      s[hh] = s[hh] * __expf(m[hh] - M) + s2 * __expf(m2 - M);
      m[hh] = M;
    }
  }
  float rden[H], exa[H];
#pragma unroll
  for (int hh = 0; hh < H; ++hh) {
    rden[hh] = 1.f / s[hh];
    exa[hh] = __expf(v0[hh] - m[hh]) * rden[hh];  // this lane's edge alpha (0 if inactive)
  }

  // Pass C: edge-serial accumulate, alphas broadcast via shuffle
  float acc[NCH];
#pragma unroll
  for (int q = 0; q < NCH; ++q) acc[q] = 0.f;
  const int cnt_first = deg < 64 ? deg : 64;
  for (int j = 0; j < cnt_first; ++j) {
    const int sn = __shfl(myn, j, 64);
    const float* hr = hfeat + (size_t)sn * HC;
    if (H == 4) {
      const float a0 = __shfl(exa[0], j, 64);
      const float a1 = __shfl(exa[1], j, 64);
      const float a2 = __shfl(exa[2], j, 64);
      const float a3 = __shfl(exa[3], j, 64);
      const float s0 = (lane & 32) ? a1 : a0;   // q=0: head = lane/32
      const float s1 = (lane & 32) ? a3 : a2;   // q=1: head = 2 + lane/32
      acc[0] = fmaf(hr[lane], s0, acc[0]);
      if (NCH > 1) acc[NCH - 1] = fmaf(hr[lane + 64], s1, acc[NCH - 1]);
    } else {  // H == 1
      const float a0 = __shfl(exa[0], j, 64);
      acc[0] = fmaf(hr[lane], a0, acc[0]);
    }
  }
  // rare tail: deg > 64
  for (int j = start + 64; j < end; ++j) {
    const int sn = nbr[j];
    float ex[H];
#pragma unroll
    for (int hh = 0; hh < H; ++hh) {
      float t = als[(size_t)sn * H + hh] + aldd[hh];
      t = t >= 0.f ? t : NEG_SLOPE * t;
      ex[hh] = __expf(t - m[hh]) * rden[hh];
    }
    const float* hr = hfeat + (size_t)sn * HC;
    if (H == 4) {
      const float s0 = (lane & 32) ? ex[1] : ex[0];
      const float s1 = (lane & 32) ? ex[3] : ex[2];
      acc[0] = fmaf(hr[lane], s0, acc[0]);
      if (NCH > 1) acc[NCH - 1] = fmaf(hr[lane + 64], s1, acc[NCH - 1]);
    } else {
      acc[0] = fmaf(hr[lane], ex[0], acc[0]);
    }
  }

  // epilogue: bias (+ELU)
#pragma unroll
  for (int q = 0; q < NCH; ++q) {
    const int hc = lane + q * 64;
    float r = acc[q] + bias[hc];
    if (ELU) r = r > 0.f ? r : (__expf(r) - 1.f);
    out[(size_t)node * HC + hc] = r;
  }
}

extern "C" void kernel_launch(void* const* d_in, const int* in_sizes, int n_in,
                              void* d_out, int out_size, void* d_ws, size_t ws_size,
                              hipStream_t stream) {
  const float* x   = (const float*)d_in[0];
  const int*   ei  = (const int*)d_in[1];
  const float* W1  = (const float*)d_in[2];
  const float* a1s = (const float*)d_in[3];
  const float* a1d = (const float*)d_in[4];
  const float* b1  = (const float*)d_in[5];
  const float* W2  = (const float*)d_in[6];
  const float* a2s = (const float*)d_in[7];
  const float* a2d = (const float*)d_in[8];
  const float* b2  = (const float*)d_in[9];

  const int N = in_sizes[0] / 128;  // 100000
  const int E = in_sizes[1] / 2;    // 1600000
  const int* esrc = ei;
  const int* edst = ei + E;

  // Workspace layout
  float* ws   = (float*)d_ws;
  float* h    = ws;                          // N*128
  float* out1 = h    + (size_t)N * 128;      // N*128
  float* als  = out1 + (size_t)N * 128;      // N*4
  float* ald  = als  + (size_t)N * 4;        // N*4
  int* cnt    = (int*)(ald + (size_t)N * 4); // N
  int* rowptr = cnt + N;                     // N+1
  int* cursor = rowptr + N + 1;              // N
  int* bsum   = cursor + N;                  // 1024
  int* nbr    = bsum + 1024;                 // E+N

  float* outF = (float*)d_out;               // N*64

  const int total = E + N;
  const int nb = (N + 1023) / 1024;

  // ---- CSR build (shared by both layers) ----
  k_fill1<<<(N + 255) / 256, 256, 0, stream>>>(cnt, N);
  k_count<<<(E + 255) / 256, 256, 0, stream>>>(edst, cnt, E);
  k_scan_local<<<nb, 256, 0, stream>>>(cnt, rowptr, bsum, N);
  k_scan_bsum<<<1, 1024, 0, stream>>>(bsum, nb);
  k_scan_add<<<(N + 256) / 256, 256, 0, stream>>>(bsum, rowptr, cursor, N, total);
  k_build<<<(total + 255) / 256, 256, 0, stream>>>(esrc, edst, cursor, nbr, E, N);

  // ---- Layer 1: H=4, C=32, concat -> [N,128], +b1, ELU ----
  // 512 threads, R=8 -> 32 rows/iter; LDS = 64KB(W) + 16KB(x) = 80KB -> 2 blocks/CU
  k_gemm_attn_v2<128, 4, 32, 4, 8><<<(N + 31) / 32, 512, 0, stream>>>(
      x, W1, a1s, a1d, h, als, ald, N);
  k_gather<4, 32, true><<<(N + 3) / 4, 256, 0, stream>>>(rowptr, nbr, als, ald, h, b1, out1, N);

  // ---- Layer 2: H=1, C=64, mean(H=1) -> [N,64], +b2 ----
  // 512 threads, R=8 -> 64 rows/iter; LDS = 32KB(W) + 32KB(x) = 64KB -> 2 blocks/CU
  k_gemm_attn_v2<128, 1, 64, 8, 8><<<(N + 63) / 64, 512, 0, stream>>>(
      out1, W2, a2s, a2d, h, als, ald, N);
  k_gather<1, 64, false><<<(N + 3) / 4, 256, 0, stream>>>(rowptr, nbr, als, ald, h, b2, outF, N);
}

// Round 5
// 622.667 us; speedup vs baseline: 2.9506x; 1.0651x over previous
//
#include <hip/hip_runtime.h>
#include <hip/hip_bf16.h>
#include <math.h>

static constexpr float NEG_SLOPE = 0.2f;
static constexpr float NEG_BIG = -3.0e38f;  // finite sentinel: avoids (-inf)-(-inf)=NaN

// ---------------- GEMM + attention logits (x-tile in LDS + R-row register blocking) ----
// h = x @ W (stored bf16), als/ald fp32 logits from fp32 accumulators.
template <int F_IN, int H, int C, int GROUPS, int R>
__global__ void k_gemm_attn_v2(const float* __restrict__ x, const float* __restrict__ W,
                               const float* __restrict__ a_src, const float* __restrict__ a_dst,
                               __hip_bfloat16* __restrict__ h_out, float* __restrict__ als,
                               float* __restrict__ ald, int N) {
  constexpr int HC = H * C;
  constexpr int NT = HC * GROUPS;       // threads per block
  constexpr int RPI = GROUPS * R;       // rows per iteration
  __shared__ float Wlds[F_IN * HC];
  __shared__ float Xlds[RPI][F_IN];
  const int tid = threadIdx.x;
  for (int i = tid; i < F_IN * HC; i += NT) Wlds[i] = W[i];
  const int g = tid / HC;
  const int t = tid % HC;
  const int hd = t / C, c = t % C;
  const float as_ = a_src[t], ad_ = a_dst[t];

  for (int base = blockIdx.x * RPI; base < N; base += gridDim.x * RPI) {
    __syncthreads();  // prior iter done reading Xlds (also covers initial W load)
    for (int i = tid; i < RPI * F_IN; i += NT) {
      const int r = i / F_IN, k = i % F_IN;
      const int row = base + r;
      Xlds[r][k] = (row < N) ? x[(size_t)row * F_IN + k] : 0.f;
    }
    __syncthreads();

    float acc[R];
#pragma unroll
    for (int r = 0; r < R; ++r) acc[r] = 0.f;
#pragma unroll 4
    for (int k4 = 0; k4 < F_IN; k4 += 4) {
      float w[4];
#pragma unroll
      for (int q = 0; q < 4; ++q) w[q] = Wlds[(k4 + q) * HC + t];
#pragma unroll
      for (int r = 0; r < R; ++r) {
        const float4 xv = *reinterpret_cast<const float4*>(&Xlds[g * R + r][k4]);
        acc[r] = fmaf(xv.x, w[0], acc[r]);
        acc[r] = fmaf(xv.y, w[1], acc[r]);
        acc[r] = fmaf(xv.z, w[2], acc[r]);
        acc[r] = fmaf(xv.w, w[3], acc[r]);
      }
    }

#pragma unroll
    for (int r = 0; r < R; ++r) {
      const int row = base + g * R + r;
      if (row < N) {
        h_out[(size_t)row * HC + t] = __float2bfloat16(acc[r]);
        float ps = acc[r] * as_, pd = acc[r] * ad_;
#pragma unroll
        for (int off = C / 2; off > 0; off >>= 1) {
          ps += __shfl_xor(ps, off, 64);
          pd += __shfl_xor(pd, off, 64);
        }
        if (c == 0) {
          als[(size_t)row * H + hd] = ps;
          ald[(size_t)row * H + hd] = pd;
        }
      }
    }
  }
}

// ---------------- CSR build (counting sort by dst) ----------------
__global__ void k_fill1(int* __restrict__ cnt, int N) {
  int i = blockIdx.x * blockDim.x + threadIdx.x;
  if (i < N) cnt[i] = 1;  // self-loop
}

__global__ void k_count(const int* __restrict__ edst, int* __restrict__ cnt, int E) {
  int i = blockIdx.x * blockDim.x + threadIdx.x;
  if (i < E) atomicAdd(cnt + edst[i], 1);
}

__global__ void k_scan_local(const int* __restrict__ cnt, int* __restrict__ rowptr,
                             int* __restrict__ bsum, int N) {
  __shared__ int lds[256];
  const int tid = threadIdx.x;
  const int base = blockIdx.x * 1024;
  int vals[4], tsum = 0;
#pragma unroll
  for (int q = 0; q < 4; ++q) {
    int i = base + tid * 4 + q;
    vals[q] = (i < N) ? cnt[i] : 0;
    tsum += vals[q];
  }
  lds[tid] = tsum;
  __syncthreads();
  for (int off = 1; off < 256; off <<= 1) {
    int t = (tid >= off) ? lds[tid - off] : 0;
    __syncthreads();
    lds[tid] += t;
    __syncthreads();
  }
  int run = lds[tid] - tsum;
  if (tid == 255) bsum[blockIdx.x] = lds[255];
#pragma unroll
  for (int q = 0; q < 4; ++q) {
    int i = base + tid * 4 + q;
    if (i < N) rowptr[i] = run;
    run += vals[q];
  }
}

__global__ void k_scan_bsum(int* __restrict__ bsum, int nb) {
  __shared__ int lds[1024];
  const int tid = threadIdx.x;
  int v = (tid < nb) ? bsum[tid] : 0;
  lds[tid] = v;
  __syncthreads();
  for (int off = 1; off < 1024; off <<= 1) {
    int t = (tid >= off) ? lds[tid - off] : 0;
    __syncthreads();
    lds[tid] += t;
    __syncthreads();
  }
  bsum[tid] = lds[tid] - v;
}

__global__ void k_scan_add(const int* __restrict__ bsum, int* __restrict__ rowptr,
                           int* __restrict__ cursor, int N, int total) {
  int i = blockIdx.x * blockDim.x + threadIdx.x;
  if (i < N) {
    int r = rowptr[i] + bsum[i >> 10];
    rowptr[i] = r;
    cursor[i] = r;
  } else if (i == N) {
    rowptr[N] = total;
  }
}

__global__ void k_build(const int* __restrict__ esrc, const int* __restrict__ edst,
                        int* __restrict__ cursor, int* __restrict__ nbr, int E, int N) {
  int i = blockIdx.x * blockDim.x + threadIdx.x;
  if (i >= E + N) return;
  const int s = i < E ? esrc[i] : i - E;
  const int d = i < E ? edst[i] : i - E;
  int pos = atomicAdd(cursor + d, 1);
  nbr[pos] = s;
}

// ---------------- Gather layer 1: H=4, C=32, bf16 h, ELU ----------------
// One wave per dst node. Edge loop: sn via readlane (SGPR base load),
// alpha via single broadcast ds_read from per-wave LDS alpha table.
__global__ void k_gather_l1(const int* __restrict__ rowptr, const int* __restrict__ nbr,
                            const float* __restrict__ als, const float* __restrict__ ald,
                            const __hip_bfloat16* __restrict__ hfeat,
                            const float* __restrict__ bias,
                            float* __restrict__ out, int N) {
  __shared__ float alds[4][256];  // [wave][edge*4 + head]
  const int lane = threadIdx.x & 63;
  const int wid = threadIdx.x >> 6;
  const int node = (int)((blockIdx.x * blockDim.x + threadIdx.x) >> 6);
  if (node >= N) return;
  const int start = rowptr[node], end = rowptr[node + 1];
  const int deg = end - start;
  const float4 aldd = ((const float4*)ald)[node];

  // Pass A: per-lane online softmax stats (usually a single iteration)
  float m[4], s[4], v0[4];
  int myn = 0;
#pragma unroll
  for (int h = 0; h < 4; ++h) { m[h] = NEG_BIG; s[h] = 0.f; v0[h] = NEG_BIG; }
  for (int base = start; base < end; base += 64) {
    const int j = base + lane;
    if (j < end) {
      const int sn = nbr[j];
      if (base == start) myn = sn;
      const float4 av = ((const float4*)als)[sn];
      const float tr[4] = {av.x + aldd.x, av.y + aldd.y, av.z + aldd.z, av.w + aldd.w};
#pragma unroll
      for (int h = 0; h < 4; ++h) {
        const float tv = tr[h] >= 0.f ? tr[h] : NEG_SLOPE * tr[h];
        if (base == start) v0[h] = tv;
        const float M = fmaxf(m[h], tv);
        s[h] = s[h] * __expf(m[h] - M) + __expf(tv - M);
        m[h] = M;
      }
    }
  }
  // Two-phase wave reduce: global max, one rescale, sum.
  float Mh[4], rden[4], ex0[4];
#pragma unroll
  for (int h = 0; h < 4; ++h) {
    float M = m[h];
#pragma unroll
    for (int off = 1; off < 64; off <<= 1) M = fmaxf(M, __shfl_xor(M, off, 64));
    float e = s[h] * __expf(m[h] - M);
#pragma unroll
    for (int off = 1; off < 64; off <<= 1) e += __shfl_xor(e, off, 64);
    Mh[h] = M;
    rden[h] = 1.f / e;
    ex0[h] = __expf(v0[h] - M) * rden[h];  // alpha of this lane's first edge
  }
  ((float4*)&alds[wid][0])[lane] = make_float4(ex0[0], ex0[1], ex0[2], ex0[3]);

  // Pass C: edge-serial accumulate. lane covers channels {2*lane, 2*lane+1}.
  float accx = 0.f, accy = 0.f;
  const int g = lane >> 4;               // head of this lane's channels
  const float* aw = &alds[wid][g];
  const int cnt_first = deg < 64 ? deg : 64;
#pragma unroll 2
  for (int j = 0; j < cnt_first; ++j) {
    const int sn = __builtin_amdgcn_readlane(myn, j);  // uniform -> SGPR
    const unsigned v = ((const unsigned*)(hfeat + (size_t)sn * 128))[lane];
    const float a = aw[j * 4];
    accx = fmaf(__uint_as_float(v << 16), a, accx);
    accy = fmaf(__uint_as_float(v & 0xffff0000u), a, accy);
  }
  // rare tail: deg > 64
  for (int j = start + 64; j < end; ++j) {
    const int sn = nbr[j];
    const float4 av = ((const float4*)als)[sn];
    const float tr[4] = {av.x + aldd.x, av.y + aldd.y, av.z + aldd.z, av.w + aldd.w};
    float e[4];
#pragma unroll
    for (int h = 0; h < 4; ++h) {
      const float tv = tr[h] >= 0.f ? tr[h] : NEG_SLOPE * tr[h];
      e[h] = __expf(tv - Mh[h]) * rden[h];
    }
    const float a = g == 0 ? e[0] : g == 1 ? e[1] : g == 2 ? e[2] : e[3];
    const unsigned v = ((const unsigned*)(hfeat + (size_t)sn * 128))[lane];
    accx = fmaf(__uint_as_float(v << 16), a, accx);
    accy = fmaf(__uint_as_float(v & 0xffff0000u), a, accy);
  }

  const float2 b2 = ((const float2*)bias)[lane];
  float r0 = accx + b2.x, r1 = accy + b2.y;
  r0 = r0 > 0.f ? r0 : __expf(r0) - 1.f;
  r1 = r1 > 0.f ? r1 : __expf(r1) - 1.f;
  ((float2*)(out + (size_t)node * 128))[lane] = make_float2(r0, r1);
}

// ---------------- Gather layer 2: H=1, C=64, bf16 h, no ELU ----------------
__global__ void k_gather_l2(const int* __restrict__ rowptr, const int* __restrict__ nbr,
                            const float* __restrict__ als, const float* __restrict__ ald,
                            const __hip_bfloat16* __restrict__ hfeat,
                            const float* __restrict__ bias,
                            float* __restrict__ out, int N) {
  const int lane = threadIdx.x & 63;
  const int node = (int)((blockIdx.x * blockDim.x + threadIdx.x) >> 6);
  if (node >= N) return;
  const int start = rowptr[node], end = rowptr[node + 1];
  const int deg = end - start;
  const float ald0 = ald[node];

  float m = NEG_BIG, s = 0.f, v0 = NEG_BIG;
  int myn = 0;
  for (int base = start; base < end; base += 64) {
    const int j = base + lane;
    if (j < end) {
      const int sn = nbr[j];
      if (base == start) myn = sn;
      float tv = als[sn] + ald0;
      tv = tv >= 0.f ? tv : NEG_SLOPE * tv;
      if (base == start) v0 = tv;
      const float M = fmaxf(m, tv);
      s = s * __expf(m - M) + __expf(tv - M);
      m = M;
    }
  }
  float M = m;
#pragma unroll
  for (int off = 1; off < 64; off <<= 1) M = fmaxf(M, __shfl_xor(M, off, 64));
  float e = s * __expf(m - M);
#pragma unroll
  for (int off = 1; off < 64; off <<= 1) e += __shfl_xor(e, off, 64);
  const float rden = 1.f / e;
  const float ex0 = __expf(v0 - M) * rden;

  float acc = 0.f;
  const int cnt_first = deg < 64 ? deg : 64;
#pragma unroll 2
  for (int j = 0; j < cnt_first; ++j) {
    const int sn = __builtin_amdgcn_readlane(myn, j);
    const float a = __uint_as_float(__builtin_amdgcn_readlane(__float_as_uint(ex0), j));
    const unsigned short u = ((const unsigned short*)(hfeat + (size_t)sn * 64))[lane];
    acc = fmaf(__uint_as_float((unsigned)u << 16), a, acc);
  }
  for (int j = start + 64; j < end; ++j) {
    const int sn = nbr[j];
    float tv = als[sn] + ald0;
    tv = tv >= 0.f ? tv : NEG_SLOPE * tv;
    const float a = __expf(tv - M) * rden;
    const unsigned short u = ((const unsigned short*)(hfeat + (size_t)sn * 64))[lane];
    acc = fmaf(__uint_as_float((unsigned)u << 16), a, acc);
  }
  out[(size_t)node * 64 + lane] = acc + bias[lane];
}

extern "C" void kernel_launch(void* const* d_in, const int* in_sizes, int n_in,
                              void* d_out, int out_size, void* d_ws, size_t ws_size,
                              hipStream_t stream) {
  const float* x   = (const float*)d_in[0];
  const int*   ei  = (const int*)d_in[1];
  const float* W1  = (const float*)d_in[2];
  const float* a1s = (const float*)d_in[3];
  const float* a1d = (const float*)d_in[4];
  const float* b1  = (const float*)d_in[5];
  const float* W2  = (const float*)d_in[6];
  const float* a2s = (const float*)d_in[7];
  const float* a2d = (const float*)d_in[8];
  const float* b2  = (const float*)d_in[9];

  const int N = in_sizes[0] / 128;  // 100000
  const int E = in_sizes[1] / 2;    // 1600000
  const int* esrc = ei;
  const int* edst = ei + E;

  // Workspace layout (h region holds bf16 but keeps its old float-sized slot)
  float* ws   = (float*)d_ws;
  __hip_bfloat16* h = (__hip_bfloat16*)ws;   // N*128 bf16 (slot sized N*128 f32)
  float* out1 = ws   + (size_t)N * 128;      // N*128 f32
  float* als  = out1 + (size_t)N * 128;      // N*4
  float* ald  = als  + (size_t)N * 4;        // N*4
  int* cnt    = (int*)(ald + (size_t)N * 4); // N
  int* rowptr = cnt + N;                     // N+1
  int* cursor = rowptr + N + 1;              // N
  int* bsum   = cursor + N;                  // 1024
  int* nbr    = bsum + 1024;                 // E+N

  float* outF = (float*)d_out;               // N*64

  const int total = E + N;
  const int nb = (N + 1023) / 1024;

  // ---- CSR build (shared by both layers) ----
  k_fill1<<<(N + 255) / 256, 256, 0, stream>>>(cnt, N);
  k_count<<<(E + 255) / 256, 256, 0, stream>>>(edst, cnt, E);
  k_scan_local<<<nb, 256, 0, stream>>>(cnt, rowptr, bsum, N);
  k_scan_bsum<<<1, 1024, 0, stream>>>(bsum, nb);
  k_scan_add<<<(N + 256) / 256, 256, 0, stream>>>(bsum, rowptr, cursor, N, total);
  k_build<<<(total + 255) / 256, 256, 0, stream>>>(esrc, edst, cursor, nbr, E, N);

  // ---- Layer 1: H=4, C=32, concat -> [N,128], +b1, ELU ----
  k_gemm_attn_v2<128, 4, 32, 4, 8><<<(N + 31) / 32, 512, 0, stream>>>(
      x, W1, a1s, a1d, h, als, ald, N);
  k_gather_l1<<<(N + 3) / 4, 256, 0, stream>>>(rowptr, nbr, als, ald, h, b1, out1, N);

  // ---- Layer 2: H=1, C=64, mean(H=1) -> [N,64], +b2 ----
  k_gemm_attn_v2<128, 1, 64, 8, 8><<<(N + 63) / 64, 512, 0, stream>>>(
      out1, W2, a2s, a2d, h, als, ald, N);
  k_gather_l2<<<(N + 3) / 4, 256, 0, stream>>>(rowptr, nbr, als, ald, h, b2, outF, N);
}

// Round 6
// 523.594 us; speedup vs baseline: 3.5088x; 1.1892x over previous
//
#include <hip/hip_runtime.h>
#include <hip/hip_bf16.h>
#include <math.h>

static constexpr float NEG_SLOPE = 0.2f;
static constexpr float NEG_BIG = -3.0e38f;  // finite sentinel: avoids (-inf)-(-inf)=NaN

// ---------------- GEMM + attention logits (x-tile in LDS + R-row register blocking) ----
template <int F_IN, int H, int C, int GROUPS, int R>
__global__ void k_gemm_attn_v2(const float* __restrict__ x, const float* __restrict__ W,
                               const float* __restrict__ a_src, const float* __restrict__ a_dst,
                               __hip_bfloat16* __restrict__ h_out, float* __restrict__ als,
                               float* __restrict__ ald, int N) {
  constexpr int HC = H * C;
  constexpr int NT = HC * GROUPS;
  constexpr int RPI = GROUPS * R;
  __shared__ float Wlds[F_IN * HC];
  __shared__ float Xlds[RPI][F_IN];
  const int tid = threadIdx.x;
  for (int i = tid; i < F_IN * HC; i += NT) Wlds[i] = W[i];
  const int g = tid / HC;
  const int t = tid % HC;
  const int hd = t / C, c = t % C;
  const float as_ = a_src[t], ad_ = a_dst[t];

  for (int base = blockIdx.x * RPI; base < N; base += gridDim.x * RPI) {
    __syncthreads();
    for (int i = tid; i < RPI * F_IN; i += NT) {
      const int r = i / F_IN, k = i % F_IN;
      const int row = base + r;
      Xlds[r][k] = (row < N) ? x[(size_t)row * F_IN + k] : 0.f;
    }
    __syncthreads();

    float acc[R];
#pragma unroll
    for (int r = 0; r < R; ++r) acc[r] = 0.f;
#pragma unroll 4
    for (int k4 = 0; k4 < F_IN; k4 += 4) {
      float w[4];
#pragma unroll
      for (int q = 0; q < 4; ++q) w[q] = Wlds[(k4 + q) * HC + t];
#pragma unroll
      for (int r = 0; r < R; ++r) {
        const float4 xv = *reinterpret_cast<const float4*>(&Xlds[g * R + r][k4]);
        acc[r] = fmaf(xv.x, w[0], acc[r]);
        acc[r] = fmaf(xv.y, w[1], acc[r]);
        acc[r] = fmaf(xv.z, w[2], acc[r]);
        acc[r] = fmaf(xv.w, w[3], acc[r]);
      }
    }

#pragma unroll
    for (int r = 0; r < R; ++r) {
      const int row = base + g * R + r;
      if (row < N) {
        h_out[(size_t)row * HC + t] = __float2bfloat16(acc[r]);
        float ps = acc[r] * as_, pd = acc[r] * ad_;
#pragma unroll
        for (int off = C / 2; off > 0; off >>= 1) {
          ps += __shfl_xor(ps, off, 64);
          pd += __shfl_xor(pd, off, 64);
        }
        if (c == 0) {
          als[(size_t)row * H + hd] = ps;
          ald[(size_t)row * H + hd] = pd;
        }
      }
    }
  }
}

// ---------------- CSR build (counting sort by dst) ----------------
__global__ void k_fill1(int* __restrict__ cnt, int N) {
  int i = blockIdx.x * blockDim.x + threadIdx.x;
  if (i < N) cnt[i] = 1;
}

__global__ void k_count(const int* __restrict__ edst, int* __restrict__ cnt, int E) {
  int i = blockIdx.x * blockDim.x + threadIdx.x;
  if (i < E) atomicAdd(cnt + edst[i], 1);
}

__global__ void k_scan_local(const int* __restrict__ cnt, int* __restrict__ rowptr,
                             int* __restrict__ bsum, int N) {
  __shared__ int lds[256];
  const int tid = threadIdx.x;
  const int base = blockIdx.x * 1024;
  int vals[4], tsum = 0;
#pragma unroll
  for (int q = 0; q < 4; ++q) {
    int i = base + tid * 4 + q;
    vals[q] = (i < N) ? cnt[i] : 0;
    tsum += vals[q];
  }
  lds[tid] = tsum;
  __syncthreads();
  for (int off = 1; off < 256; off <<= 1) {
    int t = (tid >= off) ? lds[tid - off] : 0;
    __syncthreads();
    lds[tid] += t;
    __syncthreads();
  }
  int run = lds[tid] - tsum;
  if (tid == 255) bsum[blockIdx.x] = lds[255];
#pragma unroll
  for (int q = 0; q < 4; ++q) {
    int i = base + tid * 4 + q;
    if (i < N) rowptr[i] = run;
    run += vals[q];
  }
}

__global__ void k_scan_bsum(int* __restrict__ bsum, int nb) {
  __shared__ int lds[1024];
  const int tid = threadIdx.x;
  int v = (tid < nb) ? bsum[tid] : 0;
  lds[tid] = v;
  __syncthreads();
  for (int off = 1; off < 1024; off <<= 1) {
    int t = (tid >= off) ? lds[tid - off] : 0;
    __syncthreads();
    lds[tid] += t;
    __syncthreads();
  }
  bsum[tid] = lds[tid] - v;
}

__global__ void k_scan_add(const int* __restrict__ bsum, int* __restrict__ rowptr,
                           int* __restrict__ cursor, int N, int total) {
  int i = blockIdx.x * blockDim.x + threadIdx.x;
  if (i < N) {
    int r = rowptr[i] + bsum[i >> 10];
    rowptr[i] = r;
    cursor[i] = r;
  } else if (i == N) {
    rowptr[N] = total;
  }
}

__global__ void k_build(const int* __restrict__ esrc, const int* __restrict__ edst,
                        int* __restrict__ cursor, int* __restrict__ nbr, int E, int N) {
  int i = blockIdx.x * blockDim.x + threadIdx.x;
  if (i >= E + N) return;
  const int s = i < E ? esrc[i] : i - E;
  const int d = i < E ? edst[i] : i - E;
  int pos = atomicAdd(cursor + d, 1);
  nbr[pos] = s;
}

// ---------------- Gather layer 1: H=4, C=32, bf16 h, ELU ----------------
// One wave per node. Pass C processes 4 edges/iter: lane = (slot: lane>>4) x
// (16B chunk: lane&15); one dwordx4 moves 4 rows x 256B per wave instruction.
__global__ void k_gather_l1(const int* __restrict__ rowptr, const int* __restrict__ nbr,
                            const float* __restrict__ als, const float* __restrict__ ald,
                            const __hip_bfloat16* __restrict__ hfeat,
                            const float* __restrict__ bias,
                            float* __restrict__ out, int N) {
  __shared__ float alds[4][256];  // [wave][edge*4 + head]
  __shared__ int snlds[4][64];    // [wave][edge]
  const int lane = threadIdx.x & 63;
  const int wid = threadIdx.x >> 6;
  const int node = (int)((blockIdx.x * blockDim.x + threadIdx.x) >> 6);
  if (node >= N) return;
  const int start = rowptr[node], end = rowptr[node + 1];
  const int deg = end - start;
  const float4 aldd = ((const float4*)ald)[node];

  // ---- Pass A: this lane's edge logit (deg<=64: exactly one edge per lane) ----
  float t[4];
  int myn = 0;
  {
    const int j = start + lane;
    if (j < end) {
      myn = nbr[j];
      const float4 av = ((const float4*)als)[myn];
      const float tr[4] = {av.x + aldd.x, av.y + aldd.y, av.z + aldd.z, av.w + aldd.w};
#pragma unroll
      for (int h = 0; h < 4; ++h) t[h] = tr[h] >= 0.f ? tr[h] : NEG_SLOPE * tr[h];
    } else {
#pragma unroll
      for (int h = 0; h < 4; ++h) t[h] = NEG_BIG;
    }
  }
  snlds[wid][lane] = myn;

  float Mh[4], rden[4], myex[4];
  if (deg <= 64) {
    // degenerate online softmax: per-lane stats are just (t, 1)
#pragma unroll
    for (int h = 0; h < 4; ++h) {
      float M = t[h];
#pragma unroll
      for (int off = 1; off < 64; off <<= 1) M = fmaxf(M, __shfl_xor(M, off, 64));
      const float e = __expf(t[h] - M);  // 0 for inactive lanes
      float sum = e;
#pragma unroll
      for (int off = 1; off < 64; off <<= 1) sum += __shfl_xor(sum, off, 64);
      Mh[h] = M;
      rden[h] = 1.f / sum;
      myex[h] = e * rden[h];
    }
  } else {
    // rare: fold extra chunks online, then reduce
    float m[4], s[4];
#pragma unroll
    for (int h = 0; h < 4; ++h) { m[h] = t[h]; s[h] = 1.f; }  // all 64 lanes active
    for (int base = start + 64; base < end; base += 64) {
      const int j = base + lane;
      if (j < end) {
        const int sn = nbr[j];
        const float4 av = ((const float4*)als)[sn];
        const float tr[4] = {av.x + aldd.x, av.y + aldd.y, av.z + aldd.z, av.w + aldd.w};
#pragma unroll
        for (int h = 0; h < 4; ++h) {
          const float tv = tr[h] >= 0.f ? tr[h] : NEG_SLOPE * tr[h];
          const float M = fmaxf(m[h], tv);
          s[h] = s[h] * __expf(m[h] - M) + __expf(tv - M);
          m[h] = M;
        }
      }
    }
#pragma unroll
    for (int h = 0; h < 4; ++h) {
      float M = m[h];
#pragma unroll
      for (int off = 1; off < 64; off <<= 1) M = fmaxf(M, __shfl_xor(M, off, 64));
      float e = s[h] * __expf(m[h] - M);
#pragma unroll
      for (int off = 1; off < 64; off <<= 1) e += __shfl_xor(e, off, 64);
      Mh[h] = M;
      rden[h] = 1.f / e;
      myex[h] = __expf(t[h] - M) * rden[h];
    }
  }
  ((float4*)&alds[wid][0])[lane] = make_float4(myex[0], myex[1], myex[2], myex[3]);

  // ---- Pass C: 4 edges per iteration ----
  const int sub = lane >> 4;   // edge slot
  const int q = lane & 15;     // 16B chunk -> channels q*8..q*8+7
  const int head = q >> 2;
  float acc[8];
#pragma unroll
  for (int k = 0; k < 8; ++k) acc[k] = 0.f;

  const int nq = deg < 64 ? deg : 64;
  for (int j0 = 0; j0 < nq; j0 += 4) {
    const int j = j0 + sub;  // j <= 63; out-of-range slots have alpha 0, sn 0
    const int sn = snlds[wid][j];
    const float a = alds[wid][j * 4 + head];
    const uint4 v = *(const uint4*)((const unsigned short*)hfeat + (size_t)sn * 128 + q * 8);
    acc[0] = fmaf(__uint_as_float(v.x << 16), a, acc[0]);
    acc[1] = fmaf(__uint_as_float(v.x & 0xffff0000u), a, acc[1]);
    acc[2] = fmaf(__uint_as_float(v.y << 16), a, acc[2]);
    acc[3] = fmaf(__uint_as_float(v.y & 0xffff0000u), a, acc[3]);
    acc[4] = fmaf(__uint_as_float(v.z << 16), a, acc[4]);
    acc[5] = fmaf(__uint_as_float(v.z & 0xffff0000u), a, acc[5]);
    acc[6] = fmaf(__uint_as_float(v.w << 16), a, acc[6]);
    acc[7] = fmaf(__uint_as_float(v.w & 0xffff0000u), a, acc[7]);
  }
  if (deg > 64) {
    const float Mm = head == 0 ? Mh[0] : head == 1 ? Mh[1] : head == 2 ? Mh[2] : Mh[3];
    const float rd = head == 0 ? rden[0] : head == 1 ? rden[1] : head == 2 ? rden[2] : rden[3];
    const float ad_ = head == 0 ? aldd.x : head == 1 ? aldd.y : head == 2 ? aldd.z : aldd.w;
    for (int j0 = 64; j0 < deg; j0 += 4) {
      const int j = j0 + sub;
      float a = 0.f;
      int sn = 0;
      if (j < deg) {
        sn = nbr[start + j];
        const float4 av = ((const float4*)als)[sn];
        const float as_ = head == 0 ? av.x : head == 1 ? av.y : head == 2 ? av.z : av.w;
        float tv = as_ + ad_;
        tv = tv >= 0.f ? tv : NEG_SLOPE * tv;
        a = __expf(tv - Mm) * rd;
      }
      const uint4 v = *(const uint4*)((const unsigned short*)hfeat + (size_t)sn * 128 + q * 8);
      acc[0] = fmaf(__uint_as_float(v.x << 16), a, acc[0]);
      acc[1] = fmaf(__uint_as_float(v.x & 0xffff0000u), a, acc[1]);
      acc[2] = fmaf(__uint_as_float(v.y << 16), a, acc[2]);
      acc[3] = fmaf(__uint_as_float(v.y & 0xffff0000u), a, acc[3]);
      acc[4] = fmaf(__uint_as_float(v.z << 16), a, acc[4]);
      acc[5] = fmaf(__uint_as_float(v.z & 0xffff0000u), a, acc[5]);
      acc[6] = fmaf(__uint_as_float(v.w << 16), a, acc[6]);
      acc[7] = fmaf(__uint_as_float(v.w & 0xffff0000u), a, acc[7]);
    }
  }

  // reduce across the 4 edge slots
#pragma unroll
  for (int k = 0; k < 8; ++k) {
    acc[k] += __shfl_xor(acc[k], 16, 64);
    acc[k] += __shfl_xor(acc[k], 32, 64);
  }
  if (lane < 16) {
    const float4 b0 = ((const float4*)bias)[lane * 2];
    const float4 b1 = ((const float4*)bias)[lane * 2 + 1];
    float r[8] = {acc[0] + b0.x, acc[1] + b0.y, acc[2] + b0.z, acc[3] + b0.w,
                  acc[4] + b1.x, acc[5] + b1.y, acc[6] + b1.z, acc[7] + b1.w};
#pragma unroll
    for (int k = 0; k < 8; ++k) r[k] = r[k] > 0.f ? r[k] : __expf(r[k]) - 1.f;
    float4* op = (float4*)(out + (size_t)node * 128 + lane * 8);
    op[0] = make_float4(r[0], r[1], r[2], r[3]);
    op[1] = make_float4(r[4], r[5], r[6], r[7]);
  }
}

// ---------------- Gather layer 2: H=1, C=64, bf16 h, no ELU ----------------
// 8 edges/iter: lane = (slot: lane>>3) x (16B chunk: lane&7).
__global__ void k_gather_l2(const int* __restrict__ rowptr, const int* __restrict__ nbr,
                            const float* __restrict__ als, const float* __restrict__ ald,
                            const __hip_bfloat16* __restrict__ hfeat,
                            const float* __restrict__ bias,
                            float* __restrict__ out, int N) {
  __shared__ float alds[4][64];
  __shared__ int snlds[4][64];
  const int lane = threadIdx.x & 63;
  const int wid = threadIdx.x >> 6;
  const int node = (int)((blockIdx.x * blockDim.x + threadIdx.x) >> 6);
  if (node >= N) return;
  const int start = rowptr[node], end = rowptr[node + 1];
  const int deg = end - start;
  const float ald0 = ald[node];

  float t = NEG_BIG;
  int myn = 0;
  {
    const int j = start + lane;
    if (j < end) {
      myn = nbr[j];
      float tv = als[myn] + ald0;
      t = tv >= 0.f ? tv : NEG_SLOPE * tv;
    }
  }
  snlds[wid][lane] = myn;

  float M, rden;
  if (deg <= 64) {
    M = t;
#pragma unroll
    for (int off = 1; off < 64; off <<= 1) M = fmaxf(M, __shfl_xor(M, off, 64));
    const float e = __expf(t - M);
    float sum = e;
#pragma unroll
    for (int off = 1; off < 64; off <<= 1) sum += __shfl_xor(sum, off, 64);
    rden = 1.f / sum;
    alds[wid][lane] = e * rden;
  } else {
    float m = t, s = 1.f;
    for (int base = start + 64; base < end; base += 64) {
      const int j = base + lane;
      if (j < end) {
        float tv = als[nbr[j]] + ald0;
        tv = tv >= 0.f ? tv : NEG_SLOPE * tv;
        const float Mn = fmaxf(m, tv);
        s = s * __expf(m - Mn) + __expf(tv - Mn);
        m = Mn;
      }
    }
    M = m;
#pragma unroll
    for (int off = 1; off < 64; off <<= 1) M = fmaxf(M, __shfl_xor(M, off, 64));
    float e = s * __expf(m - M);
#pragma unroll
    for (int off = 1; off < 64; off <<= 1) e += __shfl_xor(e, off, 64);
    rden = 1.f / e;
    alds[wid][lane] = __expf(t - M) * rden;
  }

  const int sub = lane >> 3;  // edge slot (0..7)
  const int q = lane & 7;     // channels q*8..q*8+7
  float acc[8];
#pragma unroll
  for (int k = 0; k < 8; ++k) acc[k] = 0.f;

  const int nq = deg < 64 ? deg : 64;
  for (int j0 = 0; j0 < nq; j0 += 8) {
    const int j = j0 + sub;
    const int sn = snlds[wid][j];
    const float a = alds[wid][j];
    const uint4 v = *(const uint4*)((const unsigned short*)hfeat + (size_t)sn * 64 + q * 8);
    acc[0] = fmaf(__uint_as_float(v.x << 16), a, acc[0]);
    acc[1] = fmaf(__uint_as_float(v.x & 0xffff0000u), a, acc[1]);
    acc[2] = fmaf(__uint_as_float(v.y << 16), a, acc[2]);
    acc[3] = fmaf(__uint_as_float(v.y & 0xffff0000u), a, acc[3]);
    acc[4] = fmaf(__uint_as_float(v.z << 16), a, acc[4]);
    acc[5] = fmaf(__uint_as_float(v.z & 0xffff0000u), a, acc[5]);
    acc[6] = fmaf(__uint_as_float(v.w << 16), a, acc[6]);
    acc[7] = fmaf(__uint_as_float(v.w & 0xffff0000u), a, acc[7]);
  }
  if (deg > 64) {
    for (int j0 = 64; j0 < deg; j0 += 8) {
      const int j = j0 + sub;
      float a = 0.f;
      int sn = 0;
      if (j < deg) {
        sn = nbr[start + j];
        float tv = als[sn] + ald0;
        tv = tv >= 0.f ? tv : NEG_SLOPE * tv;
        a = __expf(tv - M) * rden;
      }
      const uint4 v = *(const uint4*)((const unsigned short*)hfeat + (size_t)sn * 64 + q * 8);
      acc[0] = fmaf(__uint_as_float(v.x << 16), a, acc[0]);
      acc[1] = fmaf(__uint_as_float(v.x & 0xffff0000u), a, acc[1]);
      acc[2] = fmaf(__uint_as_float(v.y << 16), a, acc[2]);
      acc[3] = fmaf(__uint_as_float(v.y & 0xffff0000u), a, acc[3]);
      acc[4] = fmaf(__uint_as_float(v.z << 16), a, acc[4]);
      acc[5] = fmaf(__uint_as_float(v.z & 0xffff0000u), a, acc[5]);
      acc[6] = fmaf(__uint_as_float(v.w << 16), a, acc[6]);
      acc[7] = fmaf(__uint_as_float(v.w & 0xffff0000u), a, acc[7]);
    }
  }

#pragma unroll
  for (int k = 0; k < 8; ++k) {
    acc[k] += __shfl_xor(acc[k], 8, 64);
    acc[k] += __shfl_xor(acc[k], 16, 64);
    acc[k] += __shfl_xor(acc[k], 32, 64);
  }
  if (lane < 8) {
    const float4 b0 = ((const float4*)bias)[lane * 2];
    const float4 b1 = ((const float4*)bias)[lane * 2 + 1];
    float4* op = (float4*)(out + (size_t)node * 64 + lane * 8);
    op[0] = make_float4(acc[0] + b0.x, acc[1] + b0.y, acc[2] + b0.z, acc[3] + b0.w);
    op[1] = make_float4(acc[4] + b1.x, acc[5] + b1.y, acc[6] + b1.z, acc[7] + b1.w);
  }
}

extern "C" void kernel_launch(void* const* d_in, const int* in_sizes, int n_in,
                              void* d_out, int out_size, void* d_ws, size_t ws_size,
                              hipStream_t stream) {
  const float* x   = (const float*)d_in[0];
  const int*   ei  = (const int*)d_in[1];
  const float* W1  = (const float*)d_in[2];
  const float* a1s = (const float*)d_in[3];
  const float* a1d = (const float*)d_in[4];
  const float* b1  = (const float*)d_in[5];
  const float* W2  = (const float*)d_in[6];
  const float* a2s = (const float*)d_in[7];
  const float* a2d = (const float*)d_in[8];
  const float* b2  = (const float*)d_in[9];

  const int N = in_sizes[0] / 128;  // 100000
  const int E = in_sizes[1] / 2;    // 1600000
  const int* esrc = ei;
  const int* edst = ei + E;

  float* ws   = (float*)d_ws;
  __hip_bfloat16* h = (__hip_bfloat16*)ws;   // N*128 bf16 (slot sized N*128 f32)
  float* out1 = ws   + (size_t)N * 128;      // N*128 f32
  float* als  = out1 + (size_t)N * 128;      // N*4
  float* ald  = als  + (size_t)N * 4;        // N*4
  int* cnt    = (int*)(ald + (size_t)N * 4); // N
  int* rowptr = cnt + N;                     // N+1
  int* cursor = rowptr + N + 1;              // N
  int* bsum   = cursor + N;                  // 1024
  int* nbr    = bsum + 1024;                 // E+N

  float* outF = (float*)d_out;               // N*64

  const int total = E + N;
  const int nb = (N + 1023) / 1024;

  // ---- CSR build (shared by both layers) ----
  k_fill1<<<(N + 255) / 256, 256, 0, stream>>>(cnt, N);
  k_count<<<(E + 255) / 256, 256, 0, stream>>>(edst, cnt, E);
  k_scan_local<<<nb, 256, 0, stream>>>(cnt, rowptr, bsum, N);
  k_scan_bsum<<<1, 1024, 0, stream>>>(bsum, nb);
  k_scan_add<<<(N + 256) / 256, 256, 0, stream>>>(bsum, rowptr, cursor, N, total);
  k_build<<<(total + 255) / 256, 256, 0, stream>>>(esrc, edst, cursor, nbr, E, N);

  // ---- Layer 1: H=4, C=32, concat -> [N,128], +b1, ELU ----
  k_gemm_attn_v2<128, 4, 32, 4, 8><<<(N + 31) / 32, 512, 0, stream>>>(
      x, W1, a1s, a1d, h, als, ald, N);
  k_gather_l1<<<(N + 3) / 4, 256, 0, stream>>>(rowptr, nbr, als, ald, h, b1, out1, N);

  // ---- Layer 2: H=1, C=64, mean(H=1) -> [N,64], +b2 ----
  k_gemm_attn_v2<128, 1, 64, 8, 8><<<(N + 63) / 64, 512, 0, stream>>>(
      out1, W2, a2s, a2d, h, als, ald, N);
  k_gather_l2<<<(N + 3) / 4, 256, 0, stream>>>(rowptr, nbr, als, ald, h, b2, outF, N);
}

// Round 7
// 444.804 us; speedup vs baseline: 4.1304x; 1.1771x over previous
//
#include <hip/hip_runtime.h>
#include <hip/hip_bf16.h>
#include <math.h>

static constexpr float NEG_SLOPE = 0.2f;
static constexpr float NEG_BIG = -3.0e38f;  // finite sentinel: avoids (-inf)-(-inf)=NaN

__device__ __forceinline__ float blo(unsigned u) { return __uint_as_float(u << 16); }
__device__ __forceinline__ float bhi(unsigned u) { return __uint_as_float(u & 0xffff0000u); }
__device__ __forceinline__ unsigned pack2(float a, float b) {
  __hip_bfloat162 t = __float22bfloat162_rn(make_float2(a, b));
  union { __hip_bfloat162 b; unsigned u; } v;
  v.b = t;
  return v.u;  // low 16 bits = bf16(a), high = bf16(b)
}

// ---------------- GEMM v3: 2D register tiling (8x8/thread) + logits ----------------
// h = x @ W (x staged bf16 in LDS [k][row], W fp32 double-buffered [k][col]),
// h stored bf16; als/ald fp32 from fp32 accumulators. K = 128 fixed.
// BM=TY*8 rows, BN=TX*8 cols per block; HEADS in {4,1}; C = BN/HEADS.
template <int BM, int BN, int TX, int TY, int HEADS>
__global__ __launch_bounds__(TX * TY) void k_gemm_attn_v3(
    const float* __restrict__ x, const float* __restrict__ W,
    const float* __restrict__ a_src, const float* __restrict__ a_dst,
    __hip_bfloat16* __restrict__ h_out, float* __restrict__ als,
    float* __restrict__ ald, int N) {
  constexpr int NT = TX * TY;
  constexpr int SEG = NT / BM;            // k-segments per row for X staging
  constexpr int KPT = 128 / SEG;          // k's staged per thread
  constexpr int WPT = (32 * BN) / (NT * 4);  // float4 per thread per W chunk
  constexpr int TXPH = TX / HEADS;        // threads covering one head's cols
  __shared__ unsigned Xlds[128][BM / 2];  // u32 = bf16 row-pair, [k][row/2]
  __shared__ float Wlds[2][32 * BN];      // [buf][k-in-chunk][col]
  const int tid = threadIdx.x;
  const int base = blockIdx.x * BM;

  // ---- stage X tile (fp32 -> bf16, transposed to [k][row]) ----
  {
    const int srow = tid / SEG;
    const int k0 = (tid % SEG) * KPT;
    const int row = base + srow;
    __hip_bfloat16* xl = (__hip_bfloat16*)&Xlds[0][0];
    if (row < N) {
      const float* xr = x + (size_t)row * 128 + k0;
#pragma unroll
      for (int j = 0; j < KPT; j += 4) {
        const float4 v = *(const float4*)(xr + j);
        xl[(k0 + j + 0) * BM + srow] = __float2bfloat16(v.x);
        xl[(k0 + j + 1) * BM + srow] = __float2bfloat16(v.y);
        xl[(k0 + j + 2) * BM + srow] = __float2bfloat16(v.z);
        xl[(k0 + j + 3) * BM + srow] = __float2bfloat16(v.w);
      }
    } else {
      const __hip_bfloat16 z = __float2bfloat16(0.f);
#pragma unroll
      for (int j = 0; j < KPT; ++j) xl[(k0 + j) * BM + srow] = z;
    }
  }
  // ---- stage W chunk 0 ----
  {
    const float4* wg = (const float4*)W;
    float4* wl = (float4*)&Wlds[0][0];
#pragma unroll
    for (int q = 0; q < WPT; ++q) wl[q * NT + tid] = wg[q * NT + tid];
  }
  __syncthreads();

  const int tx = tid % TX, ty = tid / TX;
  float acc[8][8];
#pragma unroll
  for (int r = 0; r < 8; ++r)
#pragma unroll
    for (int j = 0; j < 8; ++j) acc[r][j] = 0.f;

  int cur = 0;
#pragma unroll
  for (int c = 0; c < 4; ++c) {
    float4 wreg[WPT];
    if (c < 3) {  // prefetch next W chunk to regs (overlaps compute)
      const float4* wg = (const float4*)(W + (size_t)(c + 1) * 32 * BN);
#pragma unroll
      for (int q = 0; q < WPT; ++q) wreg[q] = wg[q * NT + tid];
    }
#pragma unroll
    for (int kk = 0; kk < 32; ++kk) {
      const uint4 xv = *(const uint4*)&Xlds[c * 32 + kk][ty * 4];
      const float4 w0 = *(const float4*)&Wlds[cur][kk * BN + tx * 8];
      const float4 w1 = *(const float4*)&Wlds[cur][kk * BN + tx * 8 + 4];
      const float xr8[8] = {blo(xv.x), bhi(xv.x), blo(xv.y), bhi(xv.y),
                            blo(xv.z), bhi(xv.z), blo(xv.w), bhi(xv.w)};
      const float w8[8] = {w0.x, w0.y, w0.z, w0.w, w1.x, w1.y, w1.z, w1.w};
#pragma unroll
      for (int r = 0; r < 8; ++r)
#pragma unroll
        for (int j = 0; j < 8; ++j) acc[r][j] = fmaf(xr8[r], w8[j], acc[r][j]);
    }
    if (c < 3) {
      float4* wl = (float4*)&Wlds[cur ^ 1][0];
#pragma unroll
      for (int q = 0; q < WPT; ++q) wl[q * NT + tid] = wreg[q];
      cur ^= 1;
    }
    __syncthreads();
  }

  // ---- epilogue: h (bf16) + attention logits ----
  float asv[8], adv[8];
#pragma unroll
  for (int j = 0; j < 8; ++j) {
    asv[j] = a_src[tx * 8 + j];
    adv[j] = a_dst[tx * 8 + j];
  }
#pragma unroll
  for (int r = 0; r < 8; ++r) {
    const int row = base + ty * 8 + r;
    float ps = 0.f, pd = 0.f;
#pragma unroll
    for (int j = 0; j < 8; ++j) {
      ps = fmaf(acc[r][j], asv[j], ps);
      pd = fmaf(acc[r][j], adv[j], pd);
    }
#pragma unroll
    for (int off = 1; off < TXPH; off <<= 1) {
      ps += __shfl_xor(ps, off, 64);
      pd += __shfl_xor(pd, off, 64);
    }
    if (row < N) {
      uint4 o;
      o.x = pack2(acc[r][0], acc[r][1]);
      o.y = pack2(acc[r][2], acc[r][3]);
      o.z = pack2(acc[r][4], acc[r][5]);
      o.w = pack2(acc[r][6], acc[r][7]);
      *(uint4*)((unsigned short*)h_out + (size_t)row * BN + tx * 8) = o;
      if ((tx & (TXPH - 1)) == 0) {
        als[(size_t)row * HEADS + tx / TXPH] = ps;
        ald[(size_t)row * HEADS + tx / TXPH] = pd;
      }
    }
  }
}

// ---------------- CSR build (counting sort by dst) ----------------
__global__ void k_fill1(int* __restrict__ cnt, int N) {
  int i = blockIdx.x * blockDim.x + threadIdx.x;
  if (i < N) cnt[i] = 1;
}

__global__ void k_count(const int* __restrict__ edst, int* __restrict__ cnt, int E) {
  int i = blockIdx.x * blockDim.x + threadIdx.x;
  if (i < E) atomicAdd(cnt + edst[i], 1);
}

__global__ void k_scan_local(const int* __restrict__ cnt, int* __restrict__ rowptr,
                             int* __restrict__ bsum, int N) {
  __shared__ int lds[256];
  const int tid = threadIdx.x;
  const int base = blockIdx.x * 1024;
  int vals[4], tsum = 0;
#pragma unroll
  for (int q = 0; q < 4; ++q) {
    int i = base + tid * 4 + q;
    vals[q] = (i < N) ? cnt[i] : 0;
    tsum += vals[q];
  }
  lds[tid] = tsum;
  __syncthreads();
  for (int off = 1; off < 256; off <<= 1) {
    int t = (tid >= off) ? lds[tid - off] : 0;
    __syncthreads();
    lds[tid] += t;
    __syncthreads();
  }
  int run = lds[tid] - tsum;
  if (tid == 255) bsum[blockIdx.x] = lds[255];
#pragma unroll
  for (int q = 0; q < 4; ++q) {
    int i = base + tid * 4 + q;
    if (i < N) rowptr[i] = run;
    run += vals[q];
  }
}

__global__ void k_scan_bsum(int* __restrict__ bsum, int nb) {
  __shared__ int lds[1024];
  const int tid = threadIdx.x;
  int v = (tid < nb) ? bsum[tid] : 0;
  lds[tid] = v;
  __syncthreads();
  for (int off = 1; off < 1024; off <<= 1) {
    int t = (tid >= off) ? lds[tid - off] : 0;
    __syncthreads();
    lds[tid] += t;
    __syncthreads();
  }
  bsum[tid] = lds[tid] - v;
}

__global__ void k_scan_add(const int* __restrict__ bsum, int* __restrict__ rowptr,
                           int* __restrict__ cursor, int N, int total) {
  int i = blockIdx.x * blockDim.x + threadIdx.x;
  if (i < N) {
    int r = rowptr[i] + bsum[i >> 10];
    rowptr[i] = r;
    cursor[i] = r;
  } else if (i == N) {
    rowptr[N] = total;
  }
}

// XCD-partitioned CSR fill: part p = s*8 + (bid%8) handled only by blocks on
// that XCD (round-robin block->XCD), so each XCD's nbr writes confine to a
// ~425KB region that fits its private L2 -> write coalescing instead of
// one dirty 64B line per 4B store.
__global__ void k_build_part(const int* __restrict__ esrc, const int* __restrict__ edst,
                             int* __restrict__ cursor, int* __restrict__ nbr, int E, int N) {
  constexpr int NPARTS = 16;
  const int xcd = blockIdx.x & 7;
  const int span = (N + NPARTS - 1) / NPARTS;
  const int gid = (int)(blockIdx.x >> 3) * blockDim.x + threadIdx.x;
  const int stride = (int)(gridDim.x >> 3) * blockDim.x;
  const int E4 = E >> 2;
#pragma unroll
  for (int s = 0; s < NPARTS / 8; ++s) {
    const int p = s * 8 + xcd;
    const int lo = p * span;
    const int hi = min(N, lo + span);
    for (int i = gid; i < E4; i += stride) {
      const int4 d4 = ((const int4*)edst)[i];
      if (d4.x >= lo && d4.x < hi) nbr[atomicAdd(cursor + d4.x, 1)] = esrc[i * 4 + 0];
      if (d4.y >= lo && d4.y < hi) nbr[atomicAdd(cursor + d4.y, 1)] = esrc[i * 4 + 1];
      if (d4.z >= lo && d4.z < hi) nbr[atomicAdd(cursor + d4.z, 1)] = esrc[i * 4 + 2];
      if (d4.w >= lo && d4.w < hi) nbr[atomicAdd(cursor + d4.w, 1)] = esrc[i * 4 + 3];
    }
    for (int i = E4 * 4 + gid; i < E + N; i += stride) {
      const int d = i < E ? edst[i] : i - E;
      if (d >= lo && d < hi) {
        const int sn = i < E ? esrc[i] : i - E;
        nbr[atomicAdd(cursor + d, 1)] = sn;
      }
    }
  }
}

// ---------------- Gather layer 1: H=4, C=32, bf16 h, ELU ----------------
__global__ void k_gather_l1(const int* __restrict__ rowptr, const int* __restrict__ nbr,
                            const float* __restrict__ als, const float* __restrict__ ald,
                            const __hip_bfloat16* __restrict__ hfeat,
                            const float* __restrict__ bias,
                            float* __restrict__ out, int N) {
  __shared__ float alds[4][256];  // [wave][edge*4 + head]
  __shared__ int snlds[4][64];    // [wave][edge]
  const int lane = threadIdx.x & 63;
  const int wid = threadIdx.x >> 6;
  const int node = (int)((blockIdx.x * blockDim.x + threadIdx.x) >> 6);
  if (node >= N) return;
  const int start = rowptr[node], end = rowptr[node + 1];
  const int deg = end - start;
  const float4 aldd = ((const float4*)ald)[node];

  float t[4];
  int myn = 0;
  {
    const int j = start + lane;
    if (j < end) {
      myn = nbr[j];
      const float4 av = ((const float4*)als)[myn];
      const float tr[4] = {av.x + aldd.x, av.y + aldd.y, av.z + aldd.z, av.w + aldd.w};
#pragma unroll
      for (int h = 0; h < 4; ++h) t[h] = tr[h] >= 0.f ? tr[h] : NEG_SLOPE * tr[h];
    } else {
#pragma unroll
      for (int h = 0; h < 4; ++h) t[h] = NEG_BIG;
    }
  }
  snlds[wid][lane] = myn;

  float Mh[4], rden[4], myex[4];
  if (deg <= 64) {
#pragma unroll
    for (int h = 0; h < 4; ++h) {
      float M = t[h];
#pragma unroll
      for (int off = 1; off < 64; off <<= 1) M = fmaxf(M, __shfl_xor(M, off, 64));
      const float e = __expf(t[h] - M);
      float sum = e;
#pragma unroll
      for (int off = 1; off < 64; off <<= 1) sum += __shfl_xor(sum, off, 64);
      Mh[h] = M;
      rden[h] = 1.f / sum;
      myex[h] = e * rden[h];
    }
  } else {
    float m[4], s[4];
#pragma unroll
    for (int h = 0; h < 4; ++h) { m[h] = t[h]; s[h] = 1.f; }
    for (int base = start + 64; base < end; base += 64) {
      const int j = base + lane;
      if (j < end) {
        const int sn = nbr[j];
        const float4 av = ((const float4*)als)[sn];
        const float tr[4] = {av.x + aldd.x, av.y + aldd.y, av.z + aldd.z, av.w + aldd.w};
#pragma unroll
        for (int h = 0; h < 4; ++h) {
          const float tv = tr[h] >= 0.f ? tr[h] : NEG_SLOPE * tr[h];
          const float M = fmaxf(m[h], tv);
          s[h] = s[h] * __expf(m[h] - M) + __expf(tv - M);
          m[h] = M;
        }
      }
    }
#pragma unroll
    for (int h = 0; h < 4; ++h) {
      float M = m[h];
#pragma unroll
      for (int off = 1; off < 64; off <<= 1) M = fmaxf(M, __shfl_xor(M, off, 64));
      float e = s[h] * __expf(m[h] - M);
#pragma unroll
      for (int off = 1; off < 64; off <<= 1) e += __shfl_xor(e, off, 64);
      Mh[h] = M;
      rden[h] = 1.f / e;
      myex[h] = __expf(t[h] - M) * rden[h];
    }
  }
  ((float4*)&alds[wid][0])[lane] = make_float4(myex[0], myex[1], myex[2], myex[3]);

  const int sub = lane >> 4;
  const int q = lane & 15;
  const int head = q >> 2;
  float acc[8];
#pragma unroll
  for (int k = 0; k < 8; ++k) acc[k] = 0.f;

  const int nq = deg < 64 ? deg : 64;
  for (int j0 = 0; j0 < nq; j0 += 4) {
    const int j = j0 + sub;
    const int sn = snlds[wid][j];
    const float a = alds[wid][j * 4 + head];
    const uint4 v = *(const uint4*)((const unsigned short*)hfeat + (size_t)sn * 128 + q * 8);
    acc[0] = fmaf(blo(v.x), a, acc[0]);
    acc[1] = fmaf(bhi(v.x), a, acc[1]);
    acc[2] = fmaf(blo(v.y), a, acc[2]);
    acc[3] = fmaf(bhi(v.y), a, acc[3]);
    acc[4] = fmaf(blo(v.z), a, acc[4]);
    acc[5] = fmaf(bhi(v.z), a, acc[5]);
    acc[6] = fmaf(blo(v.w), a, acc[6]);
    acc[7] = fmaf(bhi(v.w), a, acc[7]);
  }
  if (deg > 64) {
    const float Mm = head == 0 ? Mh[0] : head == 1 ? Mh[1] : head == 2 ? Mh[2] : Mh[3];
    const float rd = head == 0 ? rden[0] : head == 1 ? rden[1] : head == 2 ? rden[2] : rden[3];
    const float ad_ = head == 0 ? aldd.x : head == 1 ? aldd.y : head == 2 ? aldd.z : aldd.w;
    for (int j0 = 64; j0 < deg; j0 += 4) {
      const int j = j0 + sub;
      float a = 0.f;
      int sn = 0;
      if (j < deg) {
        sn = nbr[start + j];
        const float4 av = ((const float4*)als)[sn];
        const float as_ = head == 0 ? av.x : head == 1 ? av.y : head == 2 ? av.z : av.w;
        float tv = as_ + ad_;
        tv = tv >= 0.f ? tv : NEG_SLOPE * tv;
        a = __expf(tv - Mm) * rd;
      }
      const uint4 v = *(const uint4*)((const unsigned short*)hfeat + (size_t)sn * 128 + q * 8);
      acc[0] = fmaf(blo(v.x), a, acc[0]);
      acc[1] = fmaf(bhi(v.x), a, acc[1]);
      acc[2] = fmaf(blo(v.y), a, acc[2]);
      acc[3] = fmaf(bhi(v.y), a, acc[3]);
      acc[4] = fmaf(blo(v.z), a, acc[4]);
      acc[5] = fmaf(bhi(v.z), a, acc[5]);
      acc[6] = fmaf(blo(v.w), a, acc[6]);
      acc[7] = fmaf(bhi(v.w), a, acc[7]);
    }
  }

#pragma unroll
  for (int k = 0; k < 8; ++k) {
    acc[k] += __shfl_xor(acc[k], 16, 64);
    acc[k] += __shfl_xor(acc[k], 32, 64);
  }
  if (lane < 16) {
    const float4 b0 = ((const float4*)bias)[lane * 2];
    const float4 b1 = ((const float4*)bias)[lane * 2 + 1];
    float r[8] = {acc[0] + b0.x, acc[1] + b0.y, acc[2] + b0.z, acc[3] + b0.w,
                  acc[4] + b1.x, acc[5] + b1.y, acc[6] + b1.z, acc[7] + b1.w};
#pragma unroll
    for (int k = 0; k < 8; ++k) r[k] = r[k] > 0.f ? r[k] : __expf(r[k]) - 1.f;
    float4* op = (float4*)(out + (size_t)node * 128 + lane * 8);
    op[0] = make_float4(r[0], r[1], r[2], r[3]);
    op[1] = make_float4(r[4], r[5], r[6], r[7]);
  }
}

// ---------------- Gather layer 2: H=1, C=64, bf16 h, no ELU ----------------
__global__ void k_gather_l2(const int* __restrict__ rowptr, const int* __restrict__ nbr,
                            const float* __restrict__ als, const float* __restrict__ ald,
                            const __hip_bfloat16* __restrict__ hfeat,
                            const float* __restrict__ bias,
                            float* __restrict__ out, int N) {
  __shared__ float alds[4][64];
  __shared__ int snlds[4][64];
  const int lane = threadIdx.x & 63;
  const int wid = threadIdx.x >> 6;
  const int node = (int)((blockIdx.x * blockDim.x + threadIdx.x) >> 6);
  if (node >= N) return;
  const int start = rowptr[node], end = rowptr[node + 1];
  const int deg = end - start;
  const float ald0 = ald[node];

  float t = NEG_BIG;
  int myn = 0;
  {
    const int j = start + lane;
    if (j < end) {
      myn = nbr[j];
      float tv = als[myn] + ald0;
      t = tv >= 0.f ? tv : NEG_SLOPE * tv;
    }
  }
  snlds[wid][lane] = myn;

  float M, rden;
  if (deg <= 64) {
    M = t;
#pragma unroll
    for (int off = 1; off < 64; off <<= 1) M = fmaxf(M, __shfl_xor(M, off, 64));
    const float e = __expf(t - M);
    float sum = e;
#pragma unroll
    for (int off = 1; off < 64; off <<= 1) sum += __shfl_xor(sum, off, 64);
    rden = 1.f / sum;
    alds[wid][lane] = e * rden;
  } else {
    float m = t, s = 1.f;
    for (int base = start + 64; base < end; base += 64) {
      const int j = base + lane;
      if (j < end) {
        float tv = als[nbr[j]] + ald0;
        tv = tv >= 0.f ? tv : NEG_SLOPE * tv;
        const float Mn = fmaxf(m, tv);
        s = s * __expf(m - Mn) + __expf(tv - Mn);
        m = Mn;
      }
    }
    M = m;
#pragma unroll
    for (int off = 1; off < 64; off <<= 1) M = fmaxf(M, __shfl_xor(M, off, 64));
    float e = s * __expf(m - M);
#pragma unroll
    for (int off = 1; off < 64; off <<= 1) e += __shfl_xor(e, off, 64);
    rden = 1.f / e;
    alds[wid][lane] = __expf(t - M) * rden;
  }

  const int sub = lane >> 3;
  const int q = lane & 7;
  float acc[8];
#pragma unroll
  for (int k = 0; k < 8; ++k) acc[k] = 0.f;

  const int nq = deg < 64 ? deg : 64;
  for (int j0 = 0; j0 < nq; j0 += 8) {
    const int j = j0 + sub;
    const int sn = snlds[wid][j];
    const float a = alds[wid][j];
    const uint4 v = *(const uint4*)((const unsigned short*)hfeat + (size_t)sn * 64 + q * 8);
    acc[0] = fmaf(blo(v.x), a, acc[0]);
    acc[1] = fmaf(bhi(v.x), a, acc[1]);
    acc[2] = fmaf(blo(v.y), a, acc[2]);
    acc[3] = fmaf(bhi(v.y), a, acc[3]);
    acc[4] = fmaf(blo(v.z), a, acc[4]);
    acc[5] = fmaf(bhi(v.z), a, acc[5]);
    acc[6] = fmaf(blo(v.w), a, acc[6]);
    acc[7] = fmaf(bhi(v.w), a, acc[7]);
  }
  if (deg > 64) {
    for (int j0 = 64; j0 < deg; j0 += 8) {
      const int j = j0 + sub;
      float a = 0.f;
      int sn = 0;
      if (j < deg) {
        sn = nbr[start + j];
        float tv = als[sn] + ald0;
        tv = tv >= 0.f ? tv : NEG_SLOPE * tv;
        a = __expf(tv - M) * rden;
      }
      const uint4 v = *(const uint4*)((const unsigned short*)hfeat + (size_t)sn * 64 + q * 8);
      acc[0] = fmaf(blo(v.x), a, acc[0]);
      acc[1] = fmaf(bhi(v.x), a, acc[1]);
      acc[2] = fmaf(blo(v.y), a, acc[2]);
      acc[3] = fmaf(bhi(v.y), a, acc[3]);
      acc[4] = fmaf(blo(v.z), a, acc[4]);
      acc[5] = fmaf(bhi(v.z), a, acc[5]);
      acc[6] = fmaf(blo(v.w), a, acc[6]);
      acc[7] = fmaf(bhi(v.w), a, acc[7]);
    }
  }

#pragma unroll
  for (int k = 0; k < 8; ++k) {
    acc[k] += __shfl_xor(acc[k], 8, 64);
    acc[k] += __shfl_xor(acc[k], 16, 64);
    acc[k] += __shfl_xor(acc[k], 32, 64);
  }
  if (lane < 8) {
    const float4 b0 = ((const float4*)bias)[lane * 2];
    const float4 b1 = ((const float4*)bias)[lane * 2 + 1];
    float4* op = (float4*)(out + (size_t)node * 64 + lane * 8);
    op[0] = make_float4(acc[0] + b0.x, acc[1] + b0.y, acc[2] + b0.z, acc[3] + b0.w);
    op[1] = make_float4(acc[4] + b1.x, acc[5] + b1.y, acc[6] + b1.z, acc[7] + b1.w);
  }
}

extern "C" void kernel_launch(void* const* d_in, const int* in_sizes, int n_in,
                              void* d_out, int out_size, void* d_ws, size_t ws_size,
                              hipStream_t stream) {
  const float* x   = (const float*)d_in[0];
  const int*   ei  = (const int*)d_in[1];
  const float* W1  = (const float*)d_in[2];
  const float* a1s = (const float*)d_in[3];
  const float* a1d = (const float*)d_in[4];
  const float* b1  = (const float*)d_in[5];
  const float* W2  = (const float*)d_in[6];
  const float* a2s = (const float*)d_in[7];
  const float* a2d = (const float*)d_in[8];
  const float* b2  = (const float*)d_in[9];

  const int N = in_sizes[0] / 128;  // 100000
  const int E = in_sizes[1] / 2;    // 1600000
  const int* esrc = ei;
  const int* edst = ei + E;

  float* ws   = (float*)d_ws;
  __hip_bfloat16* h = (__hip_bfloat16*)ws;   // N*128 bf16 (slot sized N*128 f32)
  float* out1 = ws   + (size_t)N * 128;      // N*128 f32
  float* als  = out1 + (size_t)N * 128;      // N*4
  float* ald  = als  + (size_t)N * 4;        // N*4
  int* cnt    = (int*)(ald + (size_t)N * 4); // N
  int* rowptr = cnt + N;                     // N+1
  int* cursor = rowptr + N + 1;              // N
  int* bsum   = cursor + N;                  // 1024
  int* nbr    = bsum + 1024;                 // E+N

  float* outF = (float*)d_out;               // N*64

  const int total = E + N;
  const int nb = (N + 1023) / 1024;

  // ---- CSR build (shared by both layers) ----
  k_fill1<<<(N + 255) / 256, 256, 0, stream>>>(cnt, N);
  k_count<<<(E + 255) / 256, 256, 0, stream>>>(edst, cnt, E);
  k_scan_local<<<nb, 256, 0, stream>>>(cnt, rowptr, bsum, N);
  k_scan_bsum<<<1, 1024, 0, stream>>>(bsum, nb);
  k_scan_add<<<(N + 256) / 256, 256, 0, stream>>>(bsum, rowptr, cursor, N, total);
  k_build_part<<<1280, 256, 0, stream>>>(esrc, edst, cursor, nbr, E, N);

  // ---- Layer 1: H=4, C=32, concat -> [N,128], +b1, ELU ----
  k_gemm_attn_v3<128, 128, 16, 16, 4><<<(N + 127) / 128, 256, 0, stream>>>(
      x, W1, a1s, a1d, h, als, ald, N);
  k_gather_l1<<<(N + 3) / 4, 256, 0, stream>>>(rowptr, nbr, als, ald, h, b1, out1, N);

  // ---- Layer 2: H=1, C=64, mean(H=1) -> [N,64], +b2 ----
  k_gemm_attn_v3<128, 64, 8, 16, 1><<<(N + 127) / 128, 128, 0, stream>>>(
      out1, W2, a2s, a2d, h, als, ald, N);
  k_gather_l2<<<(N + 3) / 4, 256, 0, stream>>>(rowptr, nbr, als, ald, h, b2, outF, N);
}

// Round 8
// 362.899 us; speedup vs baseline: 5.0626x; 1.2257x over previous
//
#include <hip/hip_runtime.h>
#include <hip/hip_bf16.h>
#include <math.h>

static constexpr float NEG_SLOPE = 0.2f;
static constexpr float NEG_BIG = -3.0e38f;  // finite sentinel: avoids (-inf)-(-inf)=NaN

typedef __attribute__((ext_vector_type(8))) short short8;  // 8 bf16 (4 VGPRs)
typedef __attribute__((ext_vector_type(4))) float f32x4;

__device__ __forceinline__ float blo(unsigned u) { return __uint_as_float(u << 16); }
__device__ __forceinline__ float bhi(unsigned u) { return __uint_as_float(u & 0xffff0000u); }
__device__ __forceinline__ unsigned pack2(float a, float b) {
  __hip_bfloat162 t = __float22bfloat162_rn(make_float2(a, b));
  union { __hip_bfloat162 b; unsigned u; } v;
  v.b = t;
  return v.u;  // low 16 bits = bf16(a), high = bf16(b)
}

// ---- W prep: fp32 [k][col] -> bf16 swizzled [col][k] image of the GEMM's LDS ----
// LDS uint4 slot for (col, chunk8k) = col*16 + (chunk ^ (col&7)); here we emit the
// linear image so the GEMM can do a straight uint4 copy.
__global__ void k_prep_w(const float* __restrict__ W, uint4* __restrict__ out, int BN) {
  const int i = blockIdx.x * blockDim.x + threadIdx.x;
  if (i >= BN * 16) return;
  const int col = i >> 4;
  const int chunk = (i & 15) ^ (col & 7);
  const float* wp = W + (size_t)chunk * 8 * BN + col;  // W[k=chunk*8][col]
  uint4 u;
  u.x = pack2(wp[0 * BN], wp[1 * BN]);
  u.y = pack2(wp[2 * BN], wp[3 * BN]);
  u.z = pack2(wp[4 * BN], wp[5 * BN]);
  u.w = pack2(wp[6 * BN], wp[7 * BN]);
  out[i] = u;
}

// ---- MFMA GEMM + logits: h = x@W (bf16 in, fp32 acc, bf16 out), als/ald fp32 ----
// 256 thr = 4 waves; block covers 128 rows; wave w: rows w*32..w*32+31 (2 tiles).
// 16x16x32 bf16 MFMA; frag = 8 consecutive k per lane (lane&15 = row/col,
// lane>>4 = k-group); C/D: col=lane&15, row=(lane>>4)*4+reg.
template <int BN, int HEADS>
__global__ __launch_bounds__(256) void k_mfma_gemm(
    const float* __restrict__ x, const uint4* __restrict__ wsw,
    const float* __restrict__ a_src, const float* __restrict__ a_dst,
    __hip_bfloat16* __restrict__ h_out, float* __restrict__ als,
    float* __restrict__ ald, int N) {
  constexpr int NTILES = BN / 16;
  __shared__ unsigned char Xl[128 * 256];  // 128 rows x 128 bf16 (k), XOR-swizzled
  __shared__ unsigned char Wl[BN * 256];   // BN cols x 128 bf16 (k), XOR-swizzled
  const int tid = threadIdx.x;
  const int lane = tid & 63;
  const int wid = tid >> 6;
  const int base = blockIdx.x * 128;

  // stage W: linear copy of pre-swizzled image
  {
    uint4* dst = (uint4*)Wl;
    for (int i = tid; i < BN * 16; i += 256) dst[i] = wsw[i];
  }
  // stage X: coalesced fp32 reads (16 lanes = one row), bf16 swizzled writes
  for (int it = 0; it < 8; ++it) {
    const int i = it * 256 + tid;
    const int r = i >> 4, c = i & 15;  // row-in-block, 16B chunk (8 k's)
    const int g = base + r;
    float4 f0 = make_float4(0.f, 0.f, 0.f, 0.f), f1 = f0;
    if (g < N) {
      const float* xp = x + (size_t)g * 128 + c * 8;
      f0 = *(const float4*)xp;
      f1 = *(const float4*)(xp + 4);
    }
    uint4 u;
    u.x = pack2(f0.x, f0.y);
    u.y = pack2(f0.z, f0.w);
    u.z = pack2(f1.x, f1.y);
    u.w = pack2(f1.z, f1.w);
    *(uint4*)(Xl + r * 256 + ((c * 16) ^ ((r & 7) << 4))) = u;
  }
  __syncthreads();

  const int lg = lane >> 4;  // k-group / row-group
  const int ll = lane & 15;  // row / col within tile

  union U { uint4 u; short8 s; };
  short8 afr[2][4];
#pragma unroll
  for (int rt = 0; rt < 2; ++rt) {
    const int row = wid * 32 + rt * 16 + ll;
    const unsigned char* rp = Xl + row * 256;
    const int swz = (row & 7) << 4;
#pragma unroll
    for (int ks = 0; ks < 4; ++ks) {
      U t;
      t.u = *(const uint4*)(rp + ((ks * 64 + lg * 16) ^ swz));
      afr[rt][ks] = t.s;
    }
  }

  f32x4 acc[2][NTILES];
#pragma unroll
  for (int rt = 0; rt < 2; ++rt)
#pragma unroll
    for (int t = 0; t < NTILES; ++t) acc[rt][t] = (f32x4){0.f, 0.f, 0.f, 0.f};

#pragma unroll
  for (int t = 0; t < NTILES; ++t) {
    const int col = t * 16 + ll;
    const unsigned char* cp = Wl + col * 256;
    const int swz = (col & 7) << 4;
#pragma unroll
    for (int ks = 0; ks < 4; ++ks) {
      U b;
      b.u = *(const uint4*)(cp + ((ks * 64 + lg * 16) ^ swz));
      acc[0][t] = __builtin_amdgcn_mfma_f32_16x16x32_bf16(afr[0][ks], b.s, acc[0][t], 0, 0, 0);
      acc[1][t] = __builtin_amdgcn_mfma_f32_16x16x32_bf16(afr[1][ks], b.s, acc[1][t], 0, 0, 0);
    }
  }

  // ---- logits from fp32 accumulators ----
  float asv[NTILES], adv[NTILES];
#pragma unroll
  for (int t = 0; t < NTILES; ++t) {
    asv[t] = a_src[t * 16 + ll];
    adv[t] = a_dst[t * 16 + ll];
  }
#pragma unroll
  for (int rt = 0; rt < 2; ++rt) {
#pragma unroll
    for (int r = 0; r < 4; ++r) {
      const int row = base + wid * 32 + rt * 16 + lg * 4 + r;
      if (HEADS == 4) {
        float ps[4], pd[4];
#pragma unroll
        for (int h = 0; h < 4; ++h) {
          ps[h] = acc[rt][2 * h][r] * asv[2 * h] + acc[rt][2 * h + 1][r] * asv[2 * h + 1];
          pd[h] = acc[rt][2 * h][r] * adv[2 * h] + acc[rt][2 * h + 1][r] * adv[2 * h + 1];
#pragma unroll
          for (int off = 1; off < 16; off <<= 1) {
            ps[h] += __shfl_xor(ps[h], off, 64);
            pd[h] += __shfl_xor(pd[h], off, 64);
          }
        }
        if (ll == 0 && row < N) {
          ((float4*)als)[row] = make_float4(ps[0], ps[1], ps[2], ps[3]);
          ((float4*)ald)[row] = make_float4(pd[0], pd[1], pd[2], pd[3]);
        }
      } else {
        float ps = 0.f, pd = 0.f;
#pragma unroll
        for (int t = 0; t < NTILES; ++t) {
          ps = fmaf(acc[rt][t][r], asv[t], ps);
          pd = fmaf(acc[rt][t][r], adv[t], pd);
        }
#pragma unroll
        for (int off = 1; off < 16; off <<= 1) {
          ps += __shfl_xor(ps, off, 64);
          pd += __shfl_xor(pd, off, 64);
        }
        if (ll == 0 && row < N) {
          als[row] = ps;
          ald[row] = pd;
        }
      }
    }
  }

  // ---- h store: D -> LDS (bf16, linear [row][col]) -> coalesced global uint4 ----
  __syncthreads();  // done reading Xl
#pragma unroll
  for (int rt = 0; rt < 2; ++rt) {
#pragma unroll
    for (int t = 0; t < NTILES; ++t) {
#pragma unroll
      for (int r = 0; r < 4; ++r) {
        const float v = acc[rt][t][r];
        const float vn = __shfl_xor(v, 1, 64);
        if (!(lane & 1)) {
          const int row = wid * 32 + rt * 16 + lg * 4 + r;
          *(unsigned*)(Xl + row * (BN * 2) + (t * 16 + ll) * 2) = pack2(v, vn);
        }
      }
    }
  }
  __syncthreads();
  {
    constexpr int U4 = 128 * BN / 8;  // uint4 slots (BN*2 bytes per row / 16)
    constexpr int U4R = BN / 8;       // uint4 per row
    for (int i = tid; i < U4; i += 256) {
      const int row = i / U4R;
      const int g = base + row;
      if (g < N)
        *(uint4*)((unsigned short*)h_out + (size_t)g * BN + (i % U4R) * 8) = ((uint4*)Xl)[i];
    }
  }
}

// ---------------- CSR build (counting sort by dst) ----------------
__global__ void k_fill1(int* __restrict__ cnt, int N) {
  int i = blockIdx.x * blockDim.x + threadIdx.x;
  if (i < N) cnt[i] = 1;
}

__global__ void k_count(const int* __restrict__ edst, int* __restrict__ cnt, int E) {
  int i = blockIdx.x * blockDim.x + threadIdx.x;
  if (i < E) atomicAdd(cnt + edst[i], 1);
}

__global__ void k_scan_local(const int* __restrict__ cnt, int* __restrict__ rowptr,
                             int* __restrict__ bsum, int N) {
  __shared__ int lds[256];
  const int tid = threadIdx.x;
  const int base = blockIdx.x * 1024;
  int vals[4], tsum = 0;
#pragma unroll
  for (int q = 0; q < 4; ++q) {
    int i = base + tid * 4 + q;
    vals[q] = (i < N) ? cnt[i] : 0;
    tsum += vals[q];
  }
  lds[tid] = tsum;
  __syncthreads();
  for (int off = 1; off < 256; off <<= 1) {
    int t = (tid >= off) ? lds[tid - off] : 0;
    __syncthreads();
    lds[tid] += t;
    __syncthreads();
  }
  int run = lds[tid] - tsum;
  if (tid == 255) bsum[blockIdx.x] = lds[255];
#pragma unroll
  for (int q = 0; q < 4; ++q) {
    int i = base + tid * 4 + q;
    if (i < N) rowptr[i] = run;
    run += vals[q];
  }
}

__global__ void k_scan_bsum(int* __restrict__ bsum, int nb) {
  __shared__ int lds[1024];
  const int tid = threadIdx.x;
  int v = (tid < nb) ? bsum[tid] : 0;
  lds[tid] = v;
  __syncthreads();
  for (int off = 1; off < 1024; off <<= 1) {
    int t = (tid >= off) ? lds[tid - off] : 0;
    __syncthreads();
    lds[tid] += t;
    __syncthreads();
  }
  bsum[tid] = lds[tid] - v;
}

__global__ void k_scan_add(const int* __restrict__ bsum, int* __restrict__ rowptr,
                           int* __restrict__ cursor, int N, int total) {
  int i = blockIdx.x * blockDim.x + threadIdx.x;
  if (i < N) {
    int r = rowptr[i] + bsum[i >> 10];
    rowptr[i] = r;
    cursor[i] = r;
  } else if (i == N) {
    rowptr[N] = total;
  }
}

// XCD-partitioned CSR fill (writes confined per-XCD-L2 region)
__global__ void k_build_part(const int* __restrict__ esrc, const int* __restrict__ edst,
                             int* __restrict__ cursor, int* __restrict__ nbr, int E, int N) {
  constexpr int NPARTS = 16;
  const int xcd = blockIdx.x & 7;
  const int span = (N + NPARTS - 1) / NPARTS;
  const int gid = (int)(blockIdx.x >> 3) * blockDim.x + threadIdx.x;
  const int stride = (int)(gridDim.x >> 3) * blockDim.x;
  const int E4 = E >> 2;
#pragma unroll
  for (int s = 0; s < NPARTS / 8; ++s) {
    const int p = s * 8 + xcd;
    const int lo = p * span;
    const int hi = min(N, lo + span);
    for (int i = gid; i < E4; i += stride) {
      const int4 d4 = ((const int4*)edst)[i];
      if (d4.x >= lo && d4.x < hi) nbr[atomicAdd(cursor + d4.x, 1)] = esrc[i * 4 + 0];
      if (d4.y >= lo && d4.y < hi) nbr[atomicAdd(cursor + d4.y, 1)] = esrc[i * 4 + 1];
      if (d4.z >= lo && d4.z < hi) nbr[atomicAdd(cursor + d4.z, 1)] = esrc[i * 4 + 2];
      if (d4.w >= lo && d4.w < hi) nbr[atomicAdd(cursor + d4.w, 1)] = esrc[i * 4 + 3];
    }
    for (int i = E4 * 4 + gid; i < E + N; i += stride) {
      const int d = i < E ? edst[i] : i - E;
      if (d >= lo && d < hi) {
        const int sn = i < E ? esrc[i] : i - E;
        nbr[atomicAdd(cursor + d, 1)] = sn;
      }
    }
  }
}

// ---------------- Gather layer 1: H=4, C=32, bf16 h, ELU ----------------
__global__ void k_gather_l1(const int* __restrict__ rowptr, const int* __restrict__ nbr,
                            const float* __restrict__ als, const float* __restrict__ ald,
                            const __hip_bfloat16* __restrict__ hfeat,
                            const float* __restrict__ bias,
                            float* __restrict__ out, int N) {
  __shared__ float alds[4][256];
  __shared__ int snlds[4][64];
  const int lane = threadIdx.x & 63;
  const int wid = threadIdx.x >> 6;
  const int node = (int)((blockIdx.x * blockDim.x + threadIdx.x) >> 6);
  if (node >= N) return;
  const int start = rowptr[node], end = rowptr[node + 1];
  const int deg = end - start;
  const float4 aldd = ((const float4*)ald)[node];

  float t[4];
  int myn = 0;
  {
    const int j = start + lane;
    if (j < end) {
      myn = nbr[j];
      const float4 av = ((const float4*)als)[myn];
      const float tr[4] = {av.x + aldd.x, av.y + aldd.y, av.z + aldd.z, av.w + aldd.w};
#pragma unroll
      for (int h = 0; h < 4; ++h) t[h] = tr[h] >= 0.f ? tr[h] : NEG_SLOPE * tr[h];
    } else {
#pragma unroll
      for (int h = 0; h < 4; ++h) t[h] = NEG_BIG;
    }
  }
  snlds[wid][lane] = myn;

  float Mh[4], rden[4], myex[4];
  if (deg <= 64) {
#pragma unroll
    for (int h = 0; h < 4; ++h) {
      float M = t[h];
#pragma unroll
      for (int off = 1; off < 64; off <<= 1) M = fmaxf(M, __shfl_xor(M, off, 64));
      const float e = __expf(t[h] - M);
      float sum = e;
#pragma unroll
      for (int off = 1; off < 64; off <<= 1) sum += __shfl_xor(sum, off, 64);
      Mh[h] = M;
      rden[h] = 1.f / sum;
      myex[h] = e * rden[h];
    }
  } else {
    float m[4], s[4];
#pragma unroll
    for (int h = 0; h < 4; ++h) { m[h] = t[h]; s[h] = 1.f; }
    for (int base = start + 64; base < end; base += 64) {
      const int j = base + lane;
      if (j < end) {
        const int sn = nbr[j];
        const float4 av = ((const float4*)als)[sn];
        const float tr[4] = {av.x + aldd.x, av.y + aldd.y, av.z + aldd.z, av.w + aldd.w};
#pragma unroll
        for (int h = 0; h < 4; ++h) {
          const float tv = tr[h] >= 0.f ? tr[h] : NEG_SLOPE * tr[h];
          const float M = fmaxf(m[h], tv);
          s[h] = s[h] * __expf(m[h] - M) + __expf(tv - M);
          m[h] = M;
        }
      }
    }
#pragma unroll
    for (int h = 0; h < 4; ++h) {
      float M = m[h];
#pragma unroll
      for (int off = 1; off < 64; off <<= 1) M = fmaxf(M, __shfl_xor(M, off, 64));
      float e = s[h] * __expf(m[h] - M);
#pragma unroll
      for (int off = 1; off < 64; off <<= 1) e += __shfl_xor(e, off, 64);
      Mh[h] = M;
      rden[h] = 1.f / e;
      myex[h] = __expf(t[h] - M) * rden[h];
    }
  }
  ((float4*)&alds[wid][0])[lane] = make_float4(myex[0], myex[1], myex[2], myex[3]);

  const int sub = lane >> 4;
  const int q = lane & 15;
  const int head = q >> 2;
  float acc[8];
#pragma unroll
  for (int k = 0; k < 8; ++k) acc[k] = 0.f;

  const int nq = deg < 64 ? deg : 64;
  for (int j0 = 0; j0 < nq; j0 += 4) {
    const int j = j0 + sub;
    const int sn = snlds[wid][j];
    const float a = alds[wid][j * 4 + head];
    const uint4 v = *(const uint4*)((const unsigned short*)hfeat + (size_t)sn * 128 + q * 8);
    acc[0] = fmaf(blo(v.x), a, acc[0]);
    acc[1] = fmaf(bhi(v.x), a, acc[1]);
    acc[2] = fmaf(blo(v.y), a, acc[2]);
    acc[3] = fmaf(bhi(v.y), a, acc[3]);
    acc[4] = fmaf(blo(v.z), a, acc[4]);
    acc[5] = fmaf(bhi(v.z), a, acc[5]);
    acc[6] = fmaf(blo(v.w), a, acc[6]);
    acc[7] = fmaf(bhi(v.w), a, acc[7]);
  }
  if (deg > 64) {
    const float Mm = head == 0 ? Mh[0] : head == 1 ? Mh[1] : head == 2 ? Mh[2] : Mh[3];
    const float rd = head == 0 ? rden[0] : head == 1 ? rden[1] : head == 2 ? rden[2] : rden[3];
    const float ad_ = head == 0 ? aldd.x : head == 1 ? aldd.y : head == 2 ? aldd.z : aldd.w;
    for (int j0 = 64; j0 < deg; j0 += 4) {
      const int j = j0 + sub;
      float a = 0.f;
      int sn = 0;
      if (j < deg) {
        sn = nbr[start + j];
        const float4 av = ((const float4*)als)[sn];
        const float as_ = head == 0 ? av.x : head == 1 ? av.y : head == 2 ? av.z : av.w;
        float tv = as_ + ad_;
        tv = tv >= 0.f ? tv : NEG_SLOPE * tv;
        a = __expf(tv - Mm) * rd;
      }
      const uint4 v = *(const uint4*)((const unsigned short*)hfeat + (size_t)sn * 128 + q * 8);
      acc[0] = fmaf(blo(v.x), a, acc[0]);
      acc[1] = fmaf(bhi(v.x), a, acc[1]);
      acc[2] = fmaf(blo(v.y), a, acc[2]);
      acc[3] = fmaf(bhi(v.y), a, acc[3]);
      acc[4] = fmaf(blo(v.z), a, acc[4]);
      acc[5] = fmaf(bhi(v.z), a, acc[5]);
      acc[6] = fmaf(blo(v.w), a, acc[6]);
      acc[7] = fmaf(bhi(v.w), a, acc[7]);
    }
  }

#pragma unroll
  for (int k = 0; k < 8; ++k) {
    acc[k] += __shfl_xor(acc[k], 16, 64);
    acc[k] += __shfl_xor(acc[k], 32, 64);
  }
  if (lane < 16) {
    const float4 b0 = ((const float4*)bias)[lane * 2];
    const float4 b1 = ((const float4*)bias)[lane * 2 + 1];
    float r[8] = {acc[0] + b0.x, acc[1] + b0.y, acc[2] + b0.z, acc[3] + b0.w,
                  acc[4] + b1.x, acc[5] + b1.y, acc[6] + b1.z, acc[7] + b1.w};
#pragma unroll
    for (int k = 0; k < 8; ++k) r[k] = r[k] > 0.f ? r[k] : __expf(r[k]) - 1.f;
    float4* op = (float4*)(out + (size_t)node * 128 + lane * 8);
    op[0] = make_float4(r[0], r[1], r[2], r[3]);
    op[1] = make_float4(r[4], r[5], r[6], r[7]);
  }
}

// ---------------- Gather layer 2: H=1, C=64, bf16 h, no ELU ----------------
__global__ void k_gather_l2(const int* __restrict__ rowptr, const int* __restrict__ nbr,
                            const float* __restrict__ als, const float* __restrict__ ald,
                            const __hip_bfloat16* __restrict__ hfeat,
                            const float* __restrict__ bias,
                            float* __restrict__ out, int N) {
  __shared__ float alds[4][64];
  __shared__ int snlds[4][64];
  const int lane = threadIdx.x & 63;
  const int wid = threadIdx.x >> 6;
  const int node = (int)((blockIdx.x * blockDim.x + threadIdx.x) >> 6);
  if (node >= N) return;
  const int start = rowptr[node], end = rowptr[node + 1];
  const int deg = end - start;
  const float ald0 = ald[node];

  float t = NEG_BIG;
  int myn = 0;
  {
    const int j = start + lane;
    if (j < end) {
      myn = nbr[j];
      float tv = als[myn] + ald0;
      t = tv >= 0.f ? tv : NEG_SLOPE * tv;
    }
  }
  snlds[wid][lane] = myn;

  float M, rden;
  if (deg <= 64) {
    M = t;
#pragma unroll
    for (int off = 1; off < 64; off <<= 1) M = fmaxf(M, __shfl_xor(M, off, 64));
    const float e = __expf(t - M);
    float sum = e;
#pragma unroll
    for (int off = 1; off < 64; off <<= 1) sum += __shfl_xor(sum, off, 64);
    rden = 1.f / sum;
    alds[wid][lane] = e * rden;
  } else {
    float m = t, s = 1.f;
    for (int base = start + 64; base < end; base += 64) {
      const int j = base + lane;
      if (j < end) {
        float tv = als[nbr[j]] + ald0;
        tv = tv >= 0.f ? tv : NEG_SLOPE * tv;
        const float Mn = fmaxf(m, tv);
        s = s * __expf(m - Mn) + __expf(tv - Mn);
        m = Mn;
      }
    }
    M = m;
#pragma unroll
    for (int off = 1; off < 64; off <<= 1) M = fmaxf(M, __shfl_xor(M, off, 64));
    float e = s * __expf(m - M);
#pragma unroll
    for (int off = 1; off < 64; off <<= 1) e += __shfl_xor(e, off, 64);
    rden = 1.f / e;
    alds[wid][lane] = __expf(t - M) * rden;
  }

  const int sub = lane >> 3;
  const int q = lane & 7;
  float acc[8];
#pragma unroll
  for (int k = 0; k < 8; ++k) acc[k] = 0.f;

  const int nq = deg < 64 ? deg : 64;
  for (int j0 = 0; j0 < nq; j0 += 8) {
    const int j = j0 + sub;
    const int sn = snlds[wid][j];
    const float a = alds[wid][j];
    const uint4 v = *(const uint4*)((const unsigned short*)hfeat + (size_t)sn * 64 + q * 8);
    acc[0] = fmaf(blo(v.x), a, acc[0]);
    acc[1] = fmaf(bhi(v.x), a, acc[1]);
    acc[2] = fmaf(blo(v.y), a, acc[2]);
    acc[3] = fmaf(bhi(v.y), a, acc[3]);
    acc[4] = fmaf(blo(v.z), a, acc[4]);
    acc[5] = fmaf(bhi(v.z), a, acc[5]);
    acc[6] = fmaf(blo(v.w), a, acc[6]);
    acc[7] = fmaf(bhi(v.w), a, acc[7]);
  }
  if (deg > 64) {
    for (int j0 = 64; j0 < deg; j0 += 8) {
      const int j = j0 + sub;
      float a = 0.f;
      int sn = 0;
      if (j < deg) {
        sn = nbr[start + j];
        float tv = als[sn] + ald0;
        tv = tv >= 0.f ? tv : NEG_SLOPE * tv;
        a = __expf(tv - M) * rden;
      }
      const uint4 v = *(const uint4*)((const unsigned short*)hfeat + (size_t)sn * 64 + q * 8);
      acc[0] = fmaf(blo(v.x), a, acc[0]);
      acc[1] = fmaf(bhi(v.x), a, acc[1]);
      acc[2] = fmaf(blo(v.y), a, acc[2]);
      acc[3] = fmaf(bhi(v.y), a, acc[3]);
      acc[4] = fmaf(blo(v.z), a, acc[4]);
      acc[5] = fmaf(bhi(v.z), a, acc[5]);
      acc[6] = fmaf(blo(v.w), a, acc[6]);
      acc[7] = fmaf(bhi(v.w), a, acc[7]);
    }
  }

#pragma unroll
  for (int k = 0; k < 8; ++k) {
    acc[k] += __shfl_xor(acc[k], 8, 64);
    acc[k] += __shfl_xor(acc[k], 16, 64);
    acc[k] += __shfl_xor(acc[k], 32, 64);
  }
  if (lane < 8) {
    const float4 b0 = ((const float4*)bias)[lane * 2];
    const float4 b1 = ((const float4*)bias)[lane * 2 + 1];
    float4* op = (float4*)(out + (size_t)node * 64 + lane * 8);
    op[0] = make_float4(acc[0] + b0.x, acc[1] + b0.y, acc[2] + b0.z, acc[3] + b0.w);
    op[1] = make_float4(acc[4] + b1.x, acc[5] + b1.y, acc[6] + b1.z, acc[7] + b1.w);
  }
}

extern "C" void kernel_launch(void* const* d_in, const int* in_sizes, int n_in,
                              void* d_out, int out_size, void* d_ws, size_t ws_size,
                              hipStream_t stream) {
  const float* x   = (const float*)d_in[0];
  const int*   ei  = (const int*)d_in[1];
  const float* W1  = (const float*)d_in[2];
  const float* a1s = (const float*)d_in[3];
  const float* a1d = (const float*)d_in[4];
  const float* b1  = (const float*)d_in[5];
  const float* W2  = (const float*)d_in[6];
  const float* a2s = (const float*)d_in[7];
  const float* a2d = (const float*)d_in[8];
  const float* b2  = (const float*)d_in[9];

  const int N = in_sizes[0] / 128;  // 100000
  const int E = in_sizes[1] / 2;    // 1600000
  const int* esrc = ei;
  const int* edst = ei + E;

  float* ws   = (float*)d_ws;
  __hip_bfloat16* h = (__hip_bfloat16*)ws;   // N*128 bf16 (slot sized N*128 f32)
  float* out1 = ws   + (size_t)N * 128;      // N*128 f32
  float* als  = out1 + (size_t)N * 128;      // N*4
  float* ald  = als  + (size_t)N * 4;        // N*4
  int* cnt    = (int*)(ald + (size_t)N * 4); // N
  int* rowptr = cnt + N;                     // N+1
  int* cursor = rowptr + N + 1;              // N
  int* bsum   = cursor + N;                  // 1024
  int* nbr    = bsum + 1024;                 // E+N
  // pre-swizzled bf16 W images (16B aligned)
  size_t off = ((size_t)((nbr + E + N) - (int*)ws) + 3) & ~(size_t)3;
  uint4* wsw1 = (uint4*)((int*)ws + off);    // 128*16 uint4 = 32KB
  uint4* wsw2 = wsw1 + 128 * 16;             // 64*16 uint4 = 16KB

  float* outF = (float*)d_out;               // N*64

  const int total = E + N;
  const int nb = (N + 1023) / 1024;

  // ---- W prep + CSR build ----
  k_prep_w<<<(128 * 16 + 255) / 256, 256, 0, stream>>>(W1, wsw1, 128);
  k_prep_w<<<(64 * 16 + 255) / 256, 256, 0, stream>>>(W2, wsw2, 64);
  k_fill1<<<(N + 255) / 256, 256, 0, stream>>>(cnt, N);
  k_count<<<(E + 255) / 256, 256, 0, stream>>>(edst, cnt, E);
  k_scan_local<<<nb, 256, 0, stream>>>(cnt, rowptr, bsum, N);
  k_scan_bsum<<<1, 1024, 0, stream>>>(bsum, nb);
  k_scan_add<<<(N + 256) / 256, 256, 0, stream>>>(bsum, rowptr, cursor, N, total);
  k_build_part<<<1280, 256, 0, stream>>>(esrc, edst, cursor, nbr, E, N);

  // ---- Layer 1: H=4, C=32, concat -> [N,128], +b1, ELU ----
  k_mfma_gemm<128, 4><<<(N + 127) / 128, 256, 0, stream>>>(
      x, wsw1, a1s, a1d, h, als, ald, N);
  k_gather_l1<<<(N + 3) / 4, 256, 0, stream>>>(rowptr, nbr, als, ald, h, b1, out1, N);

  // ---- Layer 2: H=1, C=64, mean(H=1) -> [N,64], +b2 ----
  k_mfma_gemm<64, 1><<<(N + 127) / 128, 256, 0, stream>>>(
      out1, wsw2, a2s, a2d, h, als, ald, N);
  k_gather_l2<<<(N + 3) / 4, 256, 0, stream>>>(rowptr, nbr, als, ald, h, b2, outF, N);
}

// Round 9
// 359.854 us; speedup vs baseline: 5.1054x; 1.0085x over previous
//
#include <hip/hip_runtime.h>
#include <hip/hip_bf16.h>
#include <math.h>

static constexpr float NEG_SLOPE = 0.2f;
static constexpr float NEG_BIG = -3.0e38f;  // finite sentinel: avoids (-inf)-(-inf)=NaN

typedef __attribute__((ext_vector_type(8))) short short8;  // 8 bf16 (4 VGPRs)
typedef __attribute__((ext_vector_type(4))) float f32x4;

__device__ __forceinline__ float blo(unsigned u) { return __uint_as_float(u << 16); }
__device__ __forceinline__ float bhi(unsigned u) { return __uint_as_float(u & 0xffff0000u); }
__device__ __forceinline__ unsigned pack2(float a, float b) {
  __hip_bfloat162 t = __float22bfloat162_rn(make_float2(a, b));
  union { __hip_bfloat162 b; unsigned u; } v;
  v.b = t;
  return v.u;  // low 16 bits = bf16(a), high = bf16(b)
}

// ---- W prep: fp32 [k][col] -> bf16 swizzled [col][k] image of the GEMM's LDS ----
__global__ void k_prep_w(const float* __restrict__ W, uint4* __restrict__ out, int BN) {
  const int i = blockIdx.x * blockDim.x + threadIdx.x;
  if (i >= BN * 16) return;
  const int col = i >> 4;
  const int chunk = (i & 15) ^ (col & 7);
  const float* wp = W + (size_t)chunk * 8 * BN + col;  // W[k=chunk*8][col]
  uint4 u;
  u.x = pack2(wp[0 * BN], wp[1 * BN]);
  u.y = pack2(wp[2 * BN], wp[3 * BN]);
  u.z = pack2(wp[4 * BN], wp[5 * BN]);
  u.w = pack2(wp[6 * BN], wp[7 * BN]);
  out[i] = u;
}

// ---- MFMA GEMM + logits (verified R7) ----
template <int BN, int HEADS>
__global__ __launch_bounds__(256) void k_mfma_gemm(
    const float* __restrict__ x, const uint4* __restrict__ wsw,
    const float* __restrict__ a_src, const float* __restrict__ a_dst,
    __hip_bfloat16* __restrict__ h_out, float* __restrict__ als,
    float* __restrict__ ald, int N) {
  constexpr int NTILES = BN / 16;
  __shared__ unsigned char Xl[128 * 256];
  __shared__ unsigned char Wl[BN * 256];
  const int tid = threadIdx.x;
  const int lane = tid & 63;
  const int wid = tid >> 6;
  const int base = blockIdx.x * 128;

  {
    uint4* dst = (uint4*)Wl;
    for (int i = tid; i < BN * 16; i += 256) dst[i] = wsw[i];
  }
  for (int it = 0; it < 8; ++it) {
    const int i = it * 256 + tid;
    const int r = i >> 4, c = i & 15;
    const int g = base + r;
    float4 f0 = make_float4(0.f, 0.f, 0.f, 0.f), f1 = f0;
    if (g < N) {
      const float* xp = x + (size_t)g * 128 + c * 8;
      f0 = *(const float4*)xp;
      f1 = *(const float4*)(xp + 4);
    }
    uint4 u;
    u.x = pack2(f0.x, f0.y);
    u.y = pack2(f0.z, f0.w);
    u.z = pack2(f1.x, f1.y);
    u.w = pack2(f1.z, f1.w);
    *(uint4*)(Xl + r * 256 + ((c * 16) ^ ((r & 7) << 4))) = u;
  }
  __syncthreads();

  const int lg = lane >> 4;
  const int ll = lane & 15;

  union U { uint4 u; short8 s; };
  short8 afr[2][4];
#pragma unroll
  for (int rt = 0; rt < 2; ++rt) {
    const int row = wid * 32 + rt * 16 + ll;
    const unsigned char* rp = Xl + row * 256;
    const int swz = (row & 7) << 4;
#pragma unroll
    for (int ks = 0; ks < 4; ++ks) {
      U t;
      t.u = *(const uint4*)(rp + ((ks * 64 + lg * 16) ^ swz));
      afr[rt][ks] = t.s;
    }
  }

  f32x4 acc[2][NTILES];
#pragma unroll
  for (int rt = 0; rt < 2; ++rt)
#pragma unroll
    for (int t = 0; t < NTILES; ++t) acc[rt][t] = (f32x4){0.f, 0.f, 0.f, 0.f};

#pragma unroll
  for (int t = 0; t < NTILES; ++t) {
    const int col = t * 16 + ll;
    const unsigned char* cp = Wl + col * 256;
    const int swz = (col & 7) << 4;
#pragma unroll
    for (int ks = 0; ks < 4; ++ks) {
      U b;
      b.u = *(const uint4*)(cp + ((ks * 64 + lg * 16) ^ swz));
      acc[0][t] = __builtin_amdgcn_mfma_f32_16x16x32_bf16(afr[0][ks], b.s, acc[0][t], 0, 0, 0);
      acc[1][t] = __builtin_amdgcn_mfma_f32_16x16x32_bf16(afr[1][ks], b.s, acc[1][t], 0, 0, 0);
    }
  }

  float asv[NTILES], adv[NTILES];
#pragma unroll
  for (int t = 0; t < NTILES; ++t) {
    asv[t] = a_src[t * 16 + ll];
    adv[t] = a_dst[t * 16 + ll];
  }
#pragma unroll
  for (int rt = 0; rt < 2; ++rt) {
#pragma unroll
    for (int r = 0; r < 4; ++r) {
      const int row = base + wid * 32 + rt * 16 + lg * 4 + r;
      if (HEADS == 4) {
        float ps[4], pd[4];
#pragma unroll
        for (int h = 0; h < 4; ++h) {
          ps[h] = acc[rt][2 * h][r] * asv[2 * h] + acc[rt][2 * h + 1][r] * asv[2 * h + 1];
          pd[h] = acc[rt][2 * h][r] * adv[2 * h] + acc[rt][2 * h + 1][r] * adv[2 * h + 1];
#pragma unroll
          for (int off = 1; off < 16; off <<= 1) {
            ps[h] += __shfl_xor(ps[h], off, 64);
            pd[h] += __shfl_xor(pd[h], off, 64);
          }
        }
        if (ll == 0 && row < N) {
          ((float4*)als)[row] = make_float4(ps[0], ps[1], ps[2], ps[3]);
          ((float4*)ald)[row] = make_float4(pd[0], pd[1], pd[2], pd[3]);
        }
      } else {
        float ps = 0.f, pd = 0.f;
#pragma unroll
        for (int t = 0; t < NTILES; ++t) {
          ps = fmaf(acc[rt][t][r], asv[t], ps);
          pd = fmaf(acc[rt][t][r], adv[t], pd);
        }
#pragma unroll
        for (int off = 1; off < 16; off <<= 1) {
          ps += __shfl_xor(ps, off, 64);
          pd += __shfl_xor(pd, off, 64);
        }
        if (ll == 0 && row < N) {
          als[row] = ps;
          ald[row] = pd;
        }
      }
    }
  }

  __syncthreads();
#pragma unroll
  for (int rt = 0; rt < 2; ++rt) {
#pragma unroll
    for (int t = 0; t < NTILES; ++t) {
#pragma unroll
      for (int r = 0; r < 4; ++r) {
        const float v = acc[rt][t][r];
        const float vn = __shfl_xor(v, 1, 64);
        if (!(lane & 1)) {
          const int row = wid * 32 + rt * 16 + lg * 4 + r;
          *(unsigned*)(Xl + row * (BN * 2) + (t * 16 + ll) * 2) = pack2(v, vn);
        }
      }
    }
  }
  __syncthreads();
  {
    constexpr int U4 = 128 * BN / 8;
    constexpr int U4R = BN / 8;
    for (int i = tid; i < U4; i += 256) {
      const int row = i / U4R;
      const int g = base + row;
      if (g < N)
        *(uint4*)((unsigned short*)h_out + (size_t)g * BN + (i % U4R) * 8) = ((uint4*)Xl)[i];
    }
  }
}

// ---------------- CSR build (counting sort by dst) ----------------
__global__ void k_fill1(int* __restrict__ cnt, int N) {
  int i = blockIdx.x * blockDim.x + threadIdx.x;
  if (i < N) cnt[i] = 1;
}

__global__ void k_count(const int* __restrict__ edst, int* __restrict__ cnt, int E) {
  int i = blockIdx.x * blockDim.x + threadIdx.x;
  if (i < E) atomicAdd(cnt + edst[i], 1);
}

__global__ void k_scan_local(const int* __restrict__ cnt, int* __restrict__ rowptr,
                             int* __restrict__ bsum, int N) {
  __shared__ int lds[256];
  const int tid = threadIdx.x;
  const int base = blockIdx.x * 1024;
  int vals[4], tsum = 0;
#pragma unroll
  for (int q = 0; q < 4; ++q) {
    int i = base + tid * 4 + q;
    vals[q] = (i < N) ? cnt[i] : 0;
    tsum += vals[q];
  }
  lds[tid] = tsum;
  __syncthreads();
  for (int off = 1; off < 256; off <<= 1) {
    int t = (tid >= off) ? lds[tid - off] : 0;
    __syncthreads();
    lds[tid] += t;
    __syncthreads();
  }
  int run = lds[tid] - tsum;
  if (tid == 255) bsum[blockIdx.x] = lds[255];
#pragma unroll
  for (int q = 0; q < 4; ++q) {
    int i = base + tid * 4 + q;
    if (i < N) rowptr[i] = run;
    run += vals[q];
  }
}

__global__ void k_scan_bsum(int* __restrict__ bsum, int nb) {
  __shared__ int lds[1024];
  const int tid = threadIdx.x;
  int v = (tid < nb) ? bsum[tid] : 0;
  lds[tid] = v;
  __syncthreads();
  for (int off = 1; off < 1024; off <<= 1) {
    int t = (tid >= off) ? lds[tid - off] : 0;
    __syncthreads();
    lds[tid] += t;
    __syncthreads();
  }
  bsum[tid] = lds[tid] - v;
}

__global__ void k_scan_add(const int* __restrict__ bsum, int* __restrict__ rowptr,
                           int* __restrict__ cursor, int N, int total) {
  int i = blockIdx.x * blockDim.x + threadIdx.x;
  if (i < N) {
    int r = rowptr[i] + bsum[i >> 10];
    rowptr[i] = r;
    cursor[i] = r;
  } else if (i == N) {
    rowptr[N] = total;
  }
}

// XCD-partitioned CSR fill (writes confined per-XCD-L2 region)
__global__ void k_build_part(const int* __restrict__ esrc, const int* __restrict__ edst,
                             int* __restrict__ cursor, int* __restrict__ nbr, int E, int N) {
  constexpr int NPARTS = 16;
  const int xcd = blockIdx.x & 7;
  const int span = (N + NPARTS - 1) / NPARTS;
  const int gid = (int)(blockIdx.x >> 3) * blockDim.x + threadIdx.x;
  const int stride = (int)(gridDim.x >> 3) * blockDim.x;
  const int E4 = E >> 2;
#pragma unroll
  for (int s = 0; s < NPARTS / 8; ++s) {
    const int p = s * 8 + xcd;
    const int lo = p * span;
    const int hi = min(N, lo + span);
    for (int i = gid; i < E4; i += stride) {
      const int4 d4 = ((const int4*)edst)[i];
      if (d4.x >= lo && d4.x < hi) nbr[atomicAdd(cursor + d4.x, 1)] = esrc[i * 4 + 0];
      if (d4.y >= lo && d4.y < hi) nbr[atomicAdd(cursor + d4.y, 1)] = esrc[i * 4 + 1];
      if (d4.z >= lo && d4.z < hi) nbr[atomicAdd(cursor + d4.z, 1)] = esrc[i * 4 + 2];
      if (d4.w >= lo && d4.w < hi) nbr[atomicAdd(cursor + d4.w, 1)] = esrc[i * 4 + 3];
    }
    for (int i = E4 * 4 + gid; i < E + N; i += stride) {
      const int d = i < E ? edst[i] : i - E;
      if (d >= lo && d < hi) {
        const int sn = i < E ? esrc[i] : i - E;
        nbr[atomicAdd(cursor + d, 1)] = sn;
      }
    }
  }
}

// ---------------- Gather layer 1: H=4, C=32, bf16 h, ELU ----------------
// LDS entry j*4+head = {alpha, bitcast(src_byte_off)}; pass C 4 edges/iter,
// one ds_read_b64 + one prefetched dwordx4 per group.
__global__ void k_gather_l1(const int* __restrict__ rowptr, const int* __restrict__ nbr,
                            const float* __restrict__ als, const float* __restrict__ ald,
                            const __hip_bfloat16* __restrict__ hfeat,
                            const float* __restrict__ bias,
                            float* __restrict__ out, int N) {
  __shared__ float2 alds[4][256];  // [wave][edge*4 + head]
  const int lane = threadIdx.x & 63;
  const int wid = threadIdx.x >> 6;
  const int node = (int)((blockIdx.x * blockDim.x + threadIdx.x) >> 6);
  if (node >= N) return;
  const int start = rowptr[node], end = rowptr[node + 1];
  const int deg = end - start;
  const float4 aldd = ((const float4*)ald)[node];

  float t[4];
  int myn = 0;
  {
    const int j = start + lane;
    if (j < end) {
      myn = nbr[j];
      const float4 av = ((const float4*)als)[myn];
      const float tr[4] = {av.x + aldd.x, av.y + aldd.y, av.z + aldd.z, av.w + aldd.w};
#pragma unroll
      for (int h = 0; h < 4; ++h) t[h] = tr[h] >= 0.f ? tr[h] : NEG_SLOPE * tr[h];
    } else {
#pragma unroll
      for (int h = 0; h < 4; ++h) t[h] = NEG_BIG;
    }
  }

  float Mh[4], rden[4], myex[4];
  if (deg <= 32) {
    // width-32 reduce: lanes 0-31 hold all edges; lanes deg..31 give alpha=0.
    // (upper half computes its own garbage stats but pass C never reads j>=32)
#pragma unroll
    for (int h = 0; h < 4; ++h) {
      float M = t[h];
#pragma unroll
      for (int off = 1; off < 32; off <<= 1) M = fmaxf(M, __shfl_xor(M, off, 64));
      const float e = __expf(t[h] - M);
      float sum = e;
#pragma unroll
      for (int off = 1; off < 32; off <<= 1) sum += __shfl_xor(sum, off, 64);
      Mh[h] = M;
      rden[h] = 1.f / sum;
      myex[h] = e * rden[h];
    }
  } else if (deg <= 64) {
#pragma unroll
    for (int h = 0; h < 4; ++h) {
      float M = t[h];
#pragma unroll
      for (int off = 1; off < 64; off <<= 1) M = fmaxf(M, __shfl_xor(M, off, 64));
      const float e = __expf(t[h] - M);
      float sum = e;
#pragma unroll
      for (int off = 1; off < 64; off <<= 1) sum += __shfl_xor(sum, off, 64);
      Mh[h] = M;
      rden[h] = 1.f / sum;
      myex[h] = e * rden[h];
    }
  } else {
    float m[4], s[4];
#pragma unroll
    for (int h = 0; h < 4; ++h) { m[h] = t[h]; s[h] = 1.f; }
    for (int base = start + 64; base < end; base += 64) {
      const int j = base + lane;
      if (j < end) {
        const int sn = nbr[j];
        const float4 av = ((const float4*)als)[sn];
        const float tr[4] = {av.x + aldd.x, av.y + aldd.y, av.z + aldd.z, av.w + aldd.w};
#pragma unroll
        for (int h = 0; h < 4; ++h) {
          const float tv = tr[h] >= 0.f ? tr[h] : NEG_SLOPE * tr[h];
          const float M = fmaxf(m[h], tv);
          s[h] = s[h] * __expf(m[h] - M) + __expf(tv - M);
          m[h] = M;
        }
      }
    }
#pragma unroll
    for (int h = 0; h < 4; ++h) {
      float M = m[h];
#pragma unroll
      for (int off = 1; off < 64; off <<= 1) M = fmaxf(M, __shfl_xor(M, off, 64));
      float e = s[h] * __expf(m[h] - M);
#pragma unroll
      for (int off = 1; off < 64; off <<= 1) e += __shfl_xor(e, off, 64);
      Mh[h] = M;
      rden[h] = 1.f / e;
      myex[h] = __expf(t[h] - M) * rden[h];
    }
  }
  {
    const float offf = __int_as_float(myn << 8);  // byte offset of 256B row
    float4* ap = (float4*)&alds[wid][lane * 4];
    ap[0] = make_float4(myex[0], offf, myex[1], offf);
    ap[1] = make_float4(myex[2], offf, myex[3], offf);
  }

  // ---- Pass C: 4 edges/iter, 2-deep pipeline ----
  const int sub = lane >> 4;
  const int q = lane & 15;
  const int head = q >> 2;
  const char* hq = (const char*)hfeat + q * 16;
  float acc[8];
#pragma unroll
  for (int k = 0; k < 8; ++k) acc[k] = 0.f;

  const int nq = deg < 64 ? deg : 64;
  const float2* aw = &alds[wid][head];
  float2 ao = aw[sub * 4];
  uint4 v = *(const uint4*)(hq + (unsigned)__float_as_int(ao.y));
  float a = ao.x;
  for (int j0 = 4; j0 < nq + 4; j0 += 4) {
    float2 ao2;
    uint4 v2;
    const bool more = j0 < nq;
    if (more) {
      ao2 = aw[(j0 + sub) * 4];
      v2 = *(const uint4*)(hq + (unsigned)__float_as_int(ao2.y));
    }
    acc[0] = fmaf(blo(v.x), a, acc[0]);
    acc[1] = fmaf(bhi(v.x), a, acc[1]);
    acc[2] = fmaf(blo(v.y), a, acc[2]);
    acc[3] = fmaf(bhi(v.y), a, acc[3]);
    acc[4] = fmaf(blo(v.z), a, acc[4]);
    acc[5] = fmaf(bhi(v.z), a, acc[5]);
    acc[6] = fmaf(blo(v.w), a, acc[6]);
    acc[7] = fmaf(bhi(v.w), a, acc[7]);
    if (more) {
      a = ao2.x;
      v = v2;
    }
  }
  if (deg > 64) {
    const float Mm = head == 0 ? Mh[0] : head == 1 ? Mh[1] : head == 2 ? Mh[2] : Mh[3];
    const float rd = head == 0 ? rden[0] : head == 1 ? rden[1] : head == 2 ? rden[2] : rden[3];
    const float ad_ = head == 0 ? aldd.x : head == 1 ? aldd.y : head == 2 ? aldd.z : aldd.w;
    for (int j0 = 64; j0 < deg; j0 += 4) {
      const int j = j0 + sub;
      float a2 = 0.f;
      int sn = 0;
      if (j < deg) {
        sn = nbr[start + j];
        const float4 av = ((const float4*)als)[sn];
        const float as_ = head == 0 ? av.x : head == 1 ? av.y : head == 2 ? av.z : av.w;
        float tv = as_ + ad_;
        tv = tv >= 0.f ? tv : NEG_SLOPE * tv;
        a2 = __expf(tv - Mm) * rd;
      }
      const uint4 w = *(const uint4*)(hq + (size_t)sn * 256);
      acc[0] = fmaf(blo(w.x), a2, acc[0]);
      acc[1] = fmaf(bhi(w.x), a2, acc[1]);
      acc[2] = fmaf(blo(w.y), a2, acc[2]);
      acc[3] = fmaf(bhi(w.y), a2, acc[3]);
      acc[4] = fmaf(blo(w.z), a2, acc[4]);
      acc[5] = fmaf(bhi(w.z), a2, acc[5]);
      acc[6] = fmaf(blo(w.w), a2, acc[6]);
      acc[7] = fmaf(bhi(w.w), a2, acc[7]);
    }
  }

#pragma unroll
  for (int k = 0; k < 8; ++k) {
    acc[k] += __shfl_xor(acc[k], 16, 64);
    acc[k] += __shfl_xor(acc[k], 32, 64);
  }
  if (lane < 16) {
    const float4 b0 = ((const float4*)bias)[lane * 2];
    const float4 b1 = ((const float4*)bias)[lane * 2 + 1];
    float r[8] = {acc[0] + b0.x, acc[1] + b0.y, acc[2] + b0.z, acc[3] + b0.w,
                  acc[4] + b1.x, acc[5] + b1.y, acc[6] + b1.z, acc[7] + b1.w};
#pragma unroll
    for (int k = 0; k < 8; ++k) r[k] = r[k] > 0.f ? r[k] : __expf(r[k]) - 1.f;
    float4* op = (float4*)(out + (size_t)node * 128 + lane * 8);
    op[0] = make_float4(r[0], r[1], r[2], r[3]);
    op[1] = make_float4(r[4], r[5], r[6], r[7]);
  }
}

// ---------------- Gather layer 2: H=1, C=64, bf16 h, no ELU ----------------
__global__ void k_gather_l2(const int* __restrict__ rowptr, const int* __restrict__ nbr,
                            const float* __restrict__ als, const float* __restrict__ ald,
                            const __hip_bfloat16* __restrict__ hfeat,
                            const float* __restrict__ bias,
                            float* __restrict__ out, int N) {
  __shared__ float2 alds[4][64];
  const int lane = threadIdx.x & 63;
  const int wid = threadIdx.x >> 6;
  const int node = (int)((blockIdx.x * blockDim.x + threadIdx.x) >> 6);
  if (node >= N) return;
  const int start = rowptr[node], end = rowptr[node + 1];
  const int deg = end - start;
  const float ald0 = ald[node];

  float t = NEG_BIG;
  int myn = 0;
  {
    const int j = start + lane;
    if (j < end) {
      myn = nbr[j];
      float tv = als[myn] + ald0;
      t = tv >= 0.f ? tv : NEG_SLOPE * tv;
    }
  }

  float M, rden, myal;
  if (deg <= 32) {
    M = t;
#pragma unroll
    for (int off = 1; off < 32; off <<= 1) M = fmaxf(M, __shfl_xor(M, off, 64));
    const float e = __expf(t - M);
    float sum = e;
#pragma unroll
    for (int off = 1; off < 32; off <<= 1) sum += __shfl_xor(sum, off, 64);
    rden = 1.f / sum;
    myal = e * rden;
  } else if (deg <= 64) {
    M = t;
#pragma unroll
    for (int off = 1; off < 64; off <<= 1) M = fmaxf(M, __shfl_xor(M, off, 64));
    const float e = __expf(t - M);
    float sum = e;
#pragma unroll
    for (int off = 1; off < 64; off <<= 1) sum += __shfl_xor(sum, off, 64);
    rden = 1.f / sum;
    myal = e * rden;
  } else {
    float m = t, s = 1.f;
    for (int base = start + 64; base < end; base += 64) {
      const int j = base + lane;
      if (j < end) {
        float tv = als[nbr[j]] + ald0;
        tv = tv >= 0.f ? tv : NEG_SLOPE * tv;
        const float Mn = fmaxf(m, tv);
        s = s * __expf(m - Mn) + __expf(tv - Mn);
        m = Mn;
      }
    }
    M = m;
#pragma unroll
    for (int off = 1; off < 64; off <<= 1) M = fmaxf(M, __shfl_xor(M, off, 64));
    float e = s * __expf(m - M);
#pragma unroll
    for (int off = 1; off < 64; off <<= 1) e += __shfl_xor(e, off, 64);
    rden = 1.f / e;
    myal = __expf(t - M) * rden;
  }
  alds[wid][lane] = make_float2(myal, __int_as_float(myn << 7));  // 128B rows

  const int sub = lane >> 3;
  const int q = lane & 7;
  const char* hq = (const char*)hfeat + q * 16;
  float acc[8];
#pragma unroll
  for (int k = 0; k < 8; ++k) acc[k] = 0.f;

  const int nq = deg < 64 ? deg : 64;
  const float2* aw = &alds[wid][0];
  float2 ao = aw[sub];
  uint4 v = *(const uint4*)(hq + (unsigned)__float_as_int(ao.y));
  float a = ao.x;
  for (int j0 = 8; j0 < nq + 8; j0 += 8) {
    float2 ao2;
    uint4 v2;
    const bool more = j0 < nq;
    if (more) {
      ao2 = aw[j0 + sub];
      v2 = *(const uint4*)(hq + (unsigned)__float_as_int(ao2.y));
    }
    acc[0] = fmaf(blo(v.x), a, acc[0]);
    acc[1] = fmaf(bhi(v.x), a, acc[1]);
    acc[2] = fmaf(blo(v.y), a, acc[2]);
    acc[3] = fmaf(bhi(v.y), a, acc[3]);
    acc[4] = fmaf(blo(v.z), a, acc[4]);
    acc[5] = fmaf(bhi(v.z), a, acc[5]);
    acc[6] = fmaf(blo(v.w), a, acc[6]);
    acc[7] = fmaf(bhi(v.w), a, acc[7]);
    if (more) {
      a = ao2.x;
      v = v2;
    }
  }
  if (deg > 64) {
    for (int j0 = 64; j0 < deg; j0 += 8) {
      const int j = j0 + sub;
      float a2 = 0.f;
      int sn = 0;
      if (j < deg) {
        sn = nbr[start + j];
        float tv = als[sn] + ald0;
        tv = tv >= 0.f ? tv : NEG_SLOPE * tv;
        a2 = __expf(tv - M) * rden;
      }
      const uint4 w = *(const uint4*)(hq + (size_t)sn * 128);
      acc[0] = fmaf(blo(w.x), a2, acc[0]);
      acc[1] = fmaf(bhi(w.x), a2, acc[1]);
      acc[2] = fmaf(blo(w.y), a2, acc[2]);
      acc[3] = fmaf(bhi(w.y), a2, acc[3]);
      acc[4] = fmaf(blo(w.z), a2, acc[4]);
      acc[5] = fmaf(bhi(w.z), a2, acc[5]);
      acc[6] = fmaf(blo(w.w), a2, acc[6]);
      acc[7] = fmaf(bhi(w.w), a2, acc[7]);
    }
  }

#pragma unroll
  for (int k = 0; k < 8; ++k) {
    acc[k] += __shfl_xor(acc[k], 8, 64);
    acc[k] += __shfl_xor(acc[k], 16, 64);
    acc[k] += __shfl_xor(acc[k], 32, 64);
  }
  if (lane < 8) {
    const float4 b0 = ((const float4*)bias)[lane * 2];
    const float4 b1 = ((const float4*)bias)[lane * 2 + 1];
    float4* op = (float4*)(out + (size_t)node * 64 + lane * 8);
    op[0] = make_float4(acc[0] + b0.x, acc[1] + b0.y, acc[2] + b0.z, acc[3] + b0.w);
    op[1] = make_float4(acc[4] + b1.x, acc[5] + b1.y, acc[6] + b1.z, acc[7] + b1.w);
  }
}

extern "C" void kernel_launch(void* const* d_in, const int* in_sizes, int n_in,
                              void* d_out, int out_size, void* d_ws, size_t ws_size,
                              hipStream_t stream) {
  const float* x   = (const float*)d_in[0];
  const int*   ei  = (const int*)d_in[1];
  const float* W1  = (const float*)d_in[2];
  const float* a1s = (const float*)d_in[3];
  const float* a1d = (const float*)d_in[4];
  const float* b1  = (const float*)d_in[5];
  const float* W2  = (const float*)d_in[6];
  const float* a2s = (const float*)d_in[7];
  const float* a2d = (const float*)d_in[8];
  const float* b2  = (const float*)d_in[9];

  const int N = in_sizes[0] / 128;  // 100000
  const int E = in_sizes[1] / 2;    // 1600000
  const int* esrc = ei;
  const int* edst = ei + E;

  float* ws   = (float*)d_ws;
  __hip_bfloat16* h = (__hip_bfloat16*)ws;   // N*128 bf16 (slot sized N*128 f32)
  float* out1 = ws   + (size_t)N * 128;      // N*128 f32
  float* als  = out1 + (size_t)N * 128;      // N*4
  float* ald  = als  + (size_t)N * 4;        // N*4
  int* cnt    = (int*)(ald + (size_t)N * 4); // N
  int* rowptr = cnt + N;                     // N+1
  int* cursor = rowptr + N + 1;              // N
  int* bsum   = cursor + N;                  // 1024
  int* nbr    = bsum + 1024;                 // E+N
  size_t off = ((size_t)((nbr + E + N) - (int*)ws) + 3) & ~(size_t)3;
  uint4* wsw1 = (uint4*)((int*)ws + off);    // 128*16 uint4 = 32KB
  uint4* wsw2 = wsw1 + 128 * 16;             // 64*16 uint4 = 16KB

  float* outF = (float*)d_out;               // N*64

  const int total = E + N;
  const int nb = (N + 1023) / 1024;

  // ---- W prep + CSR build ----
  k_prep_w<<<(128 * 16 + 255) / 256, 256, 0, stream>>>(W1, wsw1, 128);
  k_prep_w<<<(64 * 16 + 255) / 256, 256, 0, stream>>>(W2, wsw2, 64);
  k_fill1<<<(N + 255) / 256, 256, 0, stream>>>(cnt, N);
  k_count<<<(E + 255) / 256, 256, 0, stream>>>(edst, cnt, E);
  k_scan_local<<<nb, 256, 0, stream>>>(cnt, rowptr, bsum, N);
  k_scan_bsum<<<1, 1024, 0, stream>>>(bsum, nb);
  k_scan_add<<<(N + 256) / 256, 256, 0, stream>>>(bsum, rowptr, cursor, N, total);
  k_build_part<<<1280, 256, 0, stream>>>(esrc, edst, cursor, nbr, E, N);

  // ---- Layer 1: H=4, C=32, concat -> [N,128], +b1, ELU ----
  k_mfma_gemm<128, 4><<<(N + 127) / 128, 256, 0, stream>>>(
      x, wsw1, a1s, a1d, h, als, ald, N);
  k_gather_l1<<<(N + 3) / 4, 256, 0, stream>>>(rowptr, nbr, als, ald, h, b1, out1, N);

  // ---- Layer 2: H=1, C=64, mean(H=1) -> [N,64], +b2 ----
  k_mfma_gemm<64, 1><<<(N + 127) / 128, 256, 0, stream>>>(
      out1, wsw2, a2s, a2d, h, als, ald, N);
  k_gather_l2<<<(N + 3) / 4, 256, 0, stream>>>(rowptr, nbr, als, ald, h, b2, outF, N);
}

// Round 10
// 329.353 us; speedup vs baseline: 5.5782x; 1.0926x over previous
//
#include <hip/hip_runtime.h>
#include <hip/hip_bf16.h>
#include <math.h>

static constexpr float NEG_SLOPE = 0.2f;
static constexpr float NEG_BIG = -3.0e38f;  // finite sentinel: avoids (-inf)-(-inf)=NaN

typedef __attribute__((ext_vector_type(8))) short short8;  // 8 bf16 (4 VGPRs)
typedef __attribute__((ext_vector_type(4))) float f32x4;

__device__ __forceinline__ float blo(unsigned u) { return __uint_as_float(u << 16); }
__device__ __forceinline__ float bhi(unsigned u) { return __uint_as_float(u & 0xffff0000u); }
__device__ __forceinline__ unsigned pack2(float a, float b) {
  __hip_bfloat162 t = __float22bfloat162_rn(make_float2(a, b));
  union { __hip_bfloat162 b; unsigned u; } v;
  v.b = t;
  return v.u;
}

// ---- W prep: fp32 [k][col] -> bf16 swizzled [col][k] LDS image, PLUS 16 extra
// cols holding WA = W@A (attention vectors folded in, fp32 dot -> bf16 once),
// so the GEMM emits attention logits as a free extra tile.
template <int BN, int HEADS>
__global__ void k_prep_w(const float* __restrict__ W, const float* __restrict__ as_,
                         const float* __restrict__ ad_, uint4* __restrict__ out) {
  constexpr int XC = BN + 16;
  constexpr int C = BN / HEADS;
  const int i = blockIdx.x * blockDim.x + threadIdx.x;
  if (i >= XC * 16) return;
  const int col = i >> 4;
  const int chunk = (i & 15) ^ (col & 7);
  float v[8];
  if (col < BN) {
#pragma unroll
    for (int t = 0; t < 8; ++t) v[t] = W[(size_t)(chunk * 8 + t) * BN + col];
  } else {
    const int j = col - BN;
#pragma unroll
    for (int t = 0; t < 8; ++t) v[t] = 0.f;
    if (j < 2 * HEADS) {
      const int hh = (HEADS == 4) ? (j & 3) : 0;
      const bool is_src = (HEADS == 4) ? (j < 4) : (j == 0);
      const float* av = (is_src ? as_ : ad_) + hh * C;
      const float* wb = W + hh * C;
#pragma unroll
      for (int t = 0; t < 8; ++t) {
        float s = 0.f;
        for (int c = 0; c < C; ++c) s = fmaf(wb[(size_t)(chunk * 8 + t) * BN + c], av[c], s);
        v[t] = s;
      }
    }
  }
  uint4 u;
  u.x = pack2(v[0], v[1]);
  u.y = pack2(v[2], v[3]);
  u.z = pack2(v[4], v[5]);
  u.w = pack2(v[6], v[7]);
  out[i] = u;
}

// ---- MFMA GEMM: h = x@W (bf16), logits from extra tile. Single reused LDS buf.
template <int BN, int HEADS>
__global__ __launch_bounds__(256) void k_mfma_gemm(
    const float* __restrict__ x, const uint4* __restrict__ wsw,
    __hip_bfloat16* __restrict__ h_out, float* __restrict__ als,
    float* __restrict__ ald, int N) {
  constexpr int XC = BN + 16;
  constexpr int NTILES = BN / 16;
  constexpr int BUFSZ = (XC * 256 > 128 * 256) ? XC * 256 : 128 * 256;
  __shared__ unsigned char buf[BUFSZ];
  const int tid = threadIdx.x;
  const int lane = tid & 63;
  const int wid = tid >> 6;
  const int base = blockIdx.x * 128;

  // ---- stage X (fp32 -> bf16, [row][k] XOR-swizzled) ----
  for (int it = 0; it < 8; ++it) {
    const int i = it * 256 + tid;
    const int r = i >> 4, c = i & 15;
    const int g = base + r;
    float4 f0 = make_float4(0.f, 0.f, 0.f, 0.f), f1 = f0;
    if (g < N) {
      const float* xp = x + (size_t)g * 128 + c * 8;
      f0 = *(const float4*)xp;
      f1 = *(const float4*)(xp + 4);
    }
    uint4 u;
    u.x = pack2(f0.x, f0.y);
    u.y = pack2(f0.z, f0.w);
    u.z = pack2(f1.x, f1.y);
    u.w = pack2(f1.z, f1.w);
    *(uint4*)(buf + r * 256 + ((c * 16) ^ ((r & 7) << 4))) = u;
  }
  __syncthreads();

  const int lg = lane >> 4;
  const int ll = lane & 15;
  union U { uint4 u; short8 s; };
  short8 afr[2][4];
#pragma unroll
  for (int rt = 0; rt < 2; ++rt) {
    const int row = wid * 32 + rt * 16 + ll;
    const unsigned char* rp = buf + row * 256;
    const int swz = (row & 7) << 4;
#pragma unroll
    for (int ks = 0; ks < 4; ++ks) {
      U t;
      t.u = *(const uint4*)(rp + ((ks * 64 + lg * 16) ^ swz));
      afr[rt][ks] = t.s;
    }
  }
  __syncthreads();  // done with X region; reuse buf for W

  {
    uint4* dst = (uint4*)buf;
    for (int i = tid; i < XC * 16; i += 256) dst[i] = wsw[i];
  }
  __syncthreads();

  f32x4 acc[2][NTILES + 1];
#pragma unroll
  for (int rt = 0; rt < 2; ++rt)
#pragma unroll
    for (int t = 0; t <= NTILES; ++t) acc[rt][t] = (f32x4){0.f, 0.f, 0.f, 0.f};

#pragma unroll
  for (int t = 0; t <= NTILES; ++t) {
    const int col = t * 16 + ll;
    const unsigned char* cp = buf + col * 256;
    const int swz = (col & 7) << 4;
#pragma unroll
    for (int ks = 0; ks < 4; ++ks) {
      U b;
      b.u = *(const uint4*)(cp + ((ks * 64 + lg * 16) ^ swz));
      acc[0][t] = __builtin_amdgcn_mfma_f32_16x16x32_bf16(afr[0][ks], b.s, acc[0][t], 0, 0, 0);
      acc[1][t] = __builtin_amdgcn_mfma_f32_16x16x32_bf16(afr[1][ks], b.s, acc[1][t], 0, 0, 0);
    }
  }

  // ---- logits from the extra tile: col ll = {src heads, dst heads} ----
#pragma unroll
  for (int rt = 0; rt < 2; ++rt) {
#pragma unroll
    for (int r = 0; r < 4; ++r) {
      const int row = base + wid * 32 + rt * 16 + lg * 4 + r;
      if (row < N) {
        const float v = acc[rt][NTILES][r];
        if (HEADS == 4) {
          if (ll < 4) als[(size_t)row * 4 + ll] = v;
          else if (ll < 8) ald[(size_t)row * 4 + (ll - 4)] = v;
        } else {
          if (ll == 0) als[row] = v;
          else if (ll == 1) ald[row] = v;
        }
      }
    }
  }

  // ---- h store via LDS for coalesced uint4 global writes ----
  __syncthreads();
#pragma unroll
  for (int rt = 0; rt < 2; ++rt) {
#pragma unroll
    for (int t = 0; t < NTILES; ++t) {
#pragma unroll
      for (int r = 0; r < 4; ++r) {
        const float v = acc[rt][t][r];
        const float vn = __shfl_xor(v, 1, 64);
        if (!(lane & 1)) {
          const int row = wid * 32 + rt * 16 + lg * 4 + r;
          *(unsigned*)(buf + row * (BN * 2) + (t * 16 + ll) * 2) = pack2(v, vn);
        }
      }
    }
  }
  __syncthreads();
  {
    constexpr int U4 = 128 * BN / 8;
    constexpr int U4R = BN / 8;
    for (int i = tid; i < U4; i += 256) {
      const int row = i / U4R;
      const int g = base + row;
      if (g < N)
        *(uint4*)((unsigned short*)h_out + (size_t)g * BN + (i % U4R) * 8) = ((uint4*)buf)[i];
    }
  }
}

// ---------------- CSR build (counting sort by dst) ----------------
__global__ void k_count(const int* __restrict__ edst, int* __restrict__ cnt, int E) {
  int i = blockIdx.x * blockDim.x + threadIdx.x;
  if (i < E) atomicAdd(cnt + edst[i], 1);
}

// +1 folded in (self-loop); cnt must be zeroed beforehand.
__global__ void k_scan_local(const int* __restrict__ cnt, int* __restrict__ rowptr,
                             int* __restrict__ bsum, int N) {
  __shared__ int lds[256];
  const int tid = threadIdx.x;
  const int base = blockIdx.x * 1024;
  int vals[4], tsum = 0;
#pragma unroll
  for (int q = 0; q < 4; ++q) {
    int i = base + tid * 4 + q;
    vals[q] = (i < N) ? cnt[i] + 1 : 0;
    tsum += vals[q];
  }
  lds[tid] = tsum;
  __syncthreads();
  for (int off = 1; off < 256; off <<= 1) {
    int t = (tid >= off) ? lds[tid - off] : 0;
    __syncthreads();
    lds[tid] += t;
    __syncthreads();
  }
  int run = lds[tid] - tsum;
  if (tid == 255) bsum[blockIdx.x] = lds[255];
#pragma unroll
  for (int q = 0; q < 4; ++q) {
    int i = base + tid * 4 + q;
    if (i < N) rowptr[i] = run;
    run += vals[q];
  }
}

__global__ void k_scan_bsum(int* __restrict__ bsum, int nb) {
  __shared__ int lds[1024];
  const int tid = threadIdx.x;
  int v = (tid < nb) ? bsum[tid] : 0;
  lds[tid] = v;
  __syncthreads();
  for (int off = 1; off < 1024; off <<= 1) {
    int t = (tid >= off) ? lds[tid - off] : 0;
    __syncthreads();
    lds[tid] += t;
    __syncthreads();
  }
  bsum[tid] = lds[tid] - v;
}

__global__ void k_scan_add(const int* __restrict__ bsum, int* __restrict__ rowptr,
                           int* __restrict__ cursor, int N, int total) {
  int i = blockIdx.x * blockDim.x + threadIdx.x;
  if (i < N) {
    int r = rowptr[i] + bsum[i >> 10];
    rowptr[i] = r;
    cursor[i] = r;
  } else if (i == N) {
    rowptr[N] = total;
  }
}

// XCD-partitioned CSR fill, 8 parts -> ONE sweep over the edge list.
__global__ void k_build_part(const int* __restrict__ esrc, const int* __restrict__ edst,
                             int* __restrict__ cursor, int* __restrict__ nbr, int E, int N) {
  constexpr int NPARTS = 8;
  const int p = blockIdx.x & 7;
  const int span = (N + NPARTS - 1) / NPARTS;
  const int lo = p * span;
  const int hi = min(N, lo + span);
  const int gid = (int)(blockIdx.x >> 3) * blockDim.x + threadIdx.x;
  const int stride = (int)(gridDim.x >> 3) * blockDim.x;
  const int E4 = E >> 2;
  for (int i = gid; i < E4; i += stride) {
    const int4 d4 = ((const int4*)edst)[i];
    if (d4.x >= lo && d4.x < hi) nbr[atomicAdd(cursor + d4.x, 1)] = esrc[i * 4 + 0];
    if (d4.y >= lo && d4.y < hi) nbr[atomicAdd(cursor + d4.y, 1)] = esrc[i * 4 + 1];
    if (d4.z >= lo && d4.z < hi) nbr[atomicAdd(cursor + d4.z, 1)] = esrc[i * 4 + 2];
    if (d4.w >= lo && d4.w < hi) nbr[atomicAdd(cursor + d4.w, 1)] = esrc[i * 4 + 3];
  }
  for (int i = E4 * 4 + gid; i < E + N; i += stride) {
    const int d = i < E ? edst[i] : i - E;
    if (d >= lo && d < hi) {
      const int sn = i < E ? esrc[i] : i - E;
      nbr[atomicAdd(cursor + d, 1)] = sn;
    }
  }
}

// ---------------- Gather layer 1: H=4, C=32; TWO nodes per wave ----------------
// half = lane>>5 owns one node; all reduces width-32. Alpha planes stride 40
// (banks 8*head+sub distinct; halves 2-way = free).
__global__ void k_gather_l1(const int* __restrict__ rowptr, const int* __restrict__ nbr,
                            const float* __restrict__ als, const float* __restrict__ ald,
                            const __hip_bfloat16* __restrict__ hfeat,
                            const float* __restrict__ bias,
                            float* __restrict__ out, int N) {
  __shared__ float atab[4][2][4][40];    // [wave][half][head][edge]
  __shared__ unsigned otab[4][2][32];    // [wave][half][edge] byte offsets
  const int lane = threadIdx.x & 63;
  const int wid = threadIdx.x >> 6;
  const int half = lane >> 5;
  const int l32 = lane & 31;
  const int node = (int)((blockIdx.x * blockDim.x + threadIdx.x) >> 6) * 2 + half;
  const bool valid = node < N;
  int start = 0, end = 0;
  if (valid) {
    start = rowptr[node];
    end = rowptr[node + 1];
  }
  const int deg = end - start;
  const float4 aldd = valid ? ((const float4*)ald)[node] : make_float4(0.f, 0.f, 0.f, 0.f);

  // pass A: lane l32 = edge l32
  float t[4];
  int myn = 0;
  {
    const int j = start + l32;
    if (j < end) {
      myn = nbr[j];
      const float4 av = ((const float4*)als)[myn];
      const float tr[4] = {av.x + aldd.x, av.y + aldd.y, av.z + aldd.z, av.w + aldd.w};
#pragma unroll
      for (int h = 0; h < 4; ++h) t[h] = tr[h] >= 0.f ? tr[h] : NEG_SLOPE * tr[h];
    } else {
#pragma unroll
      for (int h = 0; h < 4; ++h) t[h] = NEG_BIG;
    }
  }
  otab[wid][half][l32] = (unsigned)myn << 8;  // 256B rows

  float Mh[4], rden[4], myex[4];
  if (deg <= 32) {
#pragma unroll
    for (int h = 0; h < 4; ++h) {
      float M = t[h];
#pragma unroll
      for (int off = 1; off < 32; off <<= 1) M = fmaxf(M, __shfl_xor(M, off, 64));
      const float e = __expf(t[h] - M);
      float sum = e;
#pragma unroll
      for (int off = 1; off < 32; off <<= 1) sum += __shfl_xor(sum, off, 64);
      Mh[h] = M;
      rden[h] = 1.f / sum;
      myex[h] = e * rden[h];
    }
  } else {
    float m[4], s[4];
#pragma unroll
    for (int h = 0; h < 4; ++h) {
      m[h] = t[h];
      s[h] = (t[h] > NEG_BIG) ? 1.f : 0.f;
    }
    for (int b = start + 32; b < end; b += 32) {
      const int j = b + l32;
      if (j < end) {
        const int sn = nbr[j];
        const float4 av = ((const float4*)als)[sn];
        const float tr[4] = {av.x + aldd.x, av.y + aldd.y, av.z + aldd.z, av.w + aldd.w};
#pragma unroll
        for (int h = 0; h < 4; ++h) {
          const float tv = tr[h] >= 0.f ? tr[h] : NEG_SLOPE * tr[h];
          const float M = fmaxf(m[h], tv);
          s[h] = s[h] * __expf(m[h] - M) + __expf(tv - M);
          m[h] = M;
        }
      }
    }
#pragma unroll
    for (int h = 0; h < 4; ++h) {
      float M = m[h];
#pragma unroll
      for (int off = 1; off < 32; off <<= 1) M = fmaxf(M, __shfl_xor(M, off, 64));
      float e = s[h] * __expf(m[h] - M);
#pragma unroll
      for (int off = 1; off < 32; off <<= 1) e += __shfl_xor(e, off, 64);
      Mh[h] = M;
      rden[h] = 1.f / e;
      myex[h] = __expf(t[h] - M) * rden[h];
    }
  }
#pragma unroll
  for (int h = 0; h < 4; ++h) atab[wid][half][h][l32] = myex[h];

  // pass C: 2 edge slots x 16 chunks per half
  const int sub = l32 >> 4;
  const int q = l32 & 15;
  const int head = q >> 2;
  const char* hq = (const char*)hfeat + q * 16;
  float acc[8];
#pragma unroll
  for (int k = 0; k < 8; ++k) acc[k] = 0.f;

  const int nq = deg < 32 ? deg : 32;
  const float* ap = &atab[wid][half][head][0];
  const unsigned* op = &otab[wid][half][0];
#pragma unroll 2
  for (int j0 = 0; j0 < nq; j0 += 2) {
    const int j = j0 + sub;
    const float a = ap[j];
    const uint4 v = *(const uint4*)(hq + op[j]);
    acc[0] = fmaf(blo(v.x), a, acc[0]);
    acc[1] = fmaf(bhi(v.x), a, acc[1]);
    acc[2] = fmaf(blo(v.y), a, acc[2]);
    acc[3] = fmaf(bhi(v.y), a, acc[3]);
    acc[4] = fmaf(blo(v.z), a, acc[4]);
    acc[5] = fmaf(bhi(v.z), a, acc[5]);
    acc[6] = fmaf(blo(v.w), a, acc[6]);
    acc[7] = fmaf(bhi(v.w), a, acc[7]);
  }
  if (deg > 32) {
    const float Mm = head == 0 ? Mh[0] : head == 1 ? Mh[1] : head == 2 ? Mh[2] : Mh[3];
    const float rd = head == 0 ? rden[0] : head == 1 ? rden[1] : head == 2 ? rden[2] : rden[3];
    const float ad_ = head == 0 ? aldd.x : head == 1 ? aldd.y : head == 2 ? aldd.z : aldd.w;
    for (int j0 = 32; j0 < deg; j0 += 2) {
      const int j = j0 + sub;
      float a = 0.f;
      int sn = 0;
      if (j < deg) {
        sn = nbr[start + j];
        const float4 av = ((const float4*)als)[sn];
        const float as_ = head == 0 ? av.x : head == 1 ? av.y : head == 2 ? av.z : av.w;
        float tv = as_ + ad_;
        tv = tv >= 0.f ? tv : NEG_SLOPE * tv;
        a = __expf(tv - Mm) * rd;
      }
      const uint4 v = *(const uint4*)(hq + (size_t)sn * 256);
      acc[0] = fmaf(blo(v.x), a, acc[0]);
      acc[1] = fmaf(bhi(v.x), a, acc[1]);
      acc[2] = fmaf(blo(v.y), a, acc[2]);
      acc[3] = fmaf(bhi(v.y), a, acc[3]);
      acc[4] = fmaf(blo(v.z), a, acc[4]);
      acc[5] = fmaf(bhi(v.z), a, acc[5]);
      acc[6] = fmaf(blo(v.w), a, acc[6]);
      acc[7] = fmaf(bhi(v.w), a, acc[7]);
    }
  }

#pragma unroll
  for (int k = 0; k < 8; ++k) acc[k] += __shfl_xor(acc[k], 16, 64);
  if (valid && sub == 0) {  // lanes l32<16 of each half
    const float4 b0 = ((const float4*)bias)[q * 2];
    const float4 b1 = ((const float4*)bias)[q * 2 + 1];
    float r[8] = {acc[0] + b0.x, acc[1] + b0.y, acc[2] + b0.z, acc[3] + b0.w,
                  acc[4] + b1.x, acc[5] + b1.y, acc[6] + b1.z, acc[7] + b1.w};
#pragma unroll
    for (int k = 0; k < 8; ++k) r[k] = r[k] > 0.f ? r[k] : __expf(r[k]) - 1.f;
    float4* opo = (float4*)(out + (size_t)node * 128 + q * 8);
    opo[0] = make_float4(r[0], r[1], r[2], r[3]);
    opo[1] = make_float4(r[4], r[5], r[6], r[7]);
  }
}

// ---------------- Gather layer 2: H=1, C=64; TWO nodes per wave ----------------
__global__ void k_gather_l2(const int* __restrict__ rowptr, const int* __restrict__ nbr,
                            const float* __restrict__ als, const float* __restrict__ ald,
                            const __hip_bfloat16* __restrict__ hfeat,
                            const float* __restrict__ bias,
                            float* __restrict__ out, int N) {
  __shared__ float2 atab[4][2][36];  // {alpha, off}; stride 36 keeps banks spread
  const int lane = threadIdx.x & 63;
  const int wid = threadIdx.x >> 6;
  const int half = lane >> 5;
  const int l32 = lane & 31;
  const int node = (int)((blockIdx.x * blockDim.x + threadIdx.x) >> 6) * 2 + half;
  const bool valid = node < N;
  int start = 0, end = 0;
  if (valid) {
    start = rowptr[node];
    end = rowptr[node + 1];
  }
  const int deg = end - start;
  const float ald0 = valid ? ald[node] : 0.f;

  float t = NEG_BIG;
  int myn = 0;
  {
    const int j = start + l32;
    if (j < end) {
      myn = nbr[j];
      float tv = als[myn] + ald0;
      t = tv >= 0.f ? tv : NEG_SLOPE * tv;
    }
  }

  float M, rden, myal;
  if (deg <= 32) {
    M = t;
#pragma unroll
    for (int off = 1; off < 32; off <<= 1) M = fmaxf(M, __shfl_xor(M, off, 64));
    const float e = __expf(t - M);
    float sum = e;
#pragma unroll
    for (int off = 1; off < 32; off <<= 1) sum += __shfl_xor(sum, off, 64);
    rden = 1.f / sum;
    myal = e * rden;
  } else {
    float m = t, s = (t > NEG_BIG) ? 1.f : 0.f;
    for (int b = start + 32; b < end; b += 32) {
      const int j = b + l32;
      if (j < end) {
        float tv = als[nbr[j]] + ald0;
        tv = tv >= 0.f ? tv : NEG_SLOPE * tv;
        const float Mn = fmaxf(m, tv);
        s = s * __expf(m - Mn) + __expf(tv - Mn);
        m = Mn;
      }
    }
    M = m;
#pragma unroll
    for (int off = 1; off < 32; off <<= 1) M = fmaxf(M, __shfl_xor(M, off, 64));
    float e = s * __expf(m - M);
#pragma unroll
    for (int off = 1; off < 32; off <<= 1) e += __shfl_xor(e, off, 64);
    rden = 1.f / e;
    myal = __expf(t - M) * rden;
  }
  atab[wid][half][l32 < 36 ? l32 : 35] = make_float2(myal, __int_as_float(myn << 7));

  const int sub = l32 >> 3;  // 4 edge slots
  const int q = l32 & 7;
  const char* hq = (const char*)hfeat + q * 16;
  float acc[8];
#pragma unroll
  for (int k = 0; k < 8; ++k) acc[k] = 0.f;

  const int nq = deg < 32 ? deg : 32;
  const float2* ap = &atab[wid][half][0];
#pragma unroll 2
  for (int j0 = 0; j0 < nq; j0 += 4) {
    const int j = j0 + sub;
    const float2 ao = ap[j];
    const uint4 v = *(const uint4*)(hq + (unsigned)__float_as_int(ao.y));
    const float a = ao.x;
    acc[0] = fmaf(blo(v.x), a, acc[0]);
    acc[1] = fmaf(bhi(v.x), a, acc[1]);
    acc[2] = fmaf(blo(v.y), a, acc[2]);
    acc[3] = fmaf(bhi(v.y), a, acc[3]);
    acc[4] = fmaf(blo(v.z), a, acc[4]);
    acc[5] = fmaf(bhi(v.z), a, acc[5]);
    acc[6] = fmaf(blo(v.w), a, acc[6]);
    acc[7] = fmaf(bhi(v.w), a, acc[7]);
  }
  if (deg > 32) {
    for (int j0 = 32; j0 < deg; j0 += 4) {
      const int j = j0 + sub;
      float a = 0.f;
      int sn = 0;
      if (j < deg) {
        sn = nbr[start + j];
        float tv = als[sn] + ald0;
        tv = tv >= 0.f ? tv : NEG_SLOPE * tv;
        a = __expf(tv - M) * rden;
      }
      const uint4 v = *(const uint4*)(hq + (size_t)sn * 128);
      acc[0] = fmaf(blo(v.x), a, acc[0]);
      acc[1] = fmaf(bhi(v.x), a, acc[1]);
      acc[2] = fmaf(blo(v.y), a, acc[2]);
      acc[3] = fmaf(bhi(v.y), a, acc[3]);
      acc[4] = fmaf(blo(v.z), a, acc[4]);
      acc[5] = fmaf(bhi(v.z), a, acc[5]);
      acc[6] = fmaf(blo(v.w), a, acc[6]);
      acc[7] = fmaf(bhi(v.w), a, acc[7]);
    }
  }

#pragma unroll
  for (int k = 0; k < 8; ++k) {
    acc[k] += __shfl_xor(acc[k], 8, 64);
    acc[k] += __shfl_xor(acc[k], 16, 64);
  }
  if (valid && sub == 0 && q < 8) {  // lanes l32<8 of each half
    const float4 b0 = ((const float4*)bias)[q * 2];
    const float4 b1 = ((const float4*)bias)[q * 2 + 1];
    float4* opo = (float4*)(out + (size_t)node * 64 + q * 8);
    opo[0] = make_float4(acc[0] + b0.x, acc[1] + b0.y, acc[2] + b0.z, acc[3] + b0.w);
    opo[1] = make_float4(acc[4] + b1.x, acc[5] + b1.y, acc[6] + b1.z, acc[7] + b1.w);
  }
}

extern "C" void kernel_launch(void* const* d_in, const int* in_sizes, int n_in,
                              void* d_out, int out_size, void* d_ws, size_t ws_size,
                              hipStream_t stream) {
  const float* x   = (const float*)d_in[0];
  const int*   ei  = (const int*)d_in[1];
  const float* W1  = (const float*)d_in[2];
  const float* a1s = (const float*)d_in[3];
  const float* a1d = (const float*)d_in[4];
  const float* b1  = (const float*)d_in[5];
  const float* W2  = (const float*)d_in[6];
  const float* a2s = (const float*)d_in[7];
  const float* a2d = (const float*)d_in[8];
  const float* b2  = (const float*)d_in[9];

  const int N = in_sizes[0] / 128;  // 100000
  const int E = in_sizes[1] / 2;    // 1600000
  const int* esrc = ei;
  const int* edst = ei + E;

  float* ws   = (float*)d_ws;
  __hip_bfloat16* h = (__hip_bfloat16*)ws;   // N*128 bf16 (slot sized N*128 f32)
  float* out1 = ws   + (size_t)N * 128;      // N*128 f32
  float* als  = out1 + (size_t)N * 128;      // N*4
  float* ald  = als  + (size_t)N * 4;        // N*4
  int* cnt    = (int*)(ald + (size_t)N * 4); // N
  int* rowptr = cnt + N;                     // N+1
  int* cursor = rowptr + N + 1;              // N
  int* bsum   = cursor + N;                  // 1024
  int* nbr    = bsum + 1024;                 // E+N
  size_t off = ((size_t)((nbr + E + N) - (int*)ws) + 3) & ~(size_t)3;
  uint4* wsw1 = (uint4*)((int*)ws + off);    // 144*16 uint4
  uint4* wsw2 = wsw1 + 144 * 16;             // 80*16 uint4

  float* outF = (float*)d_out;               // N*64

  const int total = E + N;
  const int nb = (N + 1023) / 1024;

  // ---- W prep + CSR build ----
  k_prep_w<128, 4><<<(144 * 16 + 255) / 256, 256, 0, stream>>>(W1, a1s, a1d, wsw1);
  k_prep_w<64, 1><<<(80 * 16 + 255) / 256, 256, 0, stream>>>(W2, a2s, a2d, wsw2);
  hipMemsetAsync(cnt, 0, (size_t)N * 4, stream);
  k_count<<<(E + 255) / 256, 256, 0, stream>>>(edst, cnt, E);
  k_scan_local<<<nb, 256, 0, stream>>>(cnt, rowptr, bsum, N);
  k_scan_bsum<<<1, 1024, 0, stream>>>(bsum, nb);
  k_scan_add<<<(N + 256) / 256, 256, 0, stream>>>(bsum, rowptr, cursor, N, total);
  k_build_part<<<1280, 256, 0, stream>>>(esrc, edst, cursor, nbr, E, N);

  // ---- Layer 1: H=4, C=32, concat -> [N,128], +b1, ELU ----
  k_mfma_gemm<128, 4><<<(N + 127) / 128, 256, 0, stream>>>(x, wsw1, h, als, ald, N);
  k_gather_l1<<<(N + 7) / 8, 256, 0, stream>>>(rowptr, nbr, als, ald, h, b1, out1, N);

  // ---- Layer 2: H=1, C=64, mean(H=1) -> [N,64], +b2 ----
  k_mfma_gemm<64, 1><<<(N + 127) / 128, 256, 0, stream>>>(out1, wsw2, h, als, ald, N);
  k_gather_l2<<<(N + 7) / 8, 256, 0, stream>>>(rowptr, nbr, als, ald, h, b2, outF, N);
}

// Round 11
// 327.313 us; speedup vs baseline: 5.6130x; 1.0062x over previous
//
#include <hip/hip_runtime.h>
#include <hip/hip_bf16.h>
#include <math.h>

static constexpr float NEG_SLOPE = 0.2f;
static constexpr float NEG_BIG = -3.0e38f;  // finite sentinel: avoids (-inf)-(-inf)=NaN

typedef __attribute__((ext_vector_type(8))) short short8;  // 8 bf16 (4 VGPRs)
typedef __attribute__((ext_vector_type(4))) float f32x4;

__device__ __forceinline__ float blo(unsigned u) { return __uint_as_float(u << 16); }
__device__ __forceinline__ float bhi(unsigned u) { return __uint_as_float(u & 0xffff0000u); }
__device__ __forceinline__ unsigned pack2(float a, float b) {
  __hip_bfloat162 t = __float22bfloat162_rn(make_float2(a, b));
  union { __hip_bfloat162 b; unsigned u; } v;
  v.b = t;
  return v.u;
}

#define FMA8(V, A)                         \
  acc[0] = fmaf(blo((V).x), (A), acc[0]);  \
  acc[1] = fmaf(bhi((V).x), (A), acc[1]);  \
  acc[2] = fmaf(blo((V).y), (A), acc[2]);  \
  acc[3] = fmaf(bhi((V).y), (A), acc[3]);  \
  acc[4] = fmaf(blo((V).z), (A), acc[4]);  \
  acc[5] = fmaf(bhi((V).z), (A), acc[5]);  \
  acc[6] = fmaf(blo((V).w), (A), acc[6]);  \
  acc[7] = fmaf(bhi((V).w), (A), acc[7])

// ---- W prep: fp32 [k][col] -> bf16 swizzled [col][k] LDS image, PLUS 16 extra
// cols holding WA = W@A so the GEMM emits attention logits as a free tile.
template <int BN, int HEADS>
__global__ void k_prep_w(const float* __restrict__ W, const float* __restrict__ as_,
                         const float* __restrict__ ad_, uint4* __restrict__ out) {
  constexpr int XC = BN + 16;
  constexpr int C = BN / HEADS;
  const int i = blockIdx.x * blockDim.x + threadIdx.x;
  if (i >= XC * 16) return;
  const int col = i >> 4;
  const int chunk = (i & 15) ^ (col & 7);
  float v[8];
  if (col < BN) {
#pragma unroll
    for (int t = 0; t < 8; ++t) v[t] = W[(size_t)(chunk * 8 + t) * BN + col];
  } else {
    const int j = col - BN;
#pragma unroll
    for (int t = 0; t < 8; ++t) v[t] = 0.f;
    if (j < 2 * HEADS) {
      const int hh = (HEADS == 4) ? (j & 3) : 0;
      const bool is_src = (HEADS == 4) ? (j < 4) : (j == 0);
      const float* av = (is_src ? as_ : ad_) + hh * C;
      const float* wb = W + hh * C;
#pragma unroll
      for (int t = 0; t < 8; ++t) {
        float s = 0.f;
        for (int c = 0; c < C; ++c) s = fmaf(wb[(size_t)(chunk * 8 + t) * BN + c], av[c], s);
        v[t] = s;
      }
    }
  }
  uint4 u;
  u.x = pack2(v[0], v[1]);
  u.y = pack2(v[2], v[3]);
  u.z = pack2(v[4], v[5]);
  u.w = pack2(v[6], v[7]);
  out[i] = u;
}

// ---- MFMA GEMM: h = x@W (bf16), logits from extra tile. Single reused LDS buf.
template <int BN, int HEADS>
__global__ __launch_bounds__(256) void k_mfma_gemm(
    const float* __restrict__ x, const uint4* __restrict__ wsw,
    __hip_bfloat16* __restrict__ h_out, float* __restrict__ als,
    float* __restrict__ ald, int N) {
  constexpr int XC = BN + 16;
  constexpr int NTILES = BN / 16;
  constexpr int BUFSZ = (XC * 256 > 128 * 256) ? XC * 256 : 128 * 256;
  __shared__ unsigned char buf[BUFSZ];
  const int tid = threadIdx.x;
  const int lane = tid & 63;
  const int wid = tid >> 6;
  const int base = blockIdx.x * 128;

  for (int it = 0; it < 8; ++it) {
    const int i = it * 256 + tid;
    const int r = i >> 4, c = i & 15;
    const int g = base + r;
    float4 f0 = make_float4(0.f, 0.f, 0.f, 0.f), f1 = f0;
    if (g < N) {
      const float* xp = x + (size_t)g * 128 + c * 8;
      f0 = *(const float4*)xp;
      f1 = *(const float4*)(xp + 4);
    }
    uint4 u;
    u.x = pack2(f0.x, f0.y);
    u.y = pack2(f0.z, f0.w);
    u.z = pack2(f1.x, f1.y);
    u.w = pack2(f1.z, f1.w);
    *(uint4*)(buf + r * 256 + ((c * 16) ^ ((r & 7) << 4))) = u;
  }
  __syncthreads();

  const int lg = lane >> 4;
  const int ll = lane & 15;
  union U { uint4 u; short8 s; };
  short8 afr[2][4];
#pragma unroll
  for (int rt = 0; rt < 2; ++rt) {
    const int row = wid * 32 + rt * 16 + ll;
    const unsigned char* rp = buf + row * 256;
    const int swz = (row & 7) << 4;
#pragma unroll
    for (int ks = 0; ks < 4; ++ks) {
      U t;
      t.u = *(const uint4*)(rp + ((ks * 64 + lg * 16) ^ swz));
      afr[rt][ks] = t.s;
    }
  }
  __syncthreads();  // done with X region; reuse buf for W

  {
    uint4* dst = (uint4*)buf;
    for (int i = tid; i < XC * 16; i += 256) dst[i] = wsw[i];
  }
  __syncthreads();

  f32x4 acc[2][NTILES + 1];
#pragma unroll
  for (int rt = 0; rt < 2; ++rt)
#pragma unroll
    for (int t = 0; t <= NTILES; ++t) acc[rt][t] = (f32x4){0.f, 0.f, 0.f, 0.f};

#pragma unroll
  for (int t = 0; t <= NTILES; ++t) {
    const int col = t * 16 + ll;
    const unsigned char* cp = buf + col * 256;
    const int swz = (col & 7) << 4;
#pragma unroll
    for (int ks = 0; ks < 4; ++ks) {
      U b;
      b.u = *(const uint4*)(cp + ((ks * 64 + lg * 16) ^ swz));
      acc[0][t] = __builtin_amdgcn_mfma_f32_16x16x32_bf16(afr[0][ks], b.s, acc[0][t], 0, 0, 0);
      acc[1][t] = __builtin_amdgcn_mfma_f32_16x16x32_bf16(afr[1][ks], b.s, acc[1][t], 0, 0, 0);
    }
  }

#pragma unroll
  for (int rt = 0; rt < 2; ++rt) {
#pragma unroll
    for (int r = 0; r < 4; ++r) {
      const int row = base + wid * 32 + rt * 16 + lg * 4 + r;
      if (row < N) {
        const float v = acc[rt][NTILES][r];
        if (HEADS == 4) {
          if (ll < 4) als[(size_t)row * 4 + ll] = v;
          else if (ll < 8) ald[(size_t)row * 4 + (ll - 4)] = v;
        } else {
          if (ll == 0) als[row] = v;
          else if (ll == 1) ald[row] = v;
        }
      }
    }
  }

  __syncthreads();
#pragma unroll
  for (int rt = 0; rt < 2; ++rt) {
#pragma unroll
    for (int t = 0; t < NTILES; ++t) {
#pragma unroll
      for (int r = 0; r < 4; ++r) {
        const float v = acc[rt][t][r];
        const float vn = __shfl_xor(v, 1, 64);
        if (!(lane & 1)) {
          const int row = wid * 32 + rt * 16 + lg * 4 + r;
          *(unsigned*)(buf + row * (BN * 2) + (t * 16 + ll) * 2) = pack2(v, vn);
        }
      }
    }
  }
  __syncthreads();
  {
    constexpr int U4 = 128 * BN / 8;
    constexpr int U4R = BN / 8;
    for (int i = tid; i < U4; i += 256) {
      const int row = i / U4R;
      const int g = base + row;
      if (g < N)
        *(uint4*)((unsigned short*)h_out + (size_t)g * BN + (i % U4R) * 8) = ((uint4*)buf)[i];
    }
  }
}

// ---------------- CSR build (counting sort by dst) ----------------
__global__ void k_count(const int* __restrict__ edst, int* __restrict__ cnt, int E) {
  int i = blockIdx.x * blockDim.x + threadIdx.x;
  if (i < E) atomicAdd(cnt + edst[i], 1);
}

// +1 folded in (self-loop); cnt must be zeroed beforehand.
__global__ void k_scan_local(const int* __restrict__ cnt, int* __restrict__ rowptr,
                             int* __restrict__ bsum, int N) {
  __shared__ int lds[256];
  const int tid = threadIdx.x;
  const int base = blockIdx.x * 1024;
  int vals[4], tsum = 0;
#pragma unroll
  for (int q = 0; q < 4; ++q) {
    int i = base + tid * 4 + q;
    vals[q] = (i < N) ? cnt[i] + 1 : 0;
    tsum += vals[q];
  }
  lds[tid] = tsum;
  __syncthreads();
  for (int off = 1; off < 256; off <<= 1) {
    int t = (tid >= off) ? lds[tid - off] : 0;
    __syncthreads();
    lds[tid] += t;
    __syncthreads();
  }
  int run = lds[tid] - tsum;
  if (tid == 255) bsum[blockIdx.x] = lds[255];
#pragma unroll
  for (int q = 0; q < 4; ++q) {
    int i = base + tid * 4 + q;
    if (i < N) rowptr[i] = run;
    run += vals[q];
  }
}

__global__ void k_scan_bsum(int* __restrict__ bsum, int nb) {
  __shared__ int lds[1024];
  const int tid = threadIdx.x;
  int v = (tid < nb) ? bsum[tid] : 0;
  lds[tid] = v;
  __syncthreads();
  for (int off = 1; off < 1024; off <<= 1) {
    int t = (tid >= off) ? lds[tid - off] : 0;
    __syncthreads();
    lds[tid] += t;
    __syncthreads();
  }
  bsum[tid] = lds[tid] - v;
}

__global__ void k_scan_add(const int* __restrict__ bsum, int* __restrict__ rowptr,
                           int* __restrict__ cursor, int N, int total) {
  int i = blockIdx.x * blockDim.x + threadIdx.x;
  if (i < N) {
    int r = rowptr[i] + bsum[i >> 10];
    rowptr[i] = r;
    cursor[i] = r;
  } else if (i == N) {
    rowptr[N] = total;
  }
}

// Partitioned CSR fill: 4 parts -> 4 streaming sweeps, writes confined to a
// 1.7MB region per part (L2-resident on that part's 2 XCDs).
__global__ void k_build_part(const int* __restrict__ esrc, const int* __restrict__ edst,
                             int* __restrict__ cursor, int* __restrict__ nbr, int E, int N) {
  constexpr int NPARTS = 4;
  const int p = blockIdx.x & 3;
  const int span = (N + NPARTS - 1) / NPARTS;
  const int lo = p * span;
  const int hi = min(N, lo + span);
  const int gid = (int)(blockIdx.x >> 2) * blockDim.x + threadIdx.x;
  const int stride = (int)(gridDim.x >> 2) * blockDim.x;
  const int E4 = E >> 2;
  for (int i = gid; i < E4; i += stride) {
    const int4 d4 = ((const int4*)edst)[i];
    const int4 s4 = ((const int4*)esrc)[i];
    if (d4.x >= lo && d4.x < hi) nbr[atomicAdd(cursor + d4.x, 1)] = s4.x;
    if (d4.y >= lo && d4.y < hi) nbr[atomicAdd(cursor + d4.y, 1)] = s4.y;
    if (d4.z >= lo && d4.z < hi) nbr[atomicAdd(cursor + d4.z, 1)] = s4.z;
    if (d4.w >= lo && d4.w < hi) nbr[atomicAdd(cursor + d4.w, 1)] = s4.w;
  }
  for (int i = E4 * 4 + gid; i < E + N; i += stride) {
    const int d = i < E ? edst[i] : i - E;
    if (d >= lo && d < hi) {
      const int sn = i < E ? esrc[i] : i - E;
      nbr[atomicAdd(cursor + d, 1)] = sn;
    }
  }
}

// ---------------- Gather layer 1: H=4, C=32; two nodes/wave; 8-edge batches ----
__global__ void k_gather_l1(const int* __restrict__ rowptr, const int* __restrict__ nbr,
                            const float* __restrict__ als, const float* __restrict__ ald,
                            const __hip_bfloat16* __restrict__ hfeat,
                            const float* __restrict__ bias,
                            float* __restrict__ out, int N) {
  __shared__ float atab[4][2][4][40];    // [wave][half][head][edge]
  __shared__ unsigned otab[4][2][32];    // [wave][half][edge] byte offsets
  const int lane = threadIdx.x & 63;
  const int wid = threadIdx.x >> 6;
  const int half = lane >> 5;
  const int l32 = lane & 31;
  const int node = (int)((blockIdx.x * blockDim.x + threadIdx.x) >> 6) * 2 + half;
  const bool valid = node < N;
  int start = 0, end = 0;
  if (valid) {
    start = rowptr[node];
    end = rowptr[node + 1];
  }
  const int deg = end - start;
  const float4 aldd = valid ? ((const float4*)ald)[node] : make_float4(0.f, 0.f, 0.f, 0.f);

  float t[4];
  int myn = 0;
  {
    const int j = start + l32;
    if (j < end) {
      myn = nbr[j];
      const float4 av = ((const float4*)als)[myn];
      const float tr[4] = {av.x + aldd.x, av.y + aldd.y, av.z + aldd.z, av.w + aldd.w};
#pragma unroll
      for (int h = 0; h < 4; ++h) t[h] = tr[h] >= 0.f ? tr[h] : NEG_SLOPE * tr[h];
    } else {
#pragma unroll
      for (int h = 0; h < 4; ++h) t[h] = NEG_BIG;
    }
  }
  otab[wid][half][l32] = (unsigned)myn << 8;  // 256B rows

  float Mh[4], rden[4], myex[4];
  if (deg <= 32) {
#pragma unroll
    for (int h = 0; h < 4; ++h) {
      float M = t[h];
#pragma unroll
      for (int off = 1; off < 32; off <<= 1) M = fmaxf(M, __shfl_xor(M, off, 64));
      const float e = __expf(t[h] - M);
      float sum = e;
#pragma unroll
      for (int off = 1; off < 32; off <<= 1) sum += __shfl_xor(sum, off, 64);
      Mh[h] = M;
      rden[h] = 1.f / sum;
      myex[h] = e * rden[h];
    }
  } else {
    float m[4], s[4];
#pragma unroll
    for (int h = 0; h < 4; ++h) {
      m[h] = t[h];
      s[h] = (t[h] > NEG_BIG) ? 1.f : 0.f;
    }
    for (int b = start + 32; b < end; b += 32) {
      const int j = b + l32;
      if (j < end) {
        const int sn = nbr[j];
        const float4 av = ((const float4*)als)[sn];
        const float tr[4] = {av.x + aldd.x, av.y + aldd.y, av.z + aldd.z, av.w + aldd.w};
#pragma unroll
        for (int h = 0; h < 4; ++h) {
          const float tv = tr[h] >= 0.f ? tr[h] : NEG_SLOPE * tr[h];
          const float M = fmaxf(m[h], tv);
          s[h] = s[h] * __expf(m[h] - M) + __expf(tv - M);
          m[h] = M;
        }
      }
    }
#pragma unroll
    for (int h = 0; h < 4; ++h) {
      float M = m[h];
#pragma unroll
      for (int off = 1; off < 32; off <<= 1) M = fmaxf(M, __shfl_xor(M, off, 64));
      float e = s[h] * __expf(m[h] - M);
#pragma unroll
      for (int off = 1; off < 32; off <<= 1) e += __shfl_xor(e, off, 64);
      Mh[h] = M;
      rden[h] = 1.f / e;
      myex[h] = __expf(t[h] - M) * rden[h];
    }
  }
#pragma unroll
  for (int h = 0; h < 4; ++h) atab[wid][half][h][l32] = myex[h];

  // pass C: 8 edges per iteration (2 slots x 4 batched loads in flight)
  const int sub = l32 >> 4;
  const int q = l32 & 15;
  const int head = q >> 2;
  const char* hq = (const char*)hfeat + q * 16;
  float acc[8];
#pragma unroll
  for (int k = 0; k < 8; ++k) acc[k] = 0.f;

  const int nq = deg < 32 ? deg : 32;
  const float* ap = &atab[wid][half][head][0];
  const unsigned* op = &otab[wid][half][0];
  for (int j0 = 0; j0 < nq; j0 += 8) {
    const float a0 = ap[j0 + sub];
    const float a1 = ap[j0 + 2 + sub];
    const float a2 = ap[j0 + 4 + sub];
    const float a3 = ap[j0 + 6 + sub];
    const uint4 v0 = *(const uint4*)(hq + op[j0 + sub]);
    const uint4 v1 = *(const uint4*)(hq + op[j0 + 2 + sub]);
    const uint4 v2 = *(const uint4*)(hq + op[j0 + 4 + sub]);
    const uint4 v3 = *(const uint4*)(hq + op[j0 + 6 + sub]);
    FMA8(v0, a0);
    FMA8(v1, a1);
    FMA8(v2, a2);
    FMA8(v3, a3);
  }
  if (deg > 32) {
    const float Mm = head == 0 ? Mh[0] : head == 1 ? Mh[1] : head == 2 ? Mh[2] : Mh[3];
    const float rd = head == 0 ? rden[0] : head == 1 ? rden[1] : head == 2 ? rden[2] : rden[3];
    const float ad_ = head == 0 ? aldd.x : head == 1 ? aldd.y : head == 2 ? aldd.z : aldd.w;
    for (int j0 = 32; j0 < deg; j0 += 2) {
      const int j = j0 + sub;
      float a = 0.f;
      int sn = 0;
      if (j < deg) {
        sn = nbr[start + j];
        const float4 av = ((const float4*)als)[sn];
        const float as_ = head == 0 ? av.x : head == 1 ? av.y : head == 2 ? av.z : av.w;
        float tv = as_ + ad_;
        tv = tv >= 0.f ? tv : NEG_SLOPE * tv;
        a = __expf(tv - Mm) * rd;
      }
      const uint4 v = *(const uint4*)(hq + (size_t)sn * 256);
      FMA8(v, a);
    }
  }

#pragma unroll
  for (int k = 0; k < 8; ++k) acc[k] += __shfl_xor(acc[k], 16, 64);
  if (valid && sub == 0) {
    const float4 b0 = ((const float4*)bias)[q * 2];
    const float4 b1 = ((const float4*)bias)[q * 2 + 1];
    float r[8] = {acc[0] + b0.x, acc[1] + b0.y, acc[2] + b0.z, acc[3] + b0.w,
                  acc[4] + b1.x, acc[5] + b1.y, acc[6] + b1.z, acc[7] + b1.w};
#pragma unroll
    for (int k = 0; k < 8; ++k) r[k] = r[k] > 0.f ? r[k] : __expf(r[k]) - 1.f;
    float4* opo = (float4*)(out + (size_t)node * 128 + q * 8);
    opo[0] = make_float4(r[0], r[1], r[2], r[3]);
    opo[1] = make_float4(r[4], r[5], r[6], r[7]);
  }
}

// ---------------- Gather layer 2: H=1, C=64; two nodes/wave; 16-edge batches ----
__global__ void k_gather_l2(const int* __restrict__ rowptr, const int* __restrict__ nbr,
                            const float* __restrict__ als, const float* __restrict__ ald,
                            const __hip_bfloat16* __restrict__ hfeat,
                            const float* __restrict__ bias,
                            float* __restrict__ out, int N) {
  __shared__ float2 atab[4][2][36];  // {alpha, off}
  const int lane = threadIdx.x & 63;
  const int wid = threadIdx.x >> 6;
  const int half = lane >> 5;
  const int l32 = lane & 31;
  const int node = (int)((blockIdx.x * blockDim.x + threadIdx.x) >> 6) * 2 + half;
  const bool valid = node < N;
  int start = 0, end = 0;
  if (valid) {
    start = rowptr[node];
    end = rowptr[node + 1];
  }
  const int deg = end - start;
  const float ald0 = valid ? ald[node] : 0.f;

  float t = NEG_BIG;
  int myn = 0;
  {
    const int j = start + l32;
    if (j < end) {
      myn = nbr[j];
      float tv = als[myn] + ald0;
      t = tv >= 0.f ? tv : NEG_SLOPE * tv;
    }
  }

  float M, rden, myal;
  if (deg <= 32) {
    M = t;
#pragma unroll
    for (int off = 1; off < 32; off <<= 1) M = fmaxf(M, __shfl_xor(M, off, 64));
    const float e = __expf(t - M);
    float sum = e;
#pragma unroll
    for (int off = 1; off < 32; off <<= 1) sum += __shfl_xor(sum, off, 64);
    rden = 1.f / sum;
    myal = e * rden;
  } else {
    float m = t, s = (t > NEG_BIG) ? 1.f : 0.f;
    for (int b = start + 32; b < end; b += 32) {
      const int j = b + l32;
      if (j < end) {
        float tv = als[nbr[j]] + ald0;
        tv = tv >= 0.f ? tv : NEG_SLOPE * tv;
        const float Mn = fmaxf(m, tv);
        s = s * __expf(m - Mn) + __expf(tv - Mn);
        m = Mn;
      }
    }
    M = m;
#pragma unroll
    for (int off = 1; off < 32; off <<= 1) M = fmaxf(M, __shfl_xor(M, off, 64));
    float e = s * __expf(m - M);
#pragma unroll
    for (int off = 1; off < 32; off <<= 1) e += __shfl_xor(e, off, 64);
    rden = 1.f / e;
    myal = __expf(t - M) * rden;
  }
  atab[wid][half][l32] = make_float2(myal, __int_as_float(myn << 7));  // 128B rows

  const int sub = l32 >> 3;  // 4 edge slots
  const int q = l32 & 7;
  const char* hq = (const char*)hfeat + q * 16;
  float acc[8];
#pragma unroll
  for (int k = 0; k < 8; ++k) acc[k] = 0.f;

  const int nq = deg < 32 ? deg : 32;
  const float2* ap = &atab[wid][half][0];
  for (int j0 = 0; j0 < nq; j0 += 16) {
    const float2 o0 = ap[j0 + sub];
    const float2 o1 = ap[j0 + 4 + sub];
    const float2 o2 = ap[j0 + 8 + sub];
    const float2 o3 = ap[j0 + 12 + sub];
    const uint4 v0 = *(const uint4*)(hq + (unsigned)__float_as_int(o0.y));
    const uint4 v1 = *(const uint4*)(hq + (unsigned)__float_as_int(o1.y));
    const uint4 v2 = *(const uint4*)(hq + (unsigned)__float_as_int(o2.y));
    const uint4 v3 = *(const uint4*)(hq + (unsigned)__float_as_int(o3.y));
    FMA8(v0, o0.x);
    FMA8(v1, o1.x);
    FMA8(v2, o2.x);
    FMA8(v3, o3.x);
  }
  if (deg > 32) {
    for (int j0 = 32; j0 < deg; j0 += 4) {
      const int j = j0 + sub;
      float a = 0.f;
      int sn = 0;
      if (j < deg) {
        sn = nbr[start + j];
        float tv = als[sn] + ald0;
        tv = tv >= 0.f ? tv : NEG_SLOPE * tv;
        a = __expf(tv - M) * rden;
      }
      const uint4 v = *(const uint4*)(hq + (size_t)sn * 128);
      FMA8(v, a);
    }
  }

#pragma unroll
  for (int k = 0; k < 8; ++k) {
    acc[k] += __shfl_xor(acc[k], 8, 64);
    acc[k] += __shfl_xor(acc[k], 16, 64);
  }
  if (valid && sub == 0) {
    const float4 b0 = ((const float4*)bias)[q * 2];
    const float4 b1 = ((const float4*)bias)[q * 2 + 1];
    float4* opo = (float4*)(out + (size_t)node * 64 + q * 8);
    opo[0] = make_float4(acc[0] + b0.x, acc[1] + b0.y, acc[2] + b0.z, acc[3] + b0.w);
    opo[1] = make_float4(acc[4] + b1.x, acc[5] + b1.y, acc[6] + b1.z, acc[7] + b1.w);
  }
}

extern "C" void kernel_launch(void* const* d_in, const int* in_sizes, int n_in,
                              void* d_out, int out_size, void* d_ws, size_t ws_size,
                              hipStream_t stream) {
  const float* x   = (const float*)d_in[0];
  const int*   ei  = (const int*)d_in[1];
  const float* W1  = (const float*)d_in[2];
  const float* a1s = (const float*)d_in[3];
  const float* a1d = (const float*)d_in[4];
  const float* b1  = (const float*)d_in[5];
  const float* W2  = (const float*)d_in[6];
  const float* a2s = (const float*)d_in[7];
  const float* a2d = (const float*)d_in[8];
  const float* b2  = (const float*)d_in[9];

  const int N = in_sizes[0] / 128;  // 100000
  const int E = in_sizes[1] / 2;    // 1600000
  const int* esrc = ei;
  const int* edst = ei + E;

  float* ws   = (float*)d_ws;
  __hip_bfloat16* h = (__hip_bfloat16*)ws;   // N*128 bf16 (slot sized N*128 f32)
  float* out1 = ws   + (size_t)N * 128;      // N*128 f32
  float* als  = out1 + (size_t)N * 128;      // N*4
  float* ald  = als  + (size_t)N * 4;        // N*4
  int* cnt    = (int*)(ald + (size_t)N * 4); // N
  int* rowptr = cnt + N;                     // N+1
  int* cursor = rowptr + N + 1;              // N
  int* bsum   = cursor + N;                  // 1024
  int* nbr    = bsum + 1024;                 // E+N
  size_t off = ((size_t)((nbr + E + N) - (int*)ws) + 3) & ~(size_t)3;
  uint4* wsw1 = (uint4*)((int*)ws + off);    // 144*16 uint4
  uint4* wsw2 = wsw1 + 144 * 16;             // 80*16 uint4

  float* outF = (float*)d_out;               // N*64

  const int total = E + N;
  const int nb = (N + 1023) / 1024;

  // ---- W prep + CSR build ----
  k_prep_w<128, 4><<<(144 * 16 + 255) / 256, 256, 0, stream>>>(W1, a1s, a1d, wsw1);
  k_prep_w<64, 1><<<(80 * 16 + 255) / 256, 256, 0, stream>>>(W2, a2s, a2d, wsw2);
  hipMemsetAsync(cnt, 0, (size_t)N * 4, stream);
  k_count<<<(E + 255) / 256, 256, 0, stream>>>(edst, cnt, E);
  k_scan_local<<<nb, 256, 0, stream>>>(cnt, rowptr, bsum, N);
  k_scan_bsum<<<1, 1024, 0, stream>>>(bsum, nb);
  k_scan_add<<<(N + 256) / 256, 256, 0, stream>>>(bsum, rowptr, cursor, N, total);
  k_build_part<<<1280, 256, 0, stream>>>(esrc, edst, cursor, nbr, E, N);

  // ---- Layer 1: H=4, C=32, concat -> [N,128], +b1, ELU ----
  k_mfma_gemm<128, 4><<<(N + 127) / 128, 256, 0, stream>>>(x, wsw1, h, als, ald, N);
  k_gather_l1<<<(N + 7) / 8, 256, 0, stream>>>(rowptr, nbr, als, ald, h, b1, out1, N);

  // ---- Layer 2: H=1, C=64, mean(H=1) -> [N,64], +b2 ----
  k_mfma_gemm<64, 1><<<(N + 127) / 128, 256, 0, stream>>>(out1, wsw2, h, als, ald, N);
  k_gather_l2<<<(N + 7) / 8, 256, 0, stream>>>(rowptr, nbr, als, ald, h, b2, outF, N);
}